// Round 5
// baseline (3196.331 us; speedup 1.0000x reference)
//
#include <hip/hip_runtime.h>

// InvariantBlock: AFNO spectral block + Galerkin linear attention + GELU FFN
// B=2 H=128 W=128 C=256; tokens 32768; KW=65; HEADS=8 DH=32; NB=16 BS=16 HID=128
// d_in / d_out are FP32 (per reference dtypes). Intermediates bf16 in ws.
// ws: < 50 MiB. Diagnostics: per-stage anomaly probes + final out scrub;
// on anomaly absmax becomes a decodable code (1000*stage, +500 NaN, 20000 out).

typedef unsigned short u16;
typedef unsigned int u32;
#define DEV __device__ __forceinline__

constexpr int Hh = 128, Ww = 128, Cch = 256, KW = 65;
constexpr float EPSN = 1e-5f, LAM = 0.01f;
constexpr float TWO_PI = 6.283185307179586f;

DEV float b2f(u16 u) { return __uint_as_float(((u32)u) << 16); }
DEV u16 f2b(float f) {
  u32 x = __float_as_uint(f);
  return (u16)((x + 0x7FFFu + ((x >> 16) & 1u)) >> 16);
}

// ---------------- probes / scrub / emit --------------------------------------
__global__ void k_clear(float* slots) {
  if (threadIdx.x < 32) slots[threadIdx.x] = 0.0f;
}

template<int CHECKZERO>
__global__ void k_probe_b(const u16* __restrict__ buf, long off, float code,
                          float* __restrict__ slots, int s) {
  int lane = threadIdx.x;
  u16 u = buf[off + lane];
  int nf = ((u & 0x7F80u) == 0x7F80u) ? 1 : 0;
  int nz = ((u & 0x7FFFu) != 0) ? 1 : 0;
  #pragma unroll
  for (int m = 1; m < 64; m <<= 1) { nf |= __shfl_xor(nf, m); nz |= __shfl_xor(nz, m); }
  if (lane == 0) {
    if (nf) slots[s] = code + 500.0f;
    else if (CHECKZERO && !nz) slots[s] = code;
  }
}

__global__ void k_probe_f(const float* __restrict__ buf, long off, float code,
                          float* __restrict__ slots, int s) {
  int lane = threadIdx.x;
  float v = buf[off + lane];
  u32 e = (__float_as_uint(v) >> 23) & 0xFFu;
  int nf = (e == 0xFFu) ? 1 : 0;
  int nz = (v != 0.0f) ? 1 : 0;
  #pragma unroll
  for (int m = 1; m < 64; m <<= 1) { nf |= __shfl_xor(nf, m); nz |= __shfl_xor(nz, m); }
  if (lane == 0) {
    if (nf) slots[s] = code + 500.0f;
    else if (!nz) slots[s] = code;
  }
}

// replace non-finite fp32 with 0; mark slots[15] (all writers store same value)
__global__ __launch_bounds__(256) void k_scrub_out(float* __restrict__ out, int n,
                                                   float* __restrict__ slots) {
  int stride = gridDim.x * 256;
  for (int i = blockIdx.x * 256 + threadIdx.x; i < n; i += stride) {
    u32 u = __float_as_uint(out[i]);
    if (((u >> 23) & 0xFFu) == 0xFFu) { out[i] = 0.0f; slots[15] = 20000.0f; }
  }
}

__global__ void k_emit(const float* __restrict__ slots, float* __restrict__ out) {
  int i = threadIdx.x;
  if (i >= 1 && i <= 15) {
    float c = slots[i];
    if (c != 0.0f) out[i] = c;
  }
}

// ---------------- LayerNorm over C=256; INF=1 fp32 input, else bf16 ----------
template<int INF>
__global__ __launch_bounds__(256) void k_ln(const void* __restrict__ in,
                                            const float* __restrict__ g,
                                            const float* __restrict__ bta,
                                            u16* __restrict__ out) {
  int tid = threadIdx.x, lane = tid & 63;
  size_t token = (size_t)blockIdx.x * 4 + (tid >> 6);
  int c = lane * 4;
  float v[4];
  if (INF) {
    float4 f = *(const float4*)((const float*)in + token * Cch + c);
    v[0] = f.x; v[1] = f.y; v[2] = f.z; v[3] = f.w;
  } else {
    ushort4 u = *(const ushort4*)((const u16*)in + token * Cch + c);
    v[0] = b2f(u.x); v[1] = b2f(u.y); v[2] = b2f(u.z); v[3] = b2f(u.w);
  }
  float s = v[0] + v[1] + v[2] + v[3];
  #pragma unroll
  for (int m = 1; m < 64; m <<= 1) s += __shfl_xor(s, m);
  float mu = s * (1.0f / 256.0f);
  float q = 0.f;
  #pragma unroll
  for (int j = 0; j < 4; j++) { float d = v[j] - mu; q += d * d; }
  #pragma unroll
  for (int m = 1; m < 64; m <<= 1) q += __shfl_xor(q, m);
  float rs = rsqrtf(q * (1.0f / 256.0f) + EPSN);
  ushort4 o;
  o.x = f2b((v[0] - mu) * rs * g[c + 0] + bta[c + 0]);
  o.y = f2b((v[1] - mu) * rs * g[c + 1] + bta[c + 1]);
  o.z = f2b((v[2] - mu) * rs * g[c + 2] + bta[c + 2]);
  o.w = f2b((v[3] - mu) * rs * g[c + 3] + bta[c + 3]);
  *(ushort4*)(out + token * Cch + c) = o;
}

// ---------------- forward rDFT over W: A[b,h,w,c] -> T[b,h,kw,c] --------------
__global__ __launch_bounds__(256) void k_dft_w(const u16* __restrict__ y,
                                               u16* __restrict__ Tr,
                                               u16* __restrict__ Ti) {
  __shared__ u16 ys[128][128];
  __shared__ float ct[128], st[128];
  int tid = threadIdx.x;
  int bh = blockIdx.x;
  int c0 = blockIdx.y * 128;
  if (tid < 128) {
    float ang = TWO_PI * (float)tid / 128.0f;
    ct[tid] = cosf(ang); st[tid] = sinf(ang);
  }
  const u16* yb = y + (size_t)bh * Ww * Cch + c0;
  for (int idx = tid; idx < 128 * 128; idx += 256) {
    int w = idx >> 7, c = idx & 127;
    ys[w][c] = yb[(size_t)w * Cch + c];
  }
  __syncthreads();
  int cl = tid & 127;
  int half = tid >> 7;
  int kws = half ? 33 : 0, kwe = half ? 65 : 33;
  for (int kw = kws; kw < kwe; kw++) {
    float ar = 0.f, ai = 0.f;
    #pragma unroll 8
    for (int w = 0; w < 128; w++) {
      int j = (w * kw) & 127;
      float a = b2f(ys[w][cl]);
      ar += a * ct[j];
      ai -= a * st[j];
    }
    size_t o = ((size_t)bh * KW + kw) * Cch + c0 + cl;
    Tr[o] = f2b(ar); Ti[o] = f2b(ai);
  }
}

// ------- complex DFT over H (fwd: e^-i, scale 1/128; inv: e^+i, no scale) ----
template<bool INV, bool SC>
__global__ __launch_bounds__(256) void k_dft_h(const u16* __restrict__ inR,
                                               const u16* __restrict__ inI,
                                               u16* __restrict__ outR,
                                               u16* __restrict__ outI) {
  __shared__ u16 sr[128][64], si[128][64];
  __shared__ float ct[128], st[128];
  int tid = threadIdx.x;
  int bk = blockIdx.x;
  int b = bk / KW, kw = bk % KW;
  int c0 = blockIdx.y * 64;
  if (tid < 128) {
    float ang = TWO_PI * (float)tid / 128.0f;
    ct[tid] = cosf(ang); st[tid] = sinf(ang);
  }
  for (int idx = tid; idx < 128 * 64; idx += 256) {
    int q = idx >> 6, c = idx & 63;
    size_t o = (((size_t)b * Hh + q) * KW + kw) * Cch + c0 + c;
    sr[q][c] = inR[o]; si[q][c] = inI[o];
  }
  __syncthreads();
  int cl = tid & 63, pq = tid >> 6;
  for (int p = pq * 32; p < pq * 32 + 32; p++) {
    float orr = 0.f, oii = 0.f;
    #pragma unroll 8
    for (int q = 0; q < 128; q++) {
      int j = (p * q) & 127;
      float ar = b2f(sr[q][cl]), ai = b2f(si[q][cl]);
      float cj = ct[j], sj = st[j];
      if (!INV) { orr += ar * cj + ai * sj; oii += ai * cj - ar * sj; }
      else      { orr += ar * cj - ai * sj; oii += ai * cj + ar * sj; }
    }
    if (SC) { orr *= (1.0f / 128.0f); oii *= (1.0f / 128.0f); }
    size_t o = (((size_t)b * Hh + p) * KW + kw) * Cch + c0 + cl;
    outR[o] = f2b(orr); outI[o] = f2b(oii);
  }
}

// ---------------- AFNO block-diagonal complex MLP + softshrink ----------------
__global__ __launch_bounds__(128) void k_afno_mlp(
    const u16* __restrict__ Zr, const u16* __restrict__ Zi,
    const float* __restrict__ w1, const float* __restrict__ b1,
    const float* __restrict__ w2, const float* __restrict__ b2,
    u16* __restrict__ Or, u16* __restrict__ Oi) {
  __shared__ float w1r[16][128], w1i[16][128];
  __shared__ float w2r[128][16], w2i[128][16];
  __shared__ float b1r[128], b1i[128];
  __shared__ float b2s[2][16];
  __shared__ float zr[16], zi[16];
  __shared__ float o1r[128], o1i[128];
  int tid = threadIdx.x;
  int n = blockIdx.x;
  for (int idx = tid; idx < 16 * 128; idx += 128) {
    int i = idx >> 7, o = idx & 127;
    w1r[i][o] = w1[((0 * 16 + n) * 16 + i) * 128 + o];
    w1i[i][o] = w1[((1 * 16 + n) * 16 + i) * 128 + o];
  }
  for (int idx = tid; idx < 128 * 16; idx += 128) {
    int j = idx >> 4, o = idx & 15;
    w2r[j][o] = w2[((0 * 16 + n) * 128 + j) * 16 + o];
    w2i[j][o] = w2[((1 * 16 + n) * 128 + j) * 16 + o];
  }
  b1r[tid] = b1[(0 * 16 + n) * 128 + tid];
  b1i[tid] = b1[(1 * 16 + n) * 128 + tid];
  if (tid < 16) {
    b2s[0][tid] = b2[(0 * 16 + n) * 16 + tid];
    b2s[1][tid] = b2[(1 * 16 + n) * 16 + tid];
  }
  int p0 = blockIdx.y * 128;
  for (int pp = 0; pp < 128; pp++) {
    size_t pos = (size_t)(p0 + pp);
    __syncthreads();
    if (tid < 16) zr[tid] = b2f(Zr[pos * Cch + n * 16 + tid]);
    else if (tid < 32) zi[tid - 16] = b2f(Zi[pos * Cch + n * 16 + (tid - 16)]);
    __syncthreads();
    float ar = b1r[tid], ai = b1i[tid];
    #pragma unroll
    for (int i = 0; i < 16; i++) {
      float xr = zr[i], xi = zi[i];
      float wr = w1r[i][tid], wi = w1i[i][tid];
      ar += xr * wr - xi * wi;
      ai += xi * wr + xr * wi;
    }
    ar = fmaxf(ar, 0.0f); ai = fmaxf(ai, 0.0f);
    o1r[tid] = ar; o1i[tid] = ai;
    __syncthreads();
    int o = tid >> 3, l = tid & 7;
    float cr = 0.f, ci = 0.f;
    #pragma unroll
    for (int jj = 0; jj < 16; jj++) {
      int j = l + (jj << 3);
      float pr = o1r[j], pi = o1i[j];
      float wr = w2r[j][o], wi = w2i[j][o];
      cr += pr * wr - pi * wi;
      ci += pi * wr + pr * wi;
    }
    cr += __shfl_xor(cr, 1); ci += __shfl_xor(ci, 1);
    cr += __shfl_xor(cr, 2); ci += __shfl_xor(ci, 2);
    cr += __shfl_xor(cr, 4); ci += __shfl_xor(ci, 4);
    if (l == 0) {
      cr += b2s[0][o]; ci += b2s[1][o];
      float vr = copysignf(fmaxf(fabsf(cr) - LAM, 0.0f), cr);
      float vi = copysignf(fmaxf(fabsf(ci) - LAM, 0.0f), ci);
      size_t off = pos * Cch + n * 16 + o;
      Or[off] = f2b(vr); Oi[off] = f2b(vi);
    }
  }
}

// ------- inverse rDFT over W + x(fp32) + ln1out(bf16) -> X1 (bf16) -----------
__global__ __launch_bounds__(256) void k_irfft_w(const u16* __restrict__ Ur,
                                                 const u16* __restrict__ Ui,
                                                 const float* __restrict__ x_in,
                                                 const u16* __restrict__ lnout,
                                                 u16* __restrict__ X1) {
  __shared__ u16 sr[65][64], si[65][64];
  __shared__ float ct[128], st[128];
  int tid = threadIdx.x;
  int bh = blockIdx.x;
  int c0 = blockIdx.y * 64;
  if (tid < 128) {
    float ang = TWO_PI * (float)tid / 128.0f;
    ct[tid] = cosf(ang); st[tid] = sinf(ang);
  }
  for (int idx = tid; idx < 65 * 64; idx += 256) {
    int k = idx >> 6, c = idx & 63;
    size_t o = ((size_t)bh * KW + k) * Cch + c0 + c;
    sr[k][c] = Ur[o]; si[k][c] = Ui[o];
  }
  __syncthreads();
  int cl = tid & 63, wq = tid >> 6;
  for (int w = wq * 32; w < wq * 32 + 32; w++) {
    float acc = b2f(sr[0][cl]);
    float nyq = b2f(sr[64][cl]);
    acc += (w & 1) ? -nyq : nyq;
    #pragma unroll 7
    for (int k = 1; k < 64; k++) {
      int j = (w * k) & 127;
      acc += 2.0f * (b2f(sr[k][cl]) * ct[j] - b2f(si[k][cl]) * st[j]);
    }
    acc *= (1.0f / 128.0f);
    size_t o = ((size_t)bh * Ww + w) * Cch + c0 + cl;
    X1[o] = f2b(x_in[o] + b2f(lnout[o]) + acc);
  }
}

// ------- GEMM: C[m,n] = act(A(bf16)[m,k]*Bw(fp32)[n,k] + bias[n]) (+resid) ---
// ACT: 0 none, 1 exact gelu. RT: 1 adds bf16 resid. OUTF: 0 bf16 out, 1 fp32.
template<int ACT, int RT, int OUTF>
__global__ __launch_bounds__(256) void k_gemm_bt(const u16* __restrict__ Ap,
                                                 const float* __restrict__ Bw,
                                                 const float* __restrict__ bias,
                                                 const u16* __restrict__ resid,
                                                 void* __restrict__ Cp,
                                                 int M, int N, int K) {
  __shared__ float As[16][68], Bs[16][68];
  int tid = threadIdx.x;
  int m0 = blockIdx.x * 64, n0 = blockIdx.y * 64;
  int lr = tid >> 2, lk = (tid & 3) * 4;
  int tm = tid >> 4, tn = tid & 15;
  float acc[4][4] = {};
  for (int k0 = 0; k0 < K; k0 += 16) {
    ushort4 a = *(const ushort4*)(Ap + (size_t)(m0 + lr) * K + k0 + lk);
    As[lk + 0][lr] = b2f(a.x); As[lk + 1][lr] = b2f(a.y);
    As[lk + 2][lr] = b2f(a.z); As[lk + 3][lr] = b2f(a.w);
    float4 bv = *(const float4*)(Bw + (size_t)(n0 + lr) * K + k0 + lk);
    Bs[lk + 0][lr] = bv.x; Bs[lk + 1][lr] = bv.y;
    Bs[lk + 2][lr] = bv.z; Bs[lk + 3][lr] = bv.w;
    __syncthreads();
    #pragma unroll
    for (int kk = 0; kk < 16; kk++) {
      float4 a4 = *(const float4*)&As[kk][tm * 4];
      float4 b4 = *(const float4*)&Bs[kk][tn * 4];
      float av[4] = {a4.x, a4.y, a4.z, a4.w};
      float bw2[4] = {b4.x, b4.y, b4.z, b4.w};
      #pragma unroll
      for (int i = 0; i < 4; i++)
        #pragma unroll
        for (int j = 0; j < 4; j++) acc[i][j] += av[i] * bw2[j];
    }
    __syncthreads();
  }
  #pragma unroll
  for (int i = 0; i < 4; i++) {
    int m = m0 + tm * 4 + i;
    #pragma unroll
    for (int j = 0; j < 4; j++) {
      int n = n0 + tn * 4 + j;
      float v = acc[i][j] + bias[n];
      if (ACT == 1) v = 0.5f * v * (1.0f + erff(v * 0.70710678118654752f));
      if (RT == 1) v += b2f(resid[(size_t)m * N + n]);
      if (OUTF) ((float*)Cp)[(size_t)m * N + n] = v;
      else ((u16*)Cp)[(size_t)m * N + n] = f2b(v);
    }
  }
}

// ---------------- per-head LN over DH=32, bf16 in-place ----------------------
__global__ __launch_bounds__(256) void k_lnhead(u16* __restrict__ X,
                                                const float* __restrict__ g,
                                                const float* __restrict__ bta) {
  int tid = threadIdx.x, lane = tid & 63;
  size_t token = (size_t)blockIdx.x * 4 + (tid >> 6);
  int c = lane * 4;
  ushort4 u = *(const ushort4*)(X + token * Cch + c);
  float v[4] = {b2f(u.x), b2f(u.y), b2f(u.z), b2f(u.w)};
  float s = v[0] + v[1] + v[2] + v[3];
  s += __shfl_xor(s, 1); s += __shfl_xor(s, 2); s += __shfl_xor(s, 4);
  float mu = s * (1.0f / 32.0f);
  float q = 0.f;
  #pragma unroll
  for (int j = 0; j < 4; j++) { float d = v[j] - mu; q += d * d; }
  q += __shfl_xor(q, 1); q += __shfl_xor(q, 2); q += __shfl_xor(q, 4);
  float rs = rsqrtf(q * (1.0f / 32.0f) + EPSN);
  ushort4 o;
  o.x = f2b((v[0] - mu) * rs * g[c + 0] + bta[c + 0]);
  o.y = f2b((v[1] - mu) * rs * g[c + 1] + bta[c + 1]);
  o.z = f2b((v[2] - mu) * rs * g[c + 2] + bta[c + 2]);
  o.w = f2b((v[3] - mu) * rs * g[c + 3] + bta[c + 3]);
  *(ushort4*)(X + token * Cch + c) = o;
}

// ---------------- kv partial sums over 16 chunks of 1024 tokens --------------
__global__ __launch_bounds__(256) void k_kv_partial(const u16* __restrict__ Kb,
                                                    const u16* __restrict__ Vb,
                                                    float* __restrict__ part) {
  __shared__ float kl[64][33], vl[64][33];
  int tid = threadIdx.x;
  int bh = blockIdx.x;               // b*8+h
  int b = bh >> 3, h = bh & 7;
  int n0 = blockIdx.y * 1024;
  int d = tid >> 3, eg = tid & 7;
  float acc[4] = {0.f, 0.f, 0.f, 0.f};
  for (int sub = 0; sub < 16; sub++) {
    __syncthreads();
    for (int idx = tid; idx < 64 * 32; idx += 256) {
      int nn = idx >> 5, c = idx & 31;
      size_t o = ((size_t)(b * 16384 + n0 + sub * 64 + nn)) * Cch + h * 32 + c;
      kl[nn][c] = b2f(Kb[o]); vl[nn][c] = b2f(Vb[o]);
    }
    __syncthreads();
    #pragma unroll 4
    for (int nn = 0; nn < 64; nn++) {
      float kd = kl[nn][d];
      #pragma unroll
      for (int j = 0; j < 4; j++) acc[j] += kd * vl[nn][eg * 4 + j];
    }
  }
  size_t base = ((size_t)bh * 16 + blockIdx.y) * 1024 + d * 32 + eg * 4;
  #pragma unroll
  for (int j = 0; j < 4; j++) part[base + j] = acc[j];
}

__global__ __launch_bounds__(1024) void k_kv_reduce(const float* __restrict__ part,
                                                    float* __restrict__ kv) {
  int bh = blockIdx.x, o = threadIdx.x;
  float s = 0.f;
  #pragma unroll
  for (int p = 0; p < 16; p++) s += part[((size_t)bh * 16 + p) * 1024 + o];
  kv[(size_t)bh * 1024 + o] = s * (1.0f / 16384.0f);
}

// ------- attn: ATT[b,n,h*32+e] = sum_d Q[b,n,h*32+d] * kv[b,h,d,e] -----------
__global__ __launch_bounds__(256) void k_attn(const u16* __restrict__ Q,
                                              const float* __restrict__ kv,
                                              u16* __restrict__ ATT) {
  __shared__ float kvl[8][32][32];
  __shared__ float qrow[256];
  int tid = threadIdx.x;
  int b = blockIdx.x;
  int t0 = blockIdx.y * 128;
  for (int idx = tid; idx < 8192; idx += 256)
    kvl[idx >> 10][(idx >> 5) & 31][idx & 31] = kv[(size_t)b * 8192 + idx];
  int h = tid >> 5, e = tid & 31;
  for (int t = 0; t < 128; t++) {
    __syncthreads();
    qrow[tid] = b2f(Q[((size_t)b * 16384 + t0 + t) * Cch + tid]);
    __syncthreads();
    float s = 0.f;
    #pragma unroll 8
    for (int d = 0; d < 32; d++) s += qrow[h * 32 + d] * kvl[h][d][e];
    ATT[((size_t)b * 16384 + t0 + t) * Cch + tid] = f2b(s);
  }
}

extern "C" void kernel_launch(void* const* d_in, const int* in_sizes, int n_in,
                              void* d_out, int out_size, void* d_ws, size_t ws_size,
                              hipStream_t stream) {
  (void)in_sizes; (void)n_in; (void)out_size; (void)ws_size;
  const float* x    = (const float*)d_in[0];
  const float* w1   = (const float*)d_in[1];
  const float* b1   = (const float*)d_in[2];
  const float* w2   = (const float*)d_in[3];
  const float* b2   = (const float*)d_in[4];
  const float* wq   = (const float*)d_in[5];
  const float* bq   = (const float*)d_in[6];
  const float* wk   = (const float*)d_in[7];
  const float* bk   = (const float*)d_in[8];
  const float* wv   = (const float*)d_in[9];
  const float* bv   = (const float*)d_in[10];
  const float* lnkg = (const float*)d_in[11];
  const float* lnkb = (const float*)d_in[12];
  const float* lnvg = (const float*)d_in[13];
  const float* lnvb = (const float*)d_in[14];
  const float* wo   = (const float*)d_in[15];
  const float* bo   = (const float*)d_in[16];
  const float* wup  = (const float*)d_in[17];
  const float* bup  = (const float*)d_in[18];
  const float* wdn  = (const float*)d_in[19];
  const float* bdn  = (const float*)d_in[20];
  const float* n1g  = (const float*)d_in[21];
  const float* n1b  = (const float*)d_in[22];
  const float* n2g  = (const float*)d_in[23];
  const float* n2b  = (const float*)d_in[24];
  const float* n3g  = (const float*)d_in[25];
  const float* n3b  = (const float*)d_in[26];

  // ---- workspace layout (bytes), total used < 49.6 MiB ----
  // R0 (A):    0 .. 16,777,216           ln outputs / residual (bf16)
  // R1:        16,777,216 .. 33,816,576  S1(r+i) -> X1 -> V -> Q -> X2
  // R2:        33,816,576 .. 50,855,936  S2(r+i) -> K -> ATT -> UP
  // KVp:       50,855,936 .. 51,904,512  fp32 [16][16][1024]
  // KVb:       51,904,512 .. 51,970,048  fp32 [16][1024]
  // slots:     51,970,048 .. +128        fp32 probe codes
  char* ws = (char*)d_ws;
  u16* A    = (u16*)(ws + 0);
  u16* S1r  = (u16*)(ws + 16777216);
  u16* S1i  = (u16*)(ws + 25296896);
  u16* S2r  = (u16*)(ws + 33816576);
  u16* S2i  = (u16*)(ws + 42336256);
  u16* X1   = (u16*)(ws + 16777216);   // over S1 (dead after dft_h inv)
  u16* Vb   = (u16*)(ws + 16777216);   // over X1 (dead after ln2)
  u16* Qb   = (u16*)(ws + 16777216);   // over V (dead after kv_partial)
  u16* X2   = (u16*)(ws + 16777216);   // over Q (dead after attn)
  u16* Kb   = (u16*)(ws + 33816576);   // over S2 (dead after irfft)
  u16* ATT  = (u16*)(ws + 33816576);   // over K (dead after kv_partial)
  u16* UP   = (u16*)(ws + 33816576);   // over ATT (dead after wo)
  float* KVp = (float*)(ws + 50855936);
  float* KVb = (float*)(ws + 51904512);
  float* slots = (float*)(ws + 51970048);
  float* outp = (float*)d_out;

  k_clear<<<1, 64, 0, stream>>>(slots);

  // ---- AFNO: x1 = x + ln1(x) + irfft2(shrink(mlp(rfft2(ln1(x))))) ----
  k_ln<1><<<8192, 256, 0, stream>>>((const void*)x, n1g, n1b, A);
  k_probe_b<1><<<1, 64, 0, stream>>>(A, 65536, 1000.0f, slots, 1);
  k_dft_w<<<dim3(256, 2), 256, 0, stream>>>(A, S1r, S1i);
  k_probe_b<1><<<1, 64, 0, stream>>>(S1r, 0, 2000.0f, slots, 2);
  k_dft_h<false, true><<<dim3(130, 4), 256, 0, stream>>>(S1r, S1i, S2r, S2i);
  k_probe_b<1><<<1, 64, 0, stream>>>(S2r, 0, 3000.0f, slots, 3);
  k_afno_mlp<<<dim3(16, 130), 128, 0, stream>>>(S2r, S2i, w1, b1, w2, b2, S1r, S1i);
  k_probe_b<0><<<1, 64, 0, stream>>>(S1r, 0, 4000.0f, slots, 4);
  k_dft_h<true, false><<<dim3(130, 4), 256, 0, stream>>>(S1r, S1i, S2r, S2i);
  k_probe_b<1><<<1, 64, 0, stream>>>(S2r, 0, 5000.0f, slots, 5);
  k_irfft_w<<<dim3(256, 4), 256, 0, stream>>>(S2r, S2i, x, A, X1);
  k_probe_b<1><<<1, 64, 0, stream>>>(X1, 65536, 6000.0f, slots, 6);

  // ---- Galerkin: x2 = ln2(x1) + wo(attn) ; residual = LN2 OUTPUT ----
  k_ln<0><<<8192, 256, 0, stream>>>((const void*)X1, n2g, n2b, A);
  k_probe_b<1><<<1, 64, 0, stream>>>(A, 65536, 7000.0f, slots, 7);
  k_gemm_bt<0, 0, 0><<<dim3(512, 4), 256, 0, stream>>>(A, wk, bk, nullptr, (void*)Kb, 32768, 256, 256);
  k_gemm_bt<0, 0, 0><<<dim3(512, 4), 256, 0, stream>>>(A, wv, bv, nullptr, (void*)Vb, 32768, 256, 256);
  k_probe_b<1><<<1, 64, 0, stream>>>(Kb, 65536, 8000.0f, slots, 8);
  k_lnhead<<<8192, 256, 0, stream>>>(Kb, lnkg, lnkb);
  k_lnhead<<<8192, 256, 0, stream>>>(Vb, lnvg, lnvb);
  k_probe_b<1><<<1, 64, 0, stream>>>(Kb, 65536, 9000.0f, slots, 9);
  k_kv_partial<<<dim3(16, 16), 256, 0, stream>>>(Kb, Vb, KVp);
  k_kv_reduce<<<16, 1024, 0, stream>>>(KVp, KVb);
  k_probe_f<<<1, 64, 0, stream>>>(KVb, 0, 10000.0f, slots, 10);
  k_gemm_bt<0, 0, 0><<<dim3(512, 4), 256, 0, stream>>>(A, wq, bq, nullptr, (void*)Qb, 32768, 256, 256);
  k_attn<<<dim3(2, 128), 256, 0, stream>>>(Qb, KVb, ATT);
  k_probe_b<1><<<1, 64, 0, stream>>>(ATT, 65536, 11000.0f, slots, 11);
  k_gemm_bt<0, 1, 0><<<dim3(512, 4), 256, 0, stream>>>(ATT, wo, bo, A, (void*)X2, 32768, 256, 256);
  k_probe_b<1><<<1, 64, 0, stream>>>(X2, 65536, 12000.0f, slots, 12);

  // ---- FFN: out = ln3(x2) + down(gelu(up(ln3))) ; residual = LN3 OUTPUT ----
  k_ln<0><<<8192, 256, 0, stream>>>((const void*)X2, n3g, n3b, A);
  k_probe_b<1><<<1, 64, 0, stream>>>(A, 65536, 13000.0f, slots, 13);
  for (int c = 0; c < 8; c++) {
    const u16* Ac = A + (size_t)c * 4096 * 256;
    k_gemm_bt<1, 0, 0><<<dim3(64, 32), 256, 0, stream>>>(Ac, wup, bup, nullptr, (void*)UP, 4096, 2048, 256);
    k_gemm_bt<0, 1, 1><<<dim3(64, 4), 256, 0, stream>>>(UP, wdn, bdn, Ac, (void*)(outp + (size_t)c * 4096 * 256), 4096, 256, 2048);
  }
  k_scrub_out<<<2048, 256, 0, stream>>>(outp, 32768 * 256, slots);
  k_emit<<<1, 64, 0, stream>>>(slots, outp);
}

// Round 6
// 2673.332 us; speedup vs baseline: 1.1956x; 1.1956x over previous
//
#include <hip/hip_runtime.h>

// InvariantBlock: AFNO spectral block + Galerkin linear attention + GELU FFN
// B=2 H=128 W=128 C=256; tokens 32768; KW=65; HEADS=8 DH=32; NB=16 BS=16 HID=128
// d_in / d_out FP32; intermediates bf16 in ws (<50 MiB). Accumulation fp32.
// R5->R6: k_afno_mlp rewritten as register-streaming (1 thread = 1 position),
// weights in LDS with uniform float4 broadcast reads; probes removed.

typedef unsigned short u16;
typedef unsigned int u32;
#define DEV __device__ __forceinline__

constexpr int Hh = 128, Ww = 128, Cch = 256, KW = 65;
constexpr float EPSN = 1e-5f, LAM = 0.01f;
constexpr float TWO_PI = 6.283185307179586f;

DEV float b2f(u16 u) { return __uint_as_float(((u32)u) << 16); }
DEV u16 f2b(float f) {
  u32 x = __float_as_uint(f);
  return (u16)((x + 0x7FFFu + ((x >> 16) & 1u)) >> 16);
}

// ---------------- LayerNorm over C=256; INF=1 fp32 input, else bf16 ----------
template<int INF>
__global__ __launch_bounds__(256) void k_ln(const void* __restrict__ in,
                                            const float* __restrict__ g,
                                            const float* __restrict__ bta,
                                            u16* __restrict__ out) {
  int tid = threadIdx.x, lane = tid & 63;
  size_t token = (size_t)blockIdx.x * 4 + (tid >> 6);
  int c = lane * 4;
  float v[4];
  if (INF) {
    float4 f = *(const float4*)((const float*)in + token * Cch + c);
    v[0] = f.x; v[1] = f.y; v[2] = f.z; v[3] = f.w;
  } else {
    ushort4 u = *(const ushort4*)((const u16*)in + token * Cch + c);
    v[0] = b2f(u.x); v[1] = b2f(u.y); v[2] = b2f(u.z); v[3] = b2f(u.w);
  }
  float s = v[0] + v[1] + v[2] + v[3];
  #pragma unroll
  for (int m = 1; m < 64; m <<= 1) s += __shfl_xor(s, m);
  float mu = s * (1.0f / 256.0f);
  float q = 0.f;
  #pragma unroll
  for (int j = 0; j < 4; j++) { float d = v[j] - mu; q += d * d; }
  #pragma unroll
  for (int m = 1; m < 64; m <<= 1) q += __shfl_xor(q, m);
  float rs = rsqrtf(q * (1.0f / 256.0f) + EPSN);
  ushort4 o;
  o.x = f2b((v[0] - mu) * rs * g[c + 0] + bta[c + 0]);
  o.y = f2b((v[1] - mu) * rs * g[c + 1] + bta[c + 1]);
  o.z = f2b((v[2] - mu) * rs * g[c + 2] + bta[c + 2]);
  o.w = f2b((v[3] - mu) * rs * g[c + 3] + bta[c + 3]);
  *(ushort4*)(out + token * Cch + c) = o;
}

// ---------------- forward rDFT over W: A[b,h,w,c] -> T[b,h,kw,c] --------------
__global__ __launch_bounds__(256) void k_dft_w(const u16* __restrict__ y,
                                               u16* __restrict__ Tr,
                                               u16* __restrict__ Ti) {
  __shared__ u16 ys[128][128];
  __shared__ float ct[128], st[128];
  int tid = threadIdx.x;
  int bh = blockIdx.x;
  int c0 = blockIdx.y * 128;
  if (tid < 128) {
    float ang = TWO_PI * (float)tid / 128.0f;
    ct[tid] = cosf(ang); st[tid] = sinf(ang);
  }
  const u16* yb = y + (size_t)bh * Ww * Cch + c0;
  for (int idx = tid; idx < 128 * 128; idx += 256) {
    int w = idx >> 7, c = idx & 127;
    ys[w][c] = yb[(size_t)w * Cch + c];
  }
  __syncthreads();
  int cl = tid & 127;
  int half = tid >> 7;
  int kws = half ? 33 : 0, kwe = half ? 65 : 33;
  for (int kw = kws; kw < kwe; kw++) {
    float ar = 0.f, ai = 0.f;
    #pragma unroll 8
    for (int w = 0; w < 128; w++) {
      int j = (w * kw) & 127;
      float a = b2f(ys[w][cl]);
      ar += a * ct[j];
      ai -= a * st[j];
    }
    size_t o = ((size_t)bh * KW + kw) * Cch + c0 + cl;
    Tr[o] = f2b(ar); Ti[o] = f2b(ai);
  }
}

// ------- complex DFT over H (fwd: e^-i, scale 1/128; inv: e^+i, no scale) ----
template<bool INV, bool SC>
__global__ __launch_bounds__(256) void k_dft_h(const u16* __restrict__ inR,
                                               const u16* __restrict__ inI,
                                               u16* __restrict__ outR,
                                               u16* __restrict__ outI) {
  __shared__ u16 sr[128][64], si[128][64];
  __shared__ float ct[128], st[128];
  int tid = threadIdx.x;
  int bk = blockIdx.x;
  int b = bk / KW, kw = bk % KW;
  int c0 = blockIdx.y * 64;
  if (tid < 128) {
    float ang = TWO_PI * (float)tid / 128.0f;
    ct[tid] = cosf(ang); st[tid] = sinf(ang);
  }
  for (int idx = tid; idx < 128 * 64; idx += 256) {
    int q = idx >> 6, c = idx & 63;
    size_t o = (((size_t)b * Hh + q) * KW + kw) * Cch + c0 + c;
    sr[q][c] = inR[o]; si[q][c] = inI[o];
  }
  __syncthreads();
  int cl = tid & 63, pq = tid >> 6;
  for (int p = pq * 32; p < pq * 32 + 32; p++) {
    float orr = 0.f, oii = 0.f;
    #pragma unroll 8
    for (int q = 0; q < 128; q++) {
      int j = (p * q) & 127;
      float ar = b2f(sr[q][cl]), ai = b2f(si[q][cl]);
      float cj = ct[j], sj = st[j];
      if (!INV) { orr += ar * cj + ai * sj; oii += ai * cj - ar * sj; }
      else      { orr += ar * cj - ai * sj; oii += ai * cj + ar * sj; }
    }
    if (SC) { orr *= (1.0f / 128.0f); oii *= (1.0f / 128.0f); }
    size_t o = (((size_t)b * Hh + p) * KW + kw) * Cch + c0 + cl;
    outR[o] = f2b(orr); outI[o] = f2b(oii);
  }
}

// ---------------- AFNO block-diagonal complex MLP + softshrink ----------------
// 1 thread = 1 position; z[16],acc[16] complex in regs; hidden dim streamed.
// LDS weights interleaved [o][2i+ri] so per-o reads are 8+8 uniform float4.
__global__ __launch_bounds__(256) void k_afno_mlp(
    const u16* __restrict__ Zr, const u16* __restrict__ Zi,
    const float* __restrict__ w1, const float* __restrict__ b1,
    const float* __restrict__ w2, const float* __restrict__ b2,
    u16* __restrict__ Or, u16* __restrict__ Oi) {
  __shared__ float w1s[128][32];   // [o][2i+ri]
  __shared__ float w2s[128][32];   // [o][2j+ri]
  __shared__ float b1s[128][2];
  __shared__ float b2s[16][2];
  int tid = threadIdx.x;
  int n = blockIdx.x;
  for (int idx = tid; idx < 16 * 128; idx += 256) {
    int i = idx >> 7, o = idx & 127;
    w1s[o][2 * i + 0] = w1[((0 * 16 + n) * 16 + i) * 128 + o];
    w1s[o][2 * i + 1] = w1[((1 * 16 + n) * 16 + i) * 128 + o];
  }
  for (int idx = tid; idx < 128 * 16; idx += 256) {
    int o = idx >> 4, j = idx & 15;
    w2s[o][2 * j + 0] = w2[((0 * 16 + n) * 128 + o) * 16 + j];
    w2s[o][2 * j + 1] = w2[((1 * 16 + n) * 128 + o) * 16 + j];
  }
  if (tid < 128) {
    b1s[tid][0] = b1[(0 * 16 + n) * 128 + tid];
    b1s[tid][1] = b1[(1 * 16 + n) * 128 + tid];
  } else if (tid < 144) {
    b2s[tid - 128][0] = b2[(0 * 16 + n) * 16 + (tid - 128)];
    b2s[tid - 128][1] = b2[(1 * 16 + n) * 16 + (tid - 128)];
  }
  __syncthreads();
  size_t pos = (size_t)blockIdx.y * 256 + tid;      // 65*256 = 16640 exact
  const u16* zrp = Zr + pos * Cch + n * 16;
  const u16* zip = Zi + pos * Cch + n * 16;
  float zr[16], zi[16];
  #pragma unroll
  for (int q = 0; q < 4; q++) {
    ushort4 ur = *(const ushort4*)(zrp + q * 4);
    ushort4 ui = *(const ushort4*)(zip + q * 4);
    zr[q * 4 + 0] = b2f(ur.x); zr[q * 4 + 1] = b2f(ur.y);
    zr[q * 4 + 2] = b2f(ur.z); zr[q * 4 + 3] = b2f(ur.w);
    zi[q * 4 + 0] = b2f(ui.x); zi[q * 4 + 1] = b2f(ui.y);
    zi[q * 4 + 2] = b2f(ui.z); zi[q * 4 + 3] = b2f(ui.w);
  }
  float cr[16], ci[16];
  #pragma unroll
  for (int j = 0; j < 16; j++) { cr[j] = b2s[j][0]; ci[j] = b2s[j][1]; }
  for (int o = 0; o < 128; o++) {
    float hr = b1s[o][0], hi = b1s[o][1];
    #pragma unroll
    for (int q = 0; q < 8; q++) {
      float4 w = *(const float4*)&w1s[o][q * 4];
      int i0 = q * 2, i1 = q * 2 + 1;
      hr += zr[i0] * w.x - zi[i0] * w.y;
      hi += zi[i0] * w.x + zr[i0] * w.y;
      hr += zr[i1] * w.z - zi[i1] * w.w;
      hi += zi[i1] * w.z + zr[i1] * w.w;
    }
    hr = fmaxf(hr, 0.0f); hi = fmaxf(hi, 0.0f);
    #pragma unroll
    for (int q = 0; q < 8; q++) {
      float4 w = *(const float4*)&w2s[o][q * 4];
      int j0 = q * 2, j1 = q * 2 + 1;
      cr[j0] += hr * w.x - hi * w.y;
      ci[j0] += hi * w.x + hr * w.y;
      cr[j1] += hr * w.z - hi * w.w;
      ci[j1] += hi * w.z + hr * w.w;
    }
  }
  u16* orp = Or + pos * Cch + n * 16;
  u16* oip = Oi + pos * Cch + n * 16;
  #pragma unroll
  for (int q = 0; q < 4; q++) {
    ushort4 ur, ui;
    u16* pr = &ur.x; u16* pi = &ui.x;
    #pragma unroll
    for (int t = 0; t < 4; t++) {
      int j = q * 4 + t;
      float vr = copysignf(fmaxf(fabsf(cr[j]) - LAM, 0.0f), cr[j]);
      float vi = copysignf(fmaxf(fabsf(ci[j]) - LAM, 0.0f), ci[j]);
      pr[t] = f2b(vr); pi[t] = f2b(vi);
    }
    *(ushort4*)(orp + q * 4) = ur;
    *(ushort4*)(oip + q * 4) = ui;
  }
}

// ------- inverse rDFT over W + x(fp32) + ln1out(bf16) -> X1 (bf16) -----------
__global__ __launch_bounds__(256) void k_irfft_w(const u16* __restrict__ Ur,
                                                 const u16* __restrict__ Ui,
                                                 const float* __restrict__ x_in,
                                                 const u16* __restrict__ lnout,
                                                 u16* __restrict__ X1) {
  __shared__ u16 sr[65][64], si[65][64];
  __shared__ float ct[128], st[128];
  int tid = threadIdx.x;
  int bh = blockIdx.x;
  int c0 = blockIdx.y * 64;
  if (tid < 128) {
    float ang = TWO_PI * (float)tid / 128.0f;
    ct[tid] = cosf(ang); st[tid] = sinf(ang);
  }
  for (int idx = tid; idx < 65 * 64; idx += 256) {
    int k = idx >> 6, c = idx & 63;
    size_t o = ((size_t)bh * KW + k) * Cch + c0 + c;
    sr[k][c] = Ur[o]; si[k][c] = Ui[o];
  }
  __syncthreads();
  int cl = tid & 63, wq = tid >> 6;
  for (int w = wq * 32; w < wq * 32 + 32; w++) {
    float acc = b2f(sr[0][cl]);
    float nyq = b2f(sr[64][cl]);
    acc += (w & 1) ? -nyq : nyq;
    #pragma unroll 7
    for (int k = 1; k < 64; k++) {
      int j = (w * k) & 127;
      acc += 2.0f * (b2f(sr[k][cl]) * ct[j] - b2f(si[k][cl]) * st[j]);
    }
    acc *= (1.0f / 128.0f);
    size_t o = ((size_t)bh * Ww + w) * Cch + c0 + cl;
    X1[o] = f2b(x_in[o] + b2f(lnout[o]) + acc);
  }
}

// ------- GEMM: C[m,n] = act(A(bf16)[m,k]*Bw(fp32)[n,k] + bias[n]) (+resid) ---
// ACT: 0 none, 1 exact gelu. RT: 1 adds bf16 resid. OUTF: 0 bf16 out, 1 fp32.
template<int ACT, int RT, int OUTF>
__global__ __launch_bounds__(256) void k_gemm_bt(const u16* __restrict__ Ap,
                                                 const float* __restrict__ Bw,
                                                 const float* __restrict__ bias,
                                                 const u16* __restrict__ resid,
                                                 void* __restrict__ Cp,
                                                 int M, int N, int K) {
  __shared__ float As[16][68], Bs[16][68];
  int tid = threadIdx.x;
  int m0 = blockIdx.x * 64, n0 = blockIdx.y * 64;
  int lr = tid >> 2, lk = (tid & 3) * 4;
  int tm = tid >> 4, tn = tid & 15;
  float acc[4][4] = {};
  for (int k0 = 0; k0 < K; k0 += 16) {
    ushort4 a = *(const ushort4*)(Ap + (size_t)(m0 + lr) * K + k0 + lk);
    As[lk + 0][lr] = b2f(a.x); As[lk + 1][lr] = b2f(a.y);
    As[lk + 2][lr] = b2f(a.z); As[lk + 3][lr] = b2f(a.w);
    float4 bv = *(const float4*)(Bw + (size_t)(n0 + lr) * K + k0 + lk);
    Bs[lk + 0][lr] = bv.x; Bs[lk + 1][lr] = bv.y;
    Bs[lk + 2][lr] = bv.z; Bs[lk + 3][lr] = bv.w;
    __syncthreads();
    #pragma unroll
    for (int kk = 0; kk < 16; kk++) {
      float4 a4 = *(const float4*)&As[kk][tm * 4];
      float4 b4 = *(const float4*)&Bs[kk][tn * 4];
      float av[4] = {a4.x, a4.y, a4.z, a4.w};
      float bw2[4] = {b4.x, b4.y, b4.z, b4.w};
      #pragma unroll
      for (int i = 0; i < 4; i++)
        #pragma unroll
        for (int j = 0; j < 4; j++) acc[i][j] += av[i] * bw2[j];
    }
    __syncthreads();
  }
  #pragma unroll
  for (int i = 0; i < 4; i++) {
    int m = m0 + tm * 4 + i;
    #pragma unroll
    for (int j = 0; j < 4; j++) {
      int n = n0 + tn * 4 + j;
      float v = acc[i][j] + bias[n];
      if (ACT == 1) v = 0.5f * v * (1.0f + erff(v * 0.70710678118654752f));
      if (RT == 1) v += b2f(resid[(size_t)m * N + n]);
      if (OUTF) ((float*)Cp)[(size_t)m * N + n] = v;
      else ((u16*)Cp)[(size_t)m * N + n] = f2b(v);
    }
  }
}

// ---------------- per-head LN over DH=32, bf16 in-place ----------------------
__global__ __launch_bounds__(256) void k_lnhead(u16* __restrict__ X,
                                                const float* __restrict__ g,
                                                const float* __restrict__ bta) {
  int tid = threadIdx.x, lane = tid & 63;
  size_t token = (size_t)blockIdx.x * 4 + (tid >> 6);
  int c = lane * 4;
  ushort4 u = *(const ushort4*)(X + token * Cch + c);
  float v[4] = {b2f(u.x), b2f(u.y), b2f(u.z), b2f(u.w)};
  float s = v[0] + v[1] + v[2] + v[3];
  s += __shfl_xor(s, 1); s += __shfl_xor(s, 2); s += __shfl_xor(s, 4);
  float mu = s * (1.0f / 32.0f);
  float q = 0.f;
  #pragma unroll
  for (int j = 0; j < 4; j++) { float d = v[j] - mu; q += d * d; }
  q += __shfl_xor(q, 1); q += __shfl_xor(q, 2); q += __shfl_xor(q, 4);
  float rs = rsqrtf(q * (1.0f / 32.0f) + EPSN);
  ushort4 o;
  o.x = f2b((v[0] - mu) * rs * g[c + 0] + bta[c + 0]);
  o.y = f2b((v[1] - mu) * rs * g[c + 1] + bta[c + 1]);
  o.z = f2b((v[2] - mu) * rs * g[c + 2] + bta[c + 2]);
  o.w = f2b((v[3] - mu) * rs * g[c + 3] + bta[c + 3]);
  *(ushort4*)(X + token * Cch + c) = o;
}

// ---------------- kv partial sums over 16 chunks of 1024 tokens --------------
__global__ __launch_bounds__(256) void k_kv_partial(const u16* __restrict__ Kb,
                                                    const u16* __restrict__ Vb,
                                                    float* __restrict__ part) {
  __shared__ float kl[64][33], vl[64][33];
  int tid = threadIdx.x;
  int bh = blockIdx.x;               // b*8+h
  int b = bh >> 3, h = bh & 7;
  int n0 = blockIdx.y * 1024;
  int d = tid >> 3, eg = tid & 7;
  float acc[4] = {0.f, 0.f, 0.f, 0.f};
  for (int sub = 0; sub < 16; sub++) {
    __syncthreads();
    for (int idx = tid; idx < 64 * 32; idx += 256) {
      int nn = idx >> 5, c = idx & 31;
      size_t o = ((size_t)(b * 16384 + n0 + sub * 64 + nn)) * Cch + h * 32 + c;
      kl[nn][c] = b2f(Kb[o]); vl[nn][c] = b2f(Vb[o]);
    }
    __syncthreads();
    #pragma unroll 4
    for (int nn = 0; nn < 64; nn++) {
      float kd = kl[nn][d];
      #pragma unroll
      for (int j = 0; j < 4; j++) acc[j] += kd * vl[nn][eg * 4 + j];
    }
  }
  size_t base = ((size_t)bh * 16 + blockIdx.y) * 1024 + d * 32 + eg * 4;
  #pragma unroll
  for (int j = 0; j < 4; j++) part[base + j] = acc[j];
}

__global__ __launch_bounds__(1024) void k_kv_reduce(const float* __restrict__ part,
                                                    float* __restrict__ kv) {
  int bh = blockIdx.x, o = threadIdx.x;
  float s = 0.f;
  #pragma unroll
  for (int p = 0; p < 16; p++) s += part[((size_t)bh * 16 + p) * 1024 + o];
  kv[(size_t)bh * 1024 + o] = s * (1.0f / 16384.0f);
}

// ------- attn: ATT[b,n,h*32+e] = sum_d Q[b,n,h*32+d] * kv[b,h,d,e] -----------
__global__ __launch_bounds__(256) void k_attn(const u16* __restrict__ Q,
                                              const float* __restrict__ kv,
                                              u16* __restrict__ ATT) {
  __shared__ float kvl[8][32][32];
  __shared__ float qrow[256];
  int tid = threadIdx.x;
  int b = blockIdx.x;
  int t0 = blockIdx.y * 128;
  for (int idx = tid; idx < 8192; idx += 256)
    kvl[idx >> 10][(idx >> 5) & 31][idx & 31] = kv[(size_t)b * 8192 + idx];
  int h = tid >> 5, e = tid & 31;
  for (int t = 0; t < 128; t++) {
    __syncthreads();
    qrow[tid] = b2f(Q[((size_t)b * 16384 + t0 + t) * Cch + tid]);
    __syncthreads();
    float s = 0.f;
    #pragma unroll 8
    for (int d = 0; d < 32; d++) s += qrow[h * 32 + d] * kvl[h][d][e];
    ATT[((size_t)b * 16384 + t0 + t) * Cch + tid] = f2b(s);
  }
}

extern "C" void kernel_launch(void* const* d_in, const int* in_sizes, int n_in,
                              void* d_out, int out_size, void* d_ws, size_t ws_size,
                              hipStream_t stream) {
  (void)in_sizes; (void)n_in; (void)out_size; (void)ws_size;
  const float* x    = (const float*)d_in[0];
  const float* w1   = (const float*)d_in[1];
  const float* b1   = (const float*)d_in[2];
  const float* w2   = (const float*)d_in[3];
  const float* b2   = (const float*)d_in[4];
  const float* wq   = (const float*)d_in[5];
  const float* bq   = (const float*)d_in[6];
  const float* wk   = (const float*)d_in[7];
  const float* bk   = (const float*)d_in[8];
  const float* wv   = (const float*)d_in[9];
  const float* bv   = (const float*)d_in[10];
  const float* lnkg = (const float*)d_in[11];
  const float* lnkb = (const float*)d_in[12];
  const float* lnvg = (const float*)d_in[13];
  const float* lnvb = (const float*)d_in[14];
  const float* wo   = (const float*)d_in[15];
  const float* bo   = (const float*)d_in[16];
  const float* wup  = (const float*)d_in[17];
  const float* bup  = (const float*)d_in[18];
  const float* wdn  = (const float*)d_in[19];
  const float* bdn  = (const float*)d_in[20];
  const float* n1g  = (const float*)d_in[21];
  const float* n1b  = (const float*)d_in[22];
  const float* n2g  = (const float*)d_in[23];
  const float* n2b  = (const float*)d_in[24];
  const float* n3g  = (const float*)d_in[25];
  const float* n3b  = (const float*)d_in[26];

  // ---- workspace layout (bytes), total used < 49.6 MiB ----
  char* ws = (char*)d_ws;
  u16* A    = (u16*)(ws + 0);
  u16* S1r  = (u16*)(ws + 16777216);
  u16* S1i  = (u16*)(ws + 25296896);
  u16* S2r  = (u16*)(ws + 33816576);
  u16* S2i  = (u16*)(ws + 42336256);
  u16* X1   = (u16*)(ws + 16777216);   // over S1 (dead after dft_h inv)
  u16* Vb   = (u16*)(ws + 16777216);   // over X1 (dead after ln2)
  u16* Qb   = (u16*)(ws + 16777216);   // over V (dead after kv_partial)
  u16* X2   = (u16*)(ws + 16777216);   // over Q (dead after attn)
  u16* Kb   = (u16*)(ws + 33816576);   // over S2 (dead after irfft)
  u16* ATT  = (u16*)(ws + 33816576);   // over K (dead after kv_partial)
  u16* UP   = (u16*)(ws + 33816576);   // over ATT (dead after wo)
  float* KVp = (float*)(ws + 50855936);
  float* KVb = (float*)(ws + 51904512);
  float* outp = (float*)d_out;

  // ---- AFNO: x1 = x + ln1(x) + irfft2(shrink(mlp(rfft2(ln1(x))))) ----
  k_ln<1><<<8192, 256, 0, stream>>>((const void*)x, n1g, n1b, A);
  k_dft_w<<<dim3(256, 2), 256, 0, stream>>>(A, S1r, S1i);
  k_dft_h<false, true><<<dim3(130, 4), 256, 0, stream>>>(S1r, S1i, S2r, S2i);
  k_afno_mlp<<<dim3(16, 65), 256, 0, stream>>>(S2r, S2i, w1, b1, w2, b2, S1r, S1i);
  k_dft_h<true, false><<<dim3(130, 4), 256, 0, stream>>>(S1r, S1i, S2r, S2i);
  k_irfft_w<<<dim3(256, 4), 256, 0, stream>>>(S2r, S2i, x, A, X1);

  // ---- Galerkin: x2 = ln2(x1) + wo(attn) ; residual = LN2 OUTPUT ----
  k_ln<0><<<8192, 256, 0, stream>>>((const void*)X1, n2g, n2b, A);
  k_gemm_bt<0, 0, 0><<<dim3(512, 4), 256, 0, stream>>>(A, wk, bk, nullptr, (void*)Kb, 32768, 256, 256);
  k_gemm_bt<0, 0, 0><<<dim3(512, 4), 256, 0, stream>>>(A, wv, bv, nullptr, (void*)Vb, 32768, 256, 256);
  k_lnhead<<<8192, 256, 0, stream>>>(Kb, lnkg, lnkb);
  k_lnhead<<<8192, 256, 0, stream>>>(Vb, lnvg, lnvb);
  k_kv_partial<<<dim3(16, 16), 256, 0, stream>>>(Kb, Vb, KVp);
  k_kv_reduce<<<16, 1024, 0, stream>>>(KVp, KVb);
  k_gemm_bt<0, 0, 0><<<dim3(512, 4), 256, 0, stream>>>(A, wq, bq, nullptr, (void*)Qb, 32768, 256, 256);
  k_attn<<<dim3(2, 128), 256, 0, stream>>>(Qb, KVb, ATT);
  k_gemm_bt<0, 1, 0><<<dim3(512, 4), 256, 0, stream>>>(ATT, wo, bo, A, (void*)X2, 32768, 256, 256);

  // ---- FFN: out = ln3(x2) + down(gelu(up(ln3))) ; residual = LN3 OUTPUT ----
  k_ln<0><<<8192, 256, 0, stream>>>((const void*)X2, n3g, n3b, A);
  for (int c = 0; c < 8; c++) {
    const u16* Ac = A + (size_t)c * 4096 * 256;
    k_gemm_bt<1, 0, 0><<<dim3(64, 32), 256, 0, stream>>>(Ac, wup, bup, nullptr, (void*)UP, 4096, 2048, 256);
    k_gemm_bt<0, 1, 1><<<dim3(64, 4), 256, 0, stream>>>(UP, wdn, bdn, Ac, (void*)(outp + (size_t)c * 4096 * 256), 4096, 256, 2048);
  }
}

// Round 8
// 1810.494 us; speedup vs baseline: 1.7654x; 1.4766x over previous
//
#include <hip/hip_runtime.h>

// InvariantBlock: AFNO spectral block + Galerkin linear attention + GELU FFN
// B=2 H=128 W=128 C=256; tokens 32768; KW=65; HEADS=8 DH=32; NB=16 BS=16 HID=128
// d_in / d_out FP32; intermediates bf16 in ws (<52 MiB). Accumulation fp32.
// R7->R8: k_mgemm staging fixed (each thread stores 2x u16x8 = full 128x32
// coverage; R7 covered only half the tile -> uninit LDS -> NaN).
// FFN now 8 chunks of 4096 rows; FFN bf16 weights in dead X2 window.

typedef unsigned short u16;
typedef unsigned int u32;
typedef __attribute__((ext_vector_type(8))) short bf16x8;
typedef __attribute__((ext_vector_type(8))) unsigned short u16x8;
typedef __attribute__((ext_vector_type(4))) float f32x4;
#define DEV __device__ __forceinline__

constexpr int Hh = 128, Ww = 128, Cch = 256, KW = 65;
constexpr float EPSN = 1e-5f, LAM = 0.01f;
constexpr float TWO_PI = 6.283185307179586f;

DEV float b2f(u16 u) { return __uint_as_float(((u32)u) << 16); }
DEV u16 f2b(float f) {
  u32 x = __float_as_uint(f);
  return (u16)((x + 0x7FFFu + ((x >> 16) & 1u)) >> 16);
}

// ---------------- fp32 -> bf16 weight convert --------------------------------
__global__ __launch_bounds__(256) void k_cvt(const float* __restrict__ src,
                                             u16* __restrict__ dst, int n) {
  int i = blockIdx.x * 256 + threadIdx.x;
  if (i < n) dst[i] = f2b(src[i]);
}

// ---------------- LayerNorm over C=256; INF=1 fp32 input, else bf16 ----------
template<int INF>
__global__ __launch_bounds__(256) void k_ln(const void* __restrict__ in,
                                            const float* __restrict__ g,
                                            const float* __restrict__ bta,
                                            u16* __restrict__ out) {
  int tid = threadIdx.x, lane = tid & 63;
  size_t token = (size_t)blockIdx.x * 4 + (tid >> 6);
  int c = lane * 4;
  float v[4];
  if (INF) {
    float4 f = *(const float4*)((const float*)in + token * Cch + c);
    v[0] = f.x; v[1] = f.y; v[2] = f.z; v[3] = f.w;
  } else {
    ushort4 u = *(const ushort4*)((const u16*)in + token * Cch + c);
    v[0] = b2f(u.x); v[1] = b2f(u.y); v[2] = b2f(u.z); v[3] = b2f(u.w);
  }
  float s = v[0] + v[1] + v[2] + v[3];
  #pragma unroll
  for (int m = 1; m < 64; m <<= 1) s += __shfl_xor(s, m);
  float mu = s * (1.0f / 256.0f);
  float q = 0.f;
  #pragma unroll
  for (int j = 0; j < 4; j++) { float d = v[j] - mu; q += d * d; }
  #pragma unroll
  for (int m = 1; m < 64; m <<= 1) q += __shfl_xor(q, m);
  float rs = rsqrtf(q * (1.0f / 256.0f) + EPSN);
  ushort4 o;
  o.x = f2b((v[0] - mu) * rs * g[c + 0] + bta[c + 0]);
  o.y = f2b((v[1] - mu) * rs * g[c + 1] + bta[c + 1]);
  o.z = f2b((v[2] - mu) * rs * g[c + 2] + bta[c + 2]);
  o.w = f2b((v[3] - mu) * rs * g[c + 3] + bta[c + 3]);
  *(ushort4*)(out + token * Cch + c) = o;
}

// ---------------- forward rDFT over W: A[b,h,w,c] -> T[b,h,kw,c] --------------
__global__ __launch_bounds__(256) void k_dft_w(const u16* __restrict__ y,
                                               u16* __restrict__ Tr,
                                               u16* __restrict__ Ti) {
  __shared__ u16 ys[128][128];
  __shared__ float ct[128], st[128];
  int tid = threadIdx.x;
  int bh = blockIdx.x;
  int c0 = blockIdx.y * 128;
  if (tid < 128) {
    float ang = TWO_PI * (float)tid / 128.0f;
    ct[tid] = cosf(ang); st[tid] = sinf(ang);
  }
  const u16* yb = y + (size_t)bh * Ww * Cch + c0;
  for (int idx = tid; idx < 128 * 128; idx += 256) {
    int w = idx >> 7, c = idx & 127;
    ys[w][c] = yb[(size_t)w * Cch + c];
  }
  __syncthreads();
  int cl = tid & 127;
  int half = tid >> 7;
  int kws = half ? 33 : 0, kwe = half ? 65 : 33;
  for (int kw = kws; kw < kwe; kw++) {
    float ar = 0.f, ai = 0.f;
    #pragma unroll 8
    for (int w = 0; w < 128; w++) {
      int j = (w * kw) & 127;
      float a = b2f(ys[w][cl]);
      ar += a * ct[j];
      ai -= a * st[j];
    }
    size_t o = ((size_t)bh * KW + kw) * Cch + c0 + cl;
    Tr[o] = f2b(ar); Ti[o] = f2b(ai);
  }
}

// ------- complex DFT over H (fwd: e^-i, scale 1/128; inv: e^+i, no scale) ----
template<bool INV, bool SC>
__global__ __launch_bounds__(256) void k_dft_h(const u16* __restrict__ inR,
                                               const u16* __restrict__ inI,
                                               u16* __restrict__ outR,
                                               u16* __restrict__ outI) {
  __shared__ u16 sr[128][64], si[128][64];
  __shared__ float ct[128], st[128];
  int tid = threadIdx.x;
  int bk = blockIdx.x;
  int b = bk / KW, kw = bk % KW;
  int c0 = blockIdx.y * 64;
  if (tid < 128) {
    float ang = TWO_PI * (float)tid / 128.0f;
    ct[tid] = cosf(ang); st[tid] = sinf(ang);
  }
  for (int idx = tid; idx < 128 * 64; idx += 256) {
    int q = idx >> 6, c = idx & 63;
    size_t o = (((size_t)b * Hh + q) * KW + kw) * Cch + c0 + c;
    sr[q][c] = inR[o]; si[q][c] = inI[o];
  }
  __syncthreads();
  int cl = tid & 63, pq = tid >> 6;
  for (int p = pq * 32; p < pq * 32 + 32; p++) {
    float orr = 0.f, oii = 0.f;
    #pragma unroll 8
    for (int q = 0; q < 128; q++) {
      int j = (p * q) & 127;
      float ar = b2f(sr[q][cl]), ai = b2f(si[q][cl]);
      float cj = ct[j], sj = st[j];
      if (!INV) { orr += ar * cj + ai * sj; oii += ai * cj - ar * sj; }
      else      { orr += ar * cj - ai * sj; oii += ai * cj + ar * sj; }
    }
    if (SC) { orr *= (1.0f / 128.0f); oii *= (1.0f / 128.0f); }
    size_t o = (((size_t)b * Hh + p) * KW + kw) * Cch + c0 + cl;
    outR[o] = f2b(orr); outI[o] = f2b(oii);
  }
}

// ---------------- AFNO block-diagonal complex MLP + softshrink ----------------
__global__ __launch_bounds__(256) void k_afno_mlp(
    const u16* __restrict__ Zr, const u16* __restrict__ Zi,
    const float* __restrict__ w1, const float* __restrict__ b1,
    const float* __restrict__ w2, const float* __restrict__ b2,
    u16* __restrict__ Or, u16* __restrict__ Oi) {
  __shared__ float w1s[128][32];   // [o][2i+ri]
  __shared__ float w2s[128][32];   // [o][2j+ri]
  __shared__ float b1s[128][2];
  __shared__ float b2s[16][2];
  int tid = threadIdx.x;
  int n = blockIdx.x;
  for (int idx = tid; idx < 16 * 128; idx += 256) {
    int i = idx >> 7, o = idx & 127;
    w1s[o][2 * i + 0] = w1[((0 * 16 + n) * 16 + i) * 128 + o];
    w1s[o][2 * i + 1] = w1[((1 * 16 + n) * 16 + i) * 128 + o];
  }
  for (int idx = tid; idx < 128 * 16; idx += 256) {
    int o = idx >> 4, j = idx & 15;
    w2s[o][2 * j + 0] = w2[((0 * 16 + n) * 128 + o) * 16 + j];
    w2s[o][2 * j + 1] = w2[((1 * 16 + n) * 128 + o) * 16 + j];
  }
  if (tid < 128) {
    b1s[tid][0] = b1[(0 * 16 + n) * 128 + tid];
    b1s[tid][1] = b1[(1 * 16 + n) * 128 + tid];
  } else if (tid < 144) {
    b2s[tid - 128][0] = b2[(0 * 16 + n) * 16 + (tid - 128)];
    b2s[tid - 128][1] = b2[(1 * 16 + n) * 16 + (tid - 128)];
  }
  __syncthreads();
  size_t pos = (size_t)blockIdx.y * 256 + tid;
  const u16* zrp = Zr + pos * Cch + n * 16;
  const u16* zip = Zi + pos * Cch + n * 16;
  float zr[16], zi[16];
  #pragma unroll
  for (int q = 0; q < 4; q++) {
    ushort4 ur = *(const ushort4*)(zrp + q * 4);
    ushort4 ui = *(const ushort4*)(zip + q * 4);
    zr[q * 4 + 0] = b2f(ur.x); zr[q * 4 + 1] = b2f(ur.y);
    zr[q * 4 + 2] = b2f(ur.z); zr[q * 4 + 3] = b2f(ur.w);
    zi[q * 4 + 0] = b2f(ui.x); zi[q * 4 + 1] = b2f(ui.y);
    zi[q * 4 + 2] = b2f(ui.z); zi[q * 4 + 3] = b2f(ui.w);
  }
  float cr[16], ci[16];
  #pragma unroll
  for (int j = 0; j < 16; j++) { cr[j] = b2s[j][0]; ci[j] = b2s[j][1]; }
  for (int o = 0; o < 128; o++) {
    float hr = b1s[o][0], hi = b1s[o][1];
    #pragma unroll
    for (int q = 0; q < 8; q++) {
      float4 w = *(const float4*)&w1s[o][q * 4];
      int i0 = q * 2, i1 = q * 2 + 1;
      hr += zr[i0] * w.x - zi[i0] * w.y;
      hi += zi[i0] * w.x + zr[i0] * w.y;
      hr += zr[i1] * w.z - zi[i1] * w.w;
      hi += zi[i1] * w.z + zr[i1] * w.w;
    }
    hr = fmaxf(hr, 0.0f); hi = fmaxf(hi, 0.0f);
    #pragma unroll
    for (int q = 0; q < 8; q++) {
      float4 w = *(const float4*)&w2s[o][q * 4];
      int j0 = q * 2, j1 = q * 2 + 1;
      cr[j0] += hr * w.x - hi * w.y;
      ci[j0] += hi * w.x + hr * w.y;
      cr[j1] += hr * w.z - hi * w.w;
      ci[j1] += hi * w.z + hr * w.w;
    }
  }
  u16* orp = Or + pos * Cch + n * 16;
  u16* oip = Oi + pos * Cch + n * 16;
  #pragma unroll
  for (int q = 0; q < 4; q++) {
    ushort4 ur, ui;
    u16* pr = &ur.x; u16* pi = &ui.x;
    #pragma unroll
    for (int t = 0; t < 4; t++) {
      int j = q * 4 + t;
      float vr = copysignf(fmaxf(fabsf(cr[j]) - LAM, 0.0f), cr[j]);
      float vi = copysignf(fmaxf(fabsf(ci[j]) - LAM, 0.0f), ci[j]);
      pr[t] = f2b(vr); pi[t] = f2b(vi);
    }
    *(ushort4*)(orp + q * 4) = ur;
    *(ushort4*)(oip + q * 4) = ui;
  }
}

// ------- inverse rDFT over W + x(fp32) + ln1out(bf16) -> X1 (bf16) -----------
__global__ __launch_bounds__(256) void k_irfft_w(const u16* __restrict__ Ur,
                                                 const u16* __restrict__ Ui,
                                                 const float* __restrict__ x_in,
                                                 const u16* __restrict__ lnout,
                                                 u16* __restrict__ X1) {
  __shared__ u16 sr[65][64], si[65][64];
  __shared__ float ct[128], st[128];
  int tid = threadIdx.x;
  int bh = blockIdx.x;
  int c0 = blockIdx.y * 64;
  if (tid < 128) {
    float ang = TWO_PI * (float)tid / 128.0f;
    ct[tid] = cosf(ang); st[tid] = sinf(ang);
  }
  for (int idx = tid; idx < 65 * 64; idx += 256) {
    int k = idx >> 6, c = idx & 63;
    size_t o = ((size_t)bh * KW + k) * Cch + c0 + c;
    sr[k][c] = Ur[o]; si[k][c] = Ui[o];
  }
  __syncthreads();
  int cl = tid & 63, wq = tid >> 6;
  for (int w = wq * 32; w < wq * 32 + 32; w++) {
    float acc = b2f(sr[0][cl]);
    float nyq = b2f(sr[64][cl]);
    acc += (w & 1) ? -nyq : nyq;
    #pragma unroll 7
    for (int k = 1; k < 64; k++) {
      int j = (w * k) & 127;
      acc += 2.0f * (b2f(sr[k][cl]) * ct[j] - b2f(si[k][cl]) * st[j]);
    }
    acc *= (1.0f / 128.0f);
    size_t o = ((size_t)bh * Ww + w) * Cch + c0 + cl;
    X1[o] = f2b(x_in[o] + b2f(lnout[o]) + acc);
  }
}

// ------- MFMA GEMM: C[m,n] = act(A[m,k]*B[n,k] + bias[n]) (+resid) -----------
// A,B bf16; acc fp32. 128x128 tile, 4 waves (64x64 each), BK=32.
// ACT: 1 gelu. RT: 1 add bf16 resid. OUTF: 1 fp32 out else bf16.
template<int ACT, int RT, int OUTF>
__global__ __launch_bounds__(256) void k_mgemm(const u16* __restrict__ Ap,
                                               const u16* __restrict__ Bp,
                                               const float* __restrict__ bias,
                                               const u16* __restrict__ resid,
                                               void* __restrict__ Cp,
                                               int M, int N, int K) {
  __shared__ u16 As[128][40];   // 80B stride: 2-way bank alias (free)
  __shared__ u16 Bs[128][40];
  int tid = threadIdx.x;
  int lane = tid & 63, w = tid >> 6;
  int wm = w >> 1, wn = w & 1;
  int m0 = blockIdx.x * 128, n0 = blockIdx.y * 128;
  int srow = tid >> 1, sseg = tid & 1;   // 2 threads/row, 16 u16 each
  const u16* ag = Ap + (size_t)(m0 + srow) * K + sseg * 16;
  const u16* bg = Bp + (size_t)(n0 + srow) * K + sseg * 16;
  int rl = lane & 15, kq = (lane >> 4) * 8;
  f32x4 acc[4][4] = {};
  for (int k0 = 0; k0 < K; k0 += 32) {
    __syncthreads();
    *(u16x8*)&As[srow][sseg * 16]     = *(const u16x8*)(ag + k0);
    *(u16x8*)&As[srow][sseg * 16 + 8] = *(const u16x8*)(ag + k0 + 8);
    *(u16x8*)&Bs[srow][sseg * 16]     = *(const u16x8*)(bg + k0);
    *(u16x8*)&Bs[srow][sseg * 16 + 8] = *(const u16x8*)(bg + k0 + 8);
    __syncthreads();
    bf16x8 af[4], bf[4];
    #pragma unroll
    for (int i = 0; i < 4; i++) {
      af[i] = *(const bf16x8*)&As[wm * 64 + i * 16 + rl][kq];
      bf[i] = *(const bf16x8*)&Bs[wn * 64 + i * 16 + rl][kq];
    }
    #pragma unroll
    for (int i = 0; i < 4; i++)
      #pragma unroll
      for (int j = 0; j < 4; j++)
        acc[i][j] = __builtin_amdgcn_mfma_f32_16x16x32_bf16(af[i], bf[j], acc[i][j], 0, 0, 0);
  }
  int rq = lane >> 4;
  #pragma unroll
  for (int i = 0; i < 4; i++) {
    #pragma unroll
    for (int j = 0; j < 4; j++) {
      #pragma unroll
      for (int r = 0; r < 4; r++) {
        int m = m0 + wm * 64 + i * 16 + rq * 4 + r;
        int n = n0 + wn * 64 + j * 16 + rl;
        float v = acc[i][j][r] + bias[n];
        if (ACT) v = 0.5f * v * (1.0f + erff(v * 0.70710678118654752f));
        if (RT) v += b2f(resid[(size_t)m * N + n]);
        if (OUTF) ((float*)Cp)[(size_t)m * N + n] = v;
        else ((u16*)Cp)[(size_t)m * N + n] = f2b(v);
      }
    }
  }
}

// ---------------- per-head LN over DH=32, bf16 in-place ----------------------
__global__ __launch_bounds__(256) void k_lnhead(u16* __restrict__ X,
                                                const float* __restrict__ g,
                                                const float* __restrict__ bta) {
  int tid = threadIdx.x, lane = tid & 63;
  size_t token = (size_t)blockIdx.x * 4 + (tid >> 6);
  int c = lane * 4;
  ushort4 u = *(const ushort4*)(X + token * Cch + c);
  float v[4] = {b2f(u.x), b2f(u.y), b2f(u.z), b2f(u.w)};
  float s = v[0] + v[1] + v[2] + v[3];
  s += __shfl_xor(s, 1); s += __shfl_xor(s, 2); s += __shfl_xor(s, 4);
  float mu = s * (1.0f / 32.0f);
  float q = 0.f;
  #pragma unroll
  for (int j = 0; j < 4; j++) { float d = v[j] - mu; q += d * d; }
  q += __shfl_xor(q, 1); q += __shfl_xor(q, 2); q += __shfl_xor(q, 4);
  float rs = rsqrtf(q * (1.0f / 32.0f) + EPSN);
  ushort4 o;
  o.x = f2b((v[0] - mu) * rs * g[c + 0] + bta[c + 0]);
  o.y = f2b((v[1] - mu) * rs * g[c + 1] + bta[c + 1]);
  o.z = f2b((v[2] - mu) * rs * g[c + 2] + bta[c + 2]);
  o.w = f2b((v[3] - mu) * rs * g[c + 3] + bta[c + 3]);
  *(ushort4*)(X + token * Cch + c) = o;
}

// ---------------- kv partial sums over 16 chunks of 1024 tokens --------------
__global__ __launch_bounds__(256) void k_kv_partial(const u16* __restrict__ Kb,
                                                    const u16* __restrict__ Vb,
                                                    float* __restrict__ part) {
  __shared__ float kl[64][33], vl[64][33];
  int tid = threadIdx.x;
  int bh = blockIdx.x;               // b*8+h
  int b = bh >> 3, h = bh & 7;
  int n0 = blockIdx.y * 1024;
  int d = tid >> 3, eg = tid & 7;
  float acc[4] = {0.f, 0.f, 0.f, 0.f};
  for (int sub = 0; sub < 16; sub++) {
    __syncthreads();
    for (int idx = tid; idx < 64 * 32; idx += 256) {
      int nn = idx >> 5, c = idx & 31;
      size_t o = ((size_t)(b * 16384 + n0 + sub * 64 + nn)) * Cch + h * 32 + c;
      kl[nn][c] = b2f(Kb[o]); vl[nn][c] = b2f(Vb[o]);
    }
    __syncthreads();
    #pragma unroll 4
    for (int nn = 0; nn < 64; nn++) {
      float kd = kl[nn][d];
      #pragma unroll
      for (int j = 0; j < 4; j++) acc[j] += kd * vl[nn][eg * 4 + j];
    }
  }
  size_t base = ((size_t)bh * 16 + blockIdx.y) * 1024 + d * 32 + eg * 4;
  #pragma unroll
  for (int j = 0; j < 4; j++) part[base + j] = acc[j];
}

__global__ __launch_bounds__(1024) void k_kv_reduce(const float* __restrict__ part,
                                                    float* __restrict__ kv) {
  int bh = blockIdx.x, o = threadIdx.x;
  float s = 0.f;
  #pragma unroll
  for (int p = 0; p < 16; p++) s += part[((size_t)bh * 16 + p) * 1024 + o];
  kv[(size_t)bh * 1024 + o] = s * (1.0f / 16384.0f);
}

// ------- attn: ATT[b,n,h*32+e] = sum_d Q[b,n,h*32+d] * kv[b,h,d,e] -----------
__global__ __launch_bounds__(256) void k_attn(const u16* __restrict__ Q,
                                              const float* __restrict__ kv,
                                              u16* __restrict__ ATT) {
  __shared__ float kvl[8][32][32];
  __shared__ float qrow[256];
  int tid = threadIdx.x;
  int b = blockIdx.x;
  int t0 = blockIdx.y * 128;
  for (int idx = tid; idx < 8192; idx += 256)
    kvl[idx >> 10][(idx >> 5) & 31][idx & 31] = kv[(size_t)b * 8192 + idx];
  int h = tid >> 5, e = tid & 31;
  for (int t = 0; t < 128; t++) {
    __syncthreads();
    qrow[tid] = b2f(Q[((size_t)b * 16384 + t0 + t) * Cch + tid]);
    __syncthreads();
    float s = 0.f;
    #pragma unroll 8
    for (int d = 0; d < 32; d++) s += qrow[h * 32 + d] * kvl[h][d][e];
    ATT[((size_t)b * 16384 + t0 + t) * Cch + tid] = f2b(s);
  }
}

extern "C" void kernel_launch(void* const* d_in, const int* in_sizes, int n_in,
                              void* d_out, int out_size, void* d_ws, size_t ws_size,
                              hipStream_t stream) {
  (void)in_sizes; (void)n_in; (void)out_size; (void)ws_size;
  const float* x    = (const float*)d_in[0];
  const float* w1   = (const float*)d_in[1];
  const float* b1   = (const float*)d_in[2];
  const float* w2   = (const float*)d_in[3];
  const float* b2   = (const float*)d_in[4];
  const float* wq   = (const float*)d_in[5];
  const float* bq   = (const float*)d_in[6];
  const float* wk   = (const float*)d_in[7];
  const float* bk   = (const float*)d_in[8];
  const float* wv   = (const float*)d_in[9];
  const float* bv   = (const float*)d_in[10];
  const float* lnkg = (const float*)d_in[11];
  const float* lnkb = (const float*)d_in[12];
  const float* lnvg = (const float*)d_in[13];
  const float* lnvb = (const float*)d_in[14];
  const float* wo   = (const float*)d_in[15];
  const float* bo   = (const float*)d_in[16];
  const float* wup  = (const float*)d_in[17];
  const float* bup  = (const float*)d_in[18];
  const float* wdn  = (const float*)d_in[19];
  const float* bdn  = (const float*)d_in[20];
  const float* n1g  = (const float*)d_in[21];
  const float* n1b  = (const float*)d_in[22];
  const float* n2g  = (const float*)d_in[23];
  const float* n2b  = (const float*)d_in[24];
  const float* n3g  = (const float*)d_in[25];
  const float* n3b  = (const float*)d_in[26];

  // ---- workspace layout (bytes), max used 51,970,048 ----
  // R0: 0..16,777,216             A (ln outputs / residual)
  // R1: 16,777,216..33,816,576    S1(r+i) | X1 | V | Q | X2 ; slack 33,554,432+
  // R2: 33,816,576..50,855,936    S2(r+i) | K | ATT | UP(4096-row chunks)
  // KVp: 50,855,936..51,904,512 ; KVb: ..51,970,048
  // wq_b/wk_b in R1 slack (33,554,432 / 33,685,504), live during QKV GEMMs.
  // wv_b/wo_b in S2i tail (50,593,792 / 50,724,864), dead before ATT reaches
  //   only 50,593,792 (ATT ends exactly there).
  // wup_b/wdn_b in dead X2 region (16,777,216 / 17,825,792), cvt after ln3.
  char* ws = (char*)d_ws;
  u16* A    = (u16*)(ws + 0);
  u16* S1r  = (u16*)(ws + 16777216);
  u16* S1i  = (u16*)(ws + 25296896);
  u16* S2r  = (u16*)(ws + 33816576);
  u16* S2i  = (u16*)(ws + 42336256);
  u16* X1   = (u16*)(ws + 16777216);
  u16* Vb   = (u16*)(ws + 16777216);
  u16* Qb   = (u16*)(ws + 16777216);
  u16* X2   = (u16*)(ws + 16777216);
  u16* Kb   = (u16*)(ws + 33816576);
  u16* ATT  = (u16*)(ws + 33816576);
  u16* UP   = (u16*)(ws + 33816576);
  u16* wq_b = (u16*)(ws + 33554432);
  u16* wk_b = (u16*)(ws + 33685504);
  u16* wv_b = (u16*)(ws + 50593792);
  u16* wo_b = (u16*)(ws + 50724864);
  u16* wup_b = (u16*)(ws + 16777216);
  u16* wdn_b = (u16*)(ws + 17825792);
  float* KVp = (float*)(ws + 50855936);
  float* KVb = (float*)(ws + 51904512);
  float* outp = (float*)d_out;

  // ---- AFNO: x1 = x + ln1(x) + irfft2(shrink(mlp(rfft2(ln1(x))))) ----
  k_ln<1><<<8192, 256, 0, stream>>>((const void*)x, n1g, n1b, A);
  k_dft_w<<<dim3(256, 2), 256, 0, stream>>>(A, S1r, S1i);
  k_dft_h<false, true><<<dim3(130, 4), 256, 0, stream>>>(S1r, S1i, S2r, S2i);
  k_afno_mlp<<<dim3(16, 65), 256, 0, stream>>>(S2r, S2i, w1, b1, w2, b2, S1r, S1i);
  k_dft_h<true, false><<<dim3(130, 4), 256, 0, stream>>>(S1r, S1i, S2r, S2i);
  k_irfft_w<<<dim3(256, 4), 256, 0, stream>>>(S2r, S2i, x, A, X1);

  // ---- convert QKV/O weights to bf16 (dead S1i/S2i slack) ----
  k_cvt<<<256, 256, 0, stream>>>(wq, wq_b, 65536);
  k_cvt<<<256, 256, 0, stream>>>(wk, wk_b, 65536);
  k_cvt<<<256, 256, 0, stream>>>(wv, wv_b, 65536);
  k_cvt<<<256, 256, 0, stream>>>(wo, wo_b, 65536);

  // ---- Galerkin: x2 = ln2(x1) + wo(attn) ; residual = LN2 OUTPUT ----
  k_ln<0><<<8192, 256, 0, stream>>>((const void*)X1, n2g, n2b, A);
  k_mgemm<0, 0, 0><<<dim3(256, 2), 256, 0, stream>>>(A, wk_b, bk, nullptr, (void*)Kb, 32768, 256, 256);
  k_mgemm<0, 0, 0><<<dim3(256, 2), 256, 0, stream>>>(A, wv_b, bv, nullptr, (void*)Vb, 32768, 256, 256);
  k_lnhead<<<8192, 256, 0, stream>>>(Kb, lnkg, lnkb);
  k_lnhead<<<8192, 256, 0, stream>>>(Vb, lnvg, lnvb);
  k_kv_partial<<<dim3(16, 16), 256, 0, stream>>>(Kb, Vb, KVp);
  k_kv_reduce<<<16, 1024, 0, stream>>>(KVp, KVb);
  k_mgemm<0, 0, 0><<<dim3(256, 2), 256, 0, stream>>>(A, wq_b, bq, nullptr, (void*)Qb, 32768, 256, 256);
  k_attn<<<dim3(2, 128), 256, 0, stream>>>(Qb, KVb, ATT);
  k_mgemm<0, 1, 0><<<dim3(256, 2), 256, 0, stream>>>(ATT, wo_b, bo, A, (void*)X2, 32768, 256, 256);

  // ---- FFN: out = ln3(x2) + down(gelu(up(ln3))) ; residual = LN3 OUTPUT ----
  k_ln<0><<<8192, 256, 0, stream>>>((const void*)X2, n3g, n3b, A);
  // X2 dead now; convert FFN weights into its window
  k_cvt<<<2048, 256, 0, stream>>>(wup, wup_b, 524288);
  k_cvt<<<2048, 256, 0, stream>>>(wdn, wdn_b, 524288);
  for (int c = 0; c < 8; c++) {
    const u16* Ac = A + (size_t)c * 4096 * 256;
    k_mgemm<1, 0, 0><<<dim3(32, 16), 256, 0, stream>>>(Ac, wup_b, bup, nullptr, (void*)UP, 4096, 2048, 256);
    k_mgemm<0, 1, 1><<<dim3(32, 2), 256, 0, stream>>>(UP, wdn_b, bdn, Ac, (void*)(outp + (size_t)c * 4096 * 256), 4096, 256, 2048);
  }
}

// Round 9
// 1161.909 us; speedup vs baseline: 2.7509x; 1.5582x over previous
//
#include <hip/hip_runtime.h>

// InvariantBlock: AFNO spectral block + Galerkin linear attention + GELU FFN
// B=2 H=128 W=128 C=256; tokens 32768; KW=65; HEADS=8 DH=32; NB=16 BS=16 HID=128
// d_in / d_out FP32; intermediates bf16 in ws. Accumulation fp32.
// R8->R9: DFT chain (dft_w, dft_h fwd/inv, irfft_w) -> MFMA with hi/lo-split
// bf16 twiddle matrices (fp32-accurate). Twiddles live in the dead-KVp window.

typedef unsigned short u16;
typedef unsigned int u32;
typedef __attribute__((ext_vector_type(8))) short bf16x8;
typedef __attribute__((ext_vector_type(8))) unsigned short u16x8;
typedef __attribute__((ext_vector_type(4))) float f32x4;
#define DEV __device__ __forceinline__

constexpr int Cch = 256;
constexpr float EPSN = 1e-5f, LAM = 0.01f;
constexpr float TWO_PI = 6.283185307179586f;

DEV float b2f(u16 u) { return __uint_as_float(((u32)u) << 16); }
DEV u16 f2b(float f) {
  u32 x = __float_as_uint(f);
  return (u16)((x + 0x7FFFu + ((x >> 16) & 1u)) >> 16);
}

// ---------------- twiddle matrices (hi/lo split bf16) ------------------------
// tw layout (u16 elems): m*16384 for m=0..11: [Cf,Sf,Snf,Cu,Su,Snu] x {hi,lo}
// (f = scaled 1/128). Then Wm_hi at 196608, Wm_lo at 217088 ([128][160]).
DEV void put2(u16* tw, int m, int idx, float v) {
  u16 hi = f2b(v);
  tw[m * 16384 + idx] = hi;
  tw[(m + 1) * 16384 + idx] = f2b(v - b2f(hi));
}

__global__ __launch_bounds__(128) void k_twid(u16* __restrict__ tw) {
  int p = blockIdx.x, q = threadIdx.x;
  int idx = p * 128 + q;
  float ang = TWO_PI * (float)((p * q) & 127) * (1.0f / 128.0f);
  float c = cosf(ang), s = sinf(ang);
  put2(tw, 0, idx, c * (1.0f / 128.0f));
  put2(tw, 2, idx, s * (1.0f / 128.0f));
  put2(tw, 4, idx, -s * (1.0f / 128.0f));
  put2(tw, 6, idx, c);
  put2(tw, 8, idx, s);
  put2(tw, 10, idx, -s);
  u16* wmh = tw + 196608;
  u16* wml = tw + 217088;
  for (int k = q; k < 160; k += 128) {
    float v = 0.0f;
    if (k < 65) {
      float sc = (k == 0 || k == 64) ? 1.0f : 2.0f;
      v = sc * cosf(TWO_PI * (float)((p * k) & 127) * (1.0f / 128.0f)) * (1.0f / 128.0f);
    } else if (k < 130) {
      int kk = k - 65;
      float sc = (kk == 0 || kk == 64) ? 1.0f : 2.0f;
      v = -sc * sinf(TWO_PI * (float)((p * kk) & 127) * (1.0f / 128.0f)) * (1.0f / 128.0f);
    }
    u16 hi = f2b(v);
    wmh[p * 160 + k] = hi;
    wml[p * 160 + k] = f2b(v - b2f(hi));
  }
}

// ---------------- fp32 -> bf16 weight convert --------------------------------
__global__ __launch_bounds__(256) void k_cvt(const float* __restrict__ src,
                                             u16* __restrict__ dst, int n) {
  int i = blockIdx.x * 256 + threadIdx.x;
  if (i < n) dst[i] = f2b(src[i]);
}

// ---------------- LayerNorm over C=256; INF=1 fp32 input, else bf16 ----------
template<int INF>
__global__ __launch_bounds__(256) void k_ln(const void* __restrict__ in,
                                            const float* __restrict__ g,
                                            const float* __restrict__ bta,
                                            u16* __restrict__ out) {
  int tid = threadIdx.x, lane = tid & 63;
  size_t token = (size_t)blockIdx.x * 4 + (tid >> 6);
  int c = lane * 4;
  float v[4];
  if (INF) {
    float4 f = *(const float4*)((const float*)in + token * Cch + c);
    v[0] = f.x; v[1] = f.y; v[2] = f.z; v[3] = f.w;
  } else {
    ushort4 u = *(const ushort4*)((const u16*)in + token * Cch + c);
    v[0] = b2f(u.x); v[1] = b2f(u.y); v[2] = b2f(u.z); v[3] = b2f(u.w);
  }
  float s = v[0] + v[1] + v[2] + v[3];
  #pragma unroll
  for (int m = 1; m < 64; m <<= 1) s += __shfl_xor(s, m);
  float mu = s * (1.0f / 256.0f);
  float q = 0.f;
  #pragma unroll
  for (int j = 0; j < 4; j++) { float d = v[j] - mu; q += d * d; }
  #pragma unroll
  for (int m = 1; m < 64; m <<= 1) q += __shfl_xor(q, m);
  float rs = rsqrtf(q * (1.0f / 256.0f) + EPSN);
  ushort4 o;
  o.x = f2b((v[0] - mu) * rs * g[c + 0] + bta[c + 0]);
  o.y = f2b((v[1] - mu) * rs * g[c + 1] + bta[c + 1]);
  o.z = f2b((v[2] - mu) * rs * g[c + 2] + bta[c + 2]);
  o.w = f2b((v[3] - mu) * rs * g[c + 3] + bta[c + 3]);
  *(ushort4*)(out + token * Cch + c) = o;
}

// ------- MFMA forward rDFT over W: Y[bh,w,c] -> T[bh,kw,c], kw<65 ------------
// out = A * Y ; z=0: A=Cu -> Tr ; z=1: A=Snu -> Ti. M=128(pad of 65), K=128.
__global__ __launch_bounds__(256) void k_dftw_m(
    const u16* __restrict__ Yg,
    const u16* __restrict__ A0hi, const u16* __restrict__ A0lo,
    const u16* __restrict__ A1hi, const u16* __restrict__ A1lo,
    u16* __restrict__ Or, u16* __restrict__ Oi) {
  __shared__ u16 Bs[128][40];
  int tid = threadIdx.x;
  int bh = blockIdx.x;
  int c0 = blockIdx.y * 128;
  const u16* Ahi = blockIdx.z ? A1hi : A0hi;
  const u16* Alo = blockIdx.z ? A1lo : A0lo;
  u16* outp = blockIdx.z ? Oi : Or;
  int lane = tid & 63, w = tid >> 6;
  int wm = w >> 1, wn = w & 1;
  int rl = lane & 15, kq = (lane >> 4) * 8, rq = lane >> 4;
  f32x4 acc[4][4] = {};
  for (int k0 = 0; k0 < 128; k0 += 32) {
    __syncthreads();
    for (int idx = tid; idx < 1024; idx += 256) {
      int q = idx >> 5, c4 = (idx & 31) * 4;
      ushort4 v = *(const ushort4*)(Yg + ((size_t)bh * 128 + k0 + q) * 256 + c0 + c4);
      Bs[c4 + 0][q] = v.x; Bs[c4 + 1][q] = v.y;
      Bs[c4 + 2][q] = v.z; Bs[c4 + 3][q] = v.w;
    }
    __syncthreads();
    bf16x8 ah[4], al[4], bf[4];
    #pragma unroll
    for (int i = 0; i < 4; i++) {
      int off = (wm * 64 + i * 16 + rl) * 128 + k0 + kq;
      ah[i] = *(const bf16x8*)(Ahi + off);
      al[i] = *(const bf16x8*)(Alo + off);
    }
    #pragma unroll
    for (int j = 0; j < 4; j++)
      bf[j] = *(const bf16x8*)&Bs[wn * 64 + j * 16 + rl][kq];
    #pragma unroll
    for (int i = 0; i < 4; i++)
      #pragma unroll
      for (int j = 0; j < 4; j++) {
        acc[i][j] = __builtin_amdgcn_mfma_f32_16x16x32_bf16(ah[i], bf[j], acc[i][j], 0, 0, 0);
        acc[i][j] = __builtin_amdgcn_mfma_f32_16x16x32_bf16(al[i], bf[j], acc[i][j], 0, 0, 0);
      }
  }
  #pragma unroll
  for (int i = 0; i < 4; i++)
    #pragma unroll
    for (int j = 0; j < 4; j++)
      #pragma unroll
      for (int r = 0; r < 4; r++) {
        int p = wm * 64 + i * 16 + rq * 4 + r;
        if (p < 65) {
          int c = c0 + wn * 64 + j * 16 + rl;
          outp[((size_t)bh * 65 + p) * 256 + c] = f2b(acc[i][j][r]);
        }
      }
}

// ------- MFMA complex DFT over H for fixed (b,kw): O = C*B1 + Ssel*B2 --------
// grid (130, 4): y&1 = c-half, y>>1 = out R/I. SR used for out=R, SI for out=I.
__global__ __launch_bounds__(256) void k_dfth_m(
    const u16* __restrict__ Br_g, const u16* __restrict__ Bi_g,
    const u16* __restrict__ Chi, const u16* __restrict__ Clo,
    const u16* __restrict__ SRhi, const u16* __restrict__ SRlo,
    const u16* __restrict__ SIhi, const u16* __restrict__ SIlo,
    u16* __restrict__ Or, u16* __restrict__ Oi) {
  __shared__ u16 B1s[128][40], B2s[128][40];
  int tid = threadIdx.x;
  int bk = blockIdx.x;
  int b = bk / 65, kw = bk % 65;
  int c0 = (blockIdx.y & 1) * 128;
  int outI = blockIdx.y >> 1;
  const u16* B1g = outI ? Bi_g : Br_g;
  const u16* B2g = outI ? Br_g : Bi_g;
  const u16* Shi = outI ? SIhi : SRhi;
  const u16* Slo = outI ? SIlo : SRlo;
  u16* outp = outI ? Oi : Or;
  int lane = tid & 63, w = tid >> 6;
  int wm = w >> 1, wn = w & 1;
  int rl = lane & 15, kq = (lane >> 4) * 8, rq = lane >> 4;
  f32x4 acc[4][4] = {};
  for (int k0 = 0; k0 < 128; k0 += 32) {
    __syncthreads();
    for (int idx = tid; idx < 1024; idx += 256) {
      int q = idx >> 5, c4 = (idx & 31) * 4;
      size_t g = (((size_t)b * 128 + k0 + q) * 65 + kw) * 256 + c0 + c4;
      ushort4 v1 = *(const ushort4*)(B1g + g);
      ushort4 v2 = *(const ushort4*)(B2g + g);
      B1s[c4 + 0][q] = v1.x; B1s[c4 + 1][q] = v1.y;
      B1s[c4 + 2][q] = v1.z; B1s[c4 + 3][q] = v1.w;
      B2s[c4 + 0][q] = v2.x; B2s[c4 + 1][q] = v2.y;
      B2s[c4 + 2][q] = v2.z; B2s[c4 + 3][q] = v2.w;
    }
    __syncthreads();
    bf16x8 aCh[4], aCl[4], aSh[4], aSl[4], b1[4], b2[4];
    #pragma unroll
    for (int i = 0; i < 4; i++) {
      int off = (wm * 64 + i * 16 + rl) * 128 + k0 + kq;
      aCh[i] = *(const bf16x8*)(Chi + off);
      aCl[i] = *(const bf16x8*)(Clo + off);
      aSh[i] = *(const bf16x8*)(Shi + off);
      aSl[i] = *(const bf16x8*)(Slo + off);
    }
    #pragma unroll
    for (int j = 0; j < 4; j++) {
      b1[j] = *(const bf16x8*)&B1s[wn * 64 + j * 16 + rl][kq];
      b2[j] = *(const bf16x8*)&B2s[wn * 64 + j * 16 + rl][kq];
    }
    #pragma unroll
    for (int i = 0; i < 4; i++)
      #pragma unroll
      for (int j = 0; j < 4; j++) {
        acc[i][j] = __builtin_amdgcn_mfma_f32_16x16x32_bf16(aCh[i], b1[j], acc[i][j], 0, 0, 0);
        acc[i][j] = __builtin_amdgcn_mfma_f32_16x16x32_bf16(aCl[i], b1[j], acc[i][j], 0, 0, 0);
        acc[i][j] = __builtin_amdgcn_mfma_f32_16x16x32_bf16(aSh[i], b2[j], acc[i][j], 0, 0, 0);
        acc[i][j] = __builtin_amdgcn_mfma_f32_16x16x32_bf16(aSl[i], b2[j], acc[i][j], 0, 0, 0);
      }
  }
  #pragma unroll
  for (int i = 0; i < 4; i++)
    #pragma unroll
    for (int j = 0; j < 4; j++)
      #pragma unroll
      for (int r = 0; r < 4; r++) {
        int p = wm * 64 + i * 16 + rq * 4 + r;
        int c = c0 + wn * 64 + j * 16 + rl;
        outp[(((size_t)b * 128 + p) * 65 + kw) * 256 + c] = f2b(acc[i][j][r]);
      }
}

// ------- MFMA inverse rDFT over W + x + ln1out -> X1. K=160 (65r+65i+pad) ----
__global__ __launch_bounds__(256) void k_irfft_m(
    const u16* __restrict__ Ur, const u16* __restrict__ Ui,
    const u16* __restrict__ Whi, const u16* __restrict__ Wlo,
    const float* __restrict__ x_in, const u16* __restrict__ lnout,
    u16* __restrict__ X1) {
  __shared__ u16 Bs[128][40];
  int tid = threadIdx.x;
  int bh = blockIdx.x;
  int c0 = blockIdx.y * 128;
  int lane = tid & 63, w = tid >> 6;
  int wm = w >> 1, wn = w & 1;
  int rl = lane & 15, kq = (lane >> 4) * 8, rq = lane >> 4;
  f32x4 acc[4][4] = {};
  for (int k0 = 0; k0 < 160; k0 += 32) {
    __syncthreads();
    for (int idx = tid; idx < 1024; idx += 256) {
      int q = idx >> 5, c4 = (idx & 31) * 4;
      int grow = k0 + q;
      ushort4 v;
      if (grow < 65)
        v = *(const ushort4*)(Ur + ((size_t)bh * 65 + grow) * 256 + c0 + c4);
      else if (grow < 130)
        v = *(const ushort4*)(Ui + ((size_t)bh * 65 + grow - 65) * 256 + c0 + c4);
      else
        v = make_ushort4(0, 0, 0, 0);
      Bs[c4 + 0][q] = v.x; Bs[c4 + 1][q] = v.y;
      Bs[c4 + 2][q] = v.z; Bs[c4 + 3][q] = v.w;
    }
    __syncthreads();
    bf16x8 ah[4], al[4], bf[4];
    #pragma unroll
    for (int i = 0; i < 4; i++) {
      int off = (wm * 64 + i * 16 + rl) * 160 + k0 + kq;
      ah[i] = *(const bf16x8*)(Whi + off);
      al[i] = *(const bf16x8*)(Wlo + off);
    }
    #pragma unroll
    for (int j = 0; j < 4; j++)
      bf[j] = *(const bf16x8*)&Bs[wn * 64 + j * 16 + rl][kq];
    #pragma unroll
    for (int i = 0; i < 4; i++)
      #pragma unroll
      for (int j = 0; j < 4; j++) {
        acc[i][j] = __builtin_amdgcn_mfma_f32_16x16x32_bf16(ah[i], bf[j], acc[i][j], 0, 0, 0);
        acc[i][j] = __builtin_amdgcn_mfma_f32_16x16x32_bf16(al[i], bf[j], acc[i][j], 0, 0, 0);
      }
  }
  #pragma unroll
  for (int i = 0; i < 4; i++)
    #pragma unroll
    for (int j = 0; j < 4; j++)
      #pragma unroll
      for (int r = 0; r < 4; r++) {
        int p = wm * 64 + i * 16 + rq * 4 + r;
        int c = c0 + wn * 64 + j * 16 + rl;
        size_t g = ((size_t)bh * 128 + p) * 256 + c;
        X1[g] = f2b(x_in[g] + b2f(lnout[g]) + acc[i][j][r]);
      }
}

// ---------------- AFNO block-diagonal complex MLP + softshrink ----------------
__global__ __launch_bounds__(256) void k_afno_mlp(
    const u16* __restrict__ Zr, const u16* __restrict__ Zi,
    const float* __restrict__ w1, const float* __restrict__ b1,
    const float* __restrict__ w2, const float* __restrict__ b2,
    u16* __restrict__ Or, u16* __restrict__ Oi) {
  __shared__ float w1s[128][32];
  __shared__ float w2s[128][32];
  __shared__ float b1s[128][2];
  __shared__ float b2s[16][2];
  int tid = threadIdx.x;
  int n = blockIdx.x;
  for (int idx = tid; idx < 16 * 128; idx += 256) {
    int i = idx >> 7, o = idx & 127;
    w1s[o][2 * i + 0] = w1[((0 * 16 + n) * 16 + i) * 128 + o];
    w1s[o][2 * i + 1] = w1[((1 * 16 + n) * 16 + i) * 128 + o];
  }
  for (int idx = tid; idx < 128 * 16; idx += 256) {
    int o = idx >> 4, j = idx & 15;
    w2s[o][2 * j + 0] = w2[((0 * 16 + n) * 128 + o) * 16 + j];
    w2s[o][2 * j + 1] = w2[((1 * 16 + n) * 128 + o) * 16 + j];
  }
  if (tid < 128) {
    b1s[tid][0] = b1[(0 * 16 + n) * 128 + tid];
    b1s[tid][1] = b1[(1 * 16 + n) * 128 + tid];
  } else if (tid < 144) {
    b2s[tid - 128][0] = b2[(0 * 16 + n) * 16 + (tid - 128)];
    b2s[tid - 128][1] = b2[(1 * 16 + n) * 16 + (tid - 128)];
  }
  __syncthreads();
  size_t pos = (size_t)blockIdx.y * 256 + tid;
  const u16* zrp = Zr + pos * Cch + n * 16;
  const u16* zip = Zi + pos * Cch + n * 16;
  float zr[16], zi[16];
  #pragma unroll
  for (int q = 0; q < 4; q++) {
    ushort4 ur = *(const ushort4*)(zrp + q * 4);
    ushort4 ui = *(const ushort4*)(zip + q * 4);
    zr[q * 4 + 0] = b2f(ur.x); zr[q * 4 + 1] = b2f(ur.y);
    zr[q * 4 + 2] = b2f(ur.z); zr[q * 4 + 3] = b2f(ur.w);
    zi[q * 4 + 0] = b2f(ui.x); zi[q * 4 + 1] = b2f(ui.y);
    zi[q * 4 + 2] = b2f(ui.z); zi[q * 4 + 3] = b2f(ui.w);
  }
  float cr[16], ci[16];
  #pragma unroll
  for (int j = 0; j < 16; j++) { cr[j] = b2s[j][0]; ci[j] = b2s[j][1]; }
  for (int o = 0; o < 128; o++) {
    float hr = b1s[o][0], hi = b1s[o][1];
    #pragma unroll
    for (int q = 0; q < 8; q++) {
      float4 w = *(const float4*)&w1s[o][q * 4];
      int i0 = q * 2, i1 = q * 2 + 1;
      hr += zr[i0] * w.x - zi[i0] * w.y;
      hi += zi[i0] * w.x + zr[i0] * w.y;
      hr += zr[i1] * w.z - zi[i1] * w.w;
      hi += zi[i1] * w.z + zr[i1] * w.w;
    }
    hr = fmaxf(hr, 0.0f); hi = fmaxf(hi, 0.0f);
    #pragma unroll
    for (int q = 0; q < 8; q++) {
      float4 w = *(const float4*)&w2s[o][q * 4];
      int j0 = q * 2, j1 = q * 2 + 1;
      cr[j0] += hr * w.x - hi * w.y;
      ci[j0] += hi * w.x + hr * w.y;
      cr[j1] += hr * w.z - hi * w.w;
      ci[j1] += hi * w.z + hr * w.w;
    }
  }
  u16* orp = Or + pos * Cch + n * 16;
  u16* oip = Oi + pos * Cch + n * 16;
  #pragma unroll
  for (int q = 0; q < 4; q++) {
    ushort4 ur, ui;
    u16* pr = &ur.x; u16* pi = &ui.x;
    #pragma unroll
    for (int t = 0; t < 4; t++) {
      int j = q * 4 + t;
      float vr = copysignf(fmaxf(fabsf(cr[j]) - LAM, 0.0f), cr[j]);
      float vi = copysignf(fmaxf(fabsf(ci[j]) - LAM, 0.0f), ci[j]);
      pr[t] = f2b(vr); pi[t] = f2b(vi);
    }
    *(ushort4*)(orp + q * 4) = ur;
    *(ushort4*)(oip + q * 4) = ui;
  }
}

// ------- MFMA GEMM: C[m,n] = act(A[m,k]*B[n,k] + bias[n]) (+resid) -----------
template<int ACT, int RT, int OUTF>
__global__ __launch_bounds__(256) void k_mgemm(const u16* __restrict__ Ap,
                                               const u16* __restrict__ Bp,
                                               const float* __restrict__ bias,
                                               const u16* __restrict__ resid,
                                               void* __restrict__ Cp,
                                               int M, int N, int K) {
  __shared__ u16 As[128][40];
  __shared__ u16 Bs[128][40];
  int tid = threadIdx.x;
  int lane = tid & 63, w = tid >> 6;
  int wm = w >> 1, wn = w & 1;
  int m0 = blockIdx.x * 128, n0 = blockIdx.y * 128;
  int srow = tid >> 1, sseg = tid & 1;
  const u16* ag = Ap + (size_t)(m0 + srow) * K + sseg * 16;
  const u16* bg = Bp + (size_t)(n0 + srow) * K + sseg * 16;
  int rl = lane & 15, kq = (lane >> 4) * 8;
  f32x4 acc[4][4] = {};
  for (int k0 = 0; k0 < K; k0 += 32) {
    __syncthreads();
    *(u16x8*)&As[srow][sseg * 16]     = *(const u16x8*)(ag + k0);
    *(u16x8*)&As[srow][sseg * 16 + 8] = *(const u16x8*)(ag + k0 + 8);
    *(u16x8*)&Bs[srow][sseg * 16]     = *(const u16x8*)(bg + k0);
    *(u16x8*)&Bs[srow][sseg * 16 + 8] = *(const u16x8*)(bg + k0 + 8);
    __syncthreads();
    bf16x8 af[4], bf[4];
    #pragma unroll
    for (int i = 0; i < 4; i++) {
      af[i] = *(const bf16x8*)&As[wm * 64 + i * 16 + rl][kq];
      bf[i] = *(const bf16x8*)&Bs[wn * 64 + i * 16 + rl][kq];
    }
    #pragma unroll
    for (int i = 0; i < 4; i++)
      #pragma unroll
      for (int j = 0; j < 4; j++)
        acc[i][j] = __builtin_amdgcn_mfma_f32_16x16x32_bf16(af[i], bf[j], acc[i][j], 0, 0, 0);
  }
  int rq = lane >> 4;
  #pragma unroll
  for (int i = 0; i < 4; i++) {
    #pragma unroll
    for (int j = 0; j < 4; j++) {
      #pragma unroll
      for (int r = 0; r < 4; r++) {
        int m = m0 + wm * 64 + i * 16 + rq * 4 + r;
        int n = n0 + wn * 64 + j * 16 + rl;
        float v = acc[i][j][r] + bias[n];
        if (ACT) v = 0.5f * v * (1.0f + erff(v * 0.70710678118654752f));
        if (RT) v += b2f(resid[(size_t)m * N + n]);
        if (OUTF) ((float*)Cp)[(size_t)m * N + n] = v;
        else ((u16*)Cp)[(size_t)m * N + n] = f2b(v);
      }
    }
  }
}

// ---------------- per-head LN over DH=32, bf16 in-place ----------------------
__global__ __launch_bounds__(256) void k_lnhead(u16* __restrict__ X,
                                                const float* __restrict__ g,
                                                const float* __restrict__ bta) {
  int tid = threadIdx.x, lane = tid & 63;
  size_t token = (size_t)blockIdx.x * 4 + (tid >> 6);
  int c = lane * 4;
  ushort4 u = *(const ushort4*)(X + token * Cch + c);
  float v[4] = {b2f(u.x), b2f(u.y), b2f(u.z), b2f(u.w)};
  float s = v[0] + v[1] + v[2] + v[3];
  s += __shfl_xor(s, 1); s += __shfl_xor(s, 2); s += __shfl_xor(s, 4);
  float mu = s * (1.0f / 32.0f);
  float q = 0.f;
  #pragma unroll
  for (int j = 0; j < 4; j++) { float d = v[j] - mu; q += d * d; }
  q += __shfl_xor(q, 1); q += __shfl_xor(q, 2); q += __shfl_xor(q, 4);
  float rs = rsqrtf(q * (1.0f / 32.0f) + EPSN);
  ushort4 o;
  o.x = f2b((v[0] - mu) * rs * g[c + 0] + bta[c + 0]);
  o.y = f2b((v[1] - mu) * rs * g[c + 1] + bta[c + 1]);
  o.z = f2b((v[2] - mu) * rs * g[c + 2] + bta[c + 2]);
  o.w = f2b((v[3] - mu) * rs * g[c + 3] + bta[c + 3]);
  *(ushort4*)(X + token * Cch + c) = o;
}

// ---------------- kv partial sums over 16 chunks of 1024 tokens --------------
__global__ __launch_bounds__(256) void k_kv_partial(const u16* __restrict__ Kb,
                                                    const u16* __restrict__ Vb,
                                                    float* __restrict__ part) {
  __shared__ float kl[64][33], vl[64][33];
  int tid = threadIdx.x;
  int bh = blockIdx.x;
  int b = bh >> 3, h = bh & 7;
  int n0 = blockIdx.y * 1024;
  int d = tid >> 3, eg = tid & 7;
  float acc[4] = {0.f, 0.f, 0.f, 0.f};
  for (int sub = 0; sub < 16; sub++) {
    __syncthreads();
    for (int idx = tid; idx < 64 * 32; idx += 256) {
      int nn = idx >> 5, c = idx & 31;
      size_t o = ((size_t)(b * 16384 + n0 + sub * 64 + nn)) * Cch + h * 32 + c;
      kl[nn][c] = b2f(Kb[o]); vl[nn][c] = b2f(Vb[o]);
    }
    __syncthreads();
    #pragma unroll 4
    for (int nn = 0; nn < 64; nn++) {
      float kd = kl[nn][d];
      #pragma unroll
      for (int j = 0; j < 4; j++) acc[j] += kd * vl[nn][eg * 4 + j];
    }
  }
  size_t base = ((size_t)bh * 16 + blockIdx.y) * 1024 + d * 32 + eg * 4;
  #pragma unroll
  for (int j = 0; j < 4; j++) part[base + j] = acc[j];
}

__global__ __launch_bounds__(1024) void k_kv_reduce(const float* __restrict__ part,
                                                    float* __restrict__ kv) {
  int bh = blockIdx.x, o = threadIdx.x;
  float s = 0.f;
  #pragma unroll
  for (int p = 0; p < 16; p++) s += part[((size_t)bh * 16 + p) * 1024 + o];
  kv[(size_t)bh * 1024 + o] = s * (1.0f / 16384.0f);
}

// ------- attn: ATT[b,n,h*32+e] = sum_d Q[b,n,h*32+d] * kv[b,h,d,e] -----------
__global__ __launch_bounds__(256) void k_attn(const u16* __restrict__ Q,
                                              const float* __restrict__ kv,
                                              u16* __restrict__ ATT) {
  __shared__ float kvl[8][32][32];
  __shared__ float qrow[256];
  int tid = threadIdx.x;
  int b = blockIdx.x;
  int t0 = blockIdx.y * 128;
  for (int idx = tid; idx < 8192; idx += 256)
    kvl[idx >> 10][(idx >> 5) & 31][idx & 31] = kv[(size_t)b * 8192 + idx];
  int h = tid >> 5, e = tid & 31;
  for (int t = 0; t < 128; t++) {
    __syncthreads();
    qrow[tid] = b2f(Q[((size_t)b * 16384 + t0 + t) * Cch + tid]);
    __syncthreads();
    float s = 0.f;
    #pragma unroll 8
    for (int d = 0; d < 32; d++) s += qrow[h * 32 + d] * kvl[h][d][e];
    ATT[((size_t)b * 16384 + t0 + t) * Cch + tid] = f2b(s);
  }
}

extern "C" void kernel_launch(void* const* d_in, const int* in_sizes, int n_in,
                              void* d_out, int out_size, void* d_ws, size_t ws_size,
                              hipStream_t stream) {
  (void)in_sizes; (void)n_in; (void)out_size; (void)ws_size;
  const float* x    = (const float*)d_in[0];
  const float* w1   = (const float*)d_in[1];
  const float* b1   = (const float*)d_in[2];
  const float* w2   = (const float*)d_in[3];
  const float* b2   = (const float*)d_in[4];
  const float* wq   = (const float*)d_in[5];
  const float* bq   = (const float*)d_in[6];
  const float* wk   = (const float*)d_in[7];
  const float* bk   = (const float*)d_in[8];
  const float* wv   = (const float*)d_in[9];
  const float* bv   = (const float*)d_in[10];
  const float* lnkg = (const float*)d_in[11];
  const float* lnkb = (const float*)d_in[12];
  const float* lnvg = (const float*)d_in[13];
  const float* lnvb = (const float*)d_in[14];
  const float* wo   = (const float*)d_in[15];
  const float* bo   = (const float*)d_in[16];
  const float* wup  = (const float*)d_in[17];
  const float* bup  = (const float*)d_in[18];
  const float* wdn  = (const float*)d_in[19];
  const float* bdn  = (const float*)d_in[20];
  const float* n1g  = (const float*)d_in[21];
  const float* n1b  = (const float*)d_in[22];
  const float* n2g  = (const float*)d_in[23];
  const float* n2b  = (const float*)d_in[24];
  const float* n3g  = (const float*)d_in[25];
  const float* n3b  = (const float*)d_in[26];

  // ---- workspace layout (bytes), max used 51,970,048 (proven safe) ----
  // R0: 0..16,777,216             A (ln outputs / residual)
  // R1: 16,777,216..33,816,576    S1(r+i) | X1 | V | Q | X2 (+slack for wq/wk)
  // R2: 33,816,576..50,855,936    S2(r+i) | K | ATT | UP (+S2i tail wv/wo)
  // TW (twiddles): 50,855,936 + 475,136 — overlays KVp; dead before kv_partial
  // KVp: 50,855,936..51,904,512 ; KVb: ..51,970,048
  char* ws = (char*)d_ws;
  u16* A    = (u16*)(ws + 0);
  u16* S1r  = (u16*)(ws + 16777216);
  u16* S1i  = (u16*)(ws + 25296896);
  u16* S2r  = (u16*)(ws + 33816576);
  u16* S2i  = (u16*)(ws + 42336256);
  u16* X1   = (u16*)(ws + 16777216);
  u16* Vb   = (u16*)(ws + 16777216);
  u16* Qb   = (u16*)(ws + 16777216);
  u16* X2   = (u16*)(ws + 16777216);
  u16* Kb   = (u16*)(ws + 33816576);
  u16* ATT  = (u16*)(ws + 33816576);
  u16* UP   = (u16*)(ws + 33816576);
  u16* wq_b = (u16*)(ws + 33554432);
  u16* wk_b = (u16*)(ws + 33685504);
  u16* wv_b = (u16*)(ws + 50593792);
  u16* wo_b = (u16*)(ws + 50724864);
  u16* wup_b = (u16*)(ws + 16777216);
  u16* wdn_b = (u16*)(ws + 17825792);
  u16* TW   = (u16*)(ws + 50855936);
  float* KVp = (float*)(ws + 50855936);
  float* KVb = (float*)(ws + 51904512);
  float* outp = (float*)d_out;

  // twiddle matrix views (u16 element offsets)
  u16 *Cf_h = TW + 0 * 16384, *Cf_l = TW + 1 * 16384;
  u16 *Sf_h = TW + 2 * 16384, *Sf_l = TW + 3 * 16384;
  u16 *Snf_h = TW + 4 * 16384, *Snf_l = TW + 5 * 16384;
  u16 *Cu_h = TW + 6 * 16384, *Cu_l = TW + 7 * 16384;
  u16 *Su_h = TW + 8 * 16384, *Su_l = TW + 9 * 16384;
  u16 *Snu_h = TW + 10 * 16384, *Snu_l = TW + 11 * 16384;
  u16 *Wm_h = TW + 196608, *Wm_l = TW + 217088;

  k_twid<<<128, 128, 0, stream>>>(TW);

  // ---- AFNO: x1 = x + ln1(x) + irfft2(shrink(mlp(rfft2(ln1(x))))) ----
  k_ln<1><<<8192, 256, 0, stream>>>((const void*)x, n1g, n1b, A);
  k_dftw_m<<<dim3(256, 2, 2), 256, 0, stream>>>(A, Cu_h, Cu_l, Snu_h, Snu_l, S1r, S1i);
  k_dfth_m<<<dim3(130, 4), 256, 0, stream>>>(S1r, S1i, Cf_h, Cf_l, Sf_h, Sf_l, Snf_h, Snf_l, S2r, S2i);
  k_afno_mlp<<<dim3(16, 65), 256, 0, stream>>>(S2r, S2i, w1, b1, w2, b2, S1r, S1i);
  k_dfth_m<<<dim3(130, 4), 256, 0, stream>>>(S1r, S1i, Cu_h, Cu_l, Snu_h, Snu_l, Su_h, Su_l, S2r, S2i);
  k_irfft_m<<<dim3(256, 2), 256, 0, stream>>>(S2r, S2i, Wm_h, Wm_l, x, A, X1);

  // ---- convert QKV/O weights to bf16 (dead S1i/S2i slack) ----
  k_cvt<<<256, 256, 0, stream>>>(wq, wq_b, 65536);
  k_cvt<<<256, 256, 0, stream>>>(wk, wk_b, 65536);
  k_cvt<<<256, 256, 0, stream>>>(wv, wv_b, 65536);
  k_cvt<<<256, 256, 0, stream>>>(wo, wo_b, 65536);

  // ---- Galerkin: x2 = ln2(x1) + wo(attn) ; residual = LN2 OUTPUT ----
  k_ln<0><<<8192, 256, 0, stream>>>((const void*)X1, n2g, n2b, A);
  k_mgemm<0, 0, 0><<<dim3(256, 2), 256, 0, stream>>>(A, wk_b, bk, nullptr, (void*)Kb, 32768, 256, 256);
  k_mgemm<0, 0, 0><<<dim3(256, 2), 256, 0, stream>>>(A, wv_b, bv, nullptr, (void*)Vb, 32768, 256, 256);
  k_lnhead<<<8192, 256, 0, stream>>>(Kb, lnkg, lnkb);
  k_lnhead<<<8192, 256, 0, stream>>>(Vb, lnvg, lnvb);
  k_kv_partial<<<dim3(16, 16), 256, 0, stream>>>(Kb, Vb, KVp);
  k_kv_reduce<<<16, 1024, 0, stream>>>(KVp, KVb);
  k_mgemm<0, 0, 0><<<dim3(256, 2), 256, 0, stream>>>(A, wq_b, bq, nullptr, (void*)Qb, 32768, 256, 256);
  k_attn<<<dim3(2, 128), 256, 0, stream>>>(Qb, KVb, ATT);
  k_mgemm<0, 1, 0><<<dim3(256, 2), 256, 0, stream>>>(ATT, wo_b, bo, A, (void*)X2, 32768, 256, 256);

  // ---- FFN: out = ln3(x2) + down(gelu(up(ln3))) ; residual = LN3 OUTPUT ----
  k_ln<0><<<8192, 256, 0, stream>>>((const void*)X2, n3g, n3b, A);
  k_cvt<<<2048, 256, 0, stream>>>(wup, wup_b, 524288);
  k_cvt<<<2048, 256, 0, stream>>>(wdn, wdn_b, 524288);
  for (int c = 0; c < 8; c++) {
    const u16* Ac = A + (size_t)c * 4096 * 256;
    k_mgemm<1, 0, 0><<<dim3(32, 16), 256, 0, stream>>>(Ac, wup_b, bup, nullptr, (void*)UP, 4096, 2048, 256);
    k_mgemm<0, 1, 1><<<dim3(32, 2), 256, 0, stream>>>(UP, wdn_b, bdn, Ac, (void*)(outp + (size_t)c * 4096 * 256), 4096, 256, 2048);
  }
}

// Round 10
// 1025.874 us; speedup vs baseline: 3.1157x; 1.1326x over previous
//
#include <hip/hip_runtime.h>

// InvariantBlock: AFNO spectral block + Galerkin linear attention + GELU FFN
// B=2 H=128 W=128 C=256; tokens 32768; KW=65; HEADS=8 DH=32; NB=16 BS=16 HID=128
// d_in / d_out FP32; intermediates bf16 in ws. Accumulation fp32.
// R9->R10: AFNO MLP -> fused MFMA kernel (hi/lo-split packed weights, staged
// in d_out-as-scratch; d_out fully overwritten by the FFN afterwards).

typedef unsigned short u16;
typedef unsigned int u32;
typedef __attribute__((ext_vector_type(8))) short bf16x8;
typedef __attribute__((ext_vector_type(8))) unsigned short u16x8;
typedef __attribute__((ext_vector_type(4))) float f32x4;
#define DEV __device__ __forceinline__

constexpr int Cch = 256;
constexpr float EPSN = 1e-5f, LAM = 0.01f;
constexpr float TWO_PI = 6.283185307179586f;

DEV float b2f(u16 u) { return __uint_as_float(((u32)u) << 16); }
DEV u16 f2b(float f) {
  u32 x = __float_as_uint(f);
  return (u16)((x + 0x7FFFu + ((x >> 16) & 1u)) >> 16);
}

// ---------------- twiddle matrices (hi/lo split bf16) ------------------------
DEV void put2(u16* tw, int m, int idx, float v) {
  u16 hi = f2b(v);
  tw[m * 16384 + idx] = hi;
  tw[(m + 1) * 16384 + idx] = f2b(v - b2f(hi));
}

__global__ __launch_bounds__(128) void k_twid(u16* __restrict__ tw) {
  int p = blockIdx.x, q = threadIdx.x;
  int idx = p * 128 + q;
  float ang = TWO_PI * (float)((p * q) & 127) * (1.0f / 128.0f);
  float c = cosf(ang), s = sinf(ang);
  put2(tw, 0, idx, c * (1.0f / 128.0f));
  put2(tw, 2, idx, s * (1.0f / 128.0f));
  put2(tw, 4, idx, -s * (1.0f / 128.0f));
  put2(tw, 6, idx, c);
  put2(tw, 8, idx, s);
  put2(tw, 10, idx, -s);
  u16* wmh = tw + 196608;
  u16* wml = tw + 217088;
  for (int k = q; k < 160; k += 128) {
    float v = 0.0f;
    if (k < 65) {
      float sc = (k == 0 || k == 64) ? 1.0f : 2.0f;
      v = sc * cosf(TWO_PI * (float)((p * k) & 127) * (1.0f / 128.0f)) * (1.0f / 128.0f);
    } else if (k < 130) {
      int kk = k - 65;
      float sc = (kk == 0 || kk == 64) ? 1.0f : 2.0f;
      v = -sc * sinf(TWO_PI * (float)((p * kk) & 127) * (1.0f / 128.0f)) * (1.0f / 128.0f);
    }
    u16 hi = f2b(v);
    wmh[p * 160 + k] = hi;
    wml[p * 160 + k] = f2b(v - b2f(hi));
  }
}

// ------- pack AFNO MLP weights as hi/lo bf16 GEMM operands -------------------
// W1pack[n][out(256)][k(32)]: out<128 -> o1r rows [w1r | -w1i]; else [w1i | w1r]
// W2pack[n][out2(32)][k(256)]: out2<16 -> o2r rows [w2r | -w2i]; else [w2i | w2r]
__global__ __launch_bounds__(256) void k_wpack(const float* __restrict__ w1,
                                               const float* __restrict__ w2,
                                               u16* __restrict__ W1h, u16* __restrict__ W1l,
                                               u16* __restrict__ W2h, u16* __restrict__ W2l) {
  int idx = blockIdx.x * 256 + threadIdx.x;
  if (idx < 131072) {
    int n = idx >> 13, rem = idx & 8191;
    int out = rem >> 5, k = rem & 31;
    float v;
    if (out < 128)
      v = (k < 16) ? w1[((size_t)n * 16 + k) * 128 + out]
                   : -w1[((size_t)(16 + n) * 16 + (k - 16)) * 128 + out];
    else {
      int o = out - 128;
      v = (k < 16) ? w1[((size_t)(16 + n) * 16 + k) * 128 + o]
                   : w1[((size_t)n * 16 + (k - 16)) * 128 + o];
    }
    u16 hi = f2b(v);
    W1h[idx] = hi; W1l[idx] = f2b(v - b2f(hi));
  } else if (idx < 262144) {
    int id2 = idx - 131072;
    int n = id2 >> 13, rem = id2 & 8191;
    int out2 = rem >> 8, k = rem & 255;
    float v;
    if (out2 < 16)
      v = (k < 128) ? w2[((size_t)n * 128 + k) * 16 + out2]
                    : -w2[((size_t)(16 + n) * 128 + (k - 128)) * 16 + out2];
    else {
      int o = out2 - 16;
      v = (k < 128) ? w2[((size_t)(16 + n) * 128 + k) * 16 + o]
                    : w2[((size_t)n * 128 + (k - 128)) * 16 + o];
    }
    u16 hi = f2b(v);
    W2h[id2] = hi; W2l[id2] = f2b(v - b2f(hi));
  }
}

// ---------------- fp32 -> bf16 weight convert --------------------------------
__global__ __launch_bounds__(256) void k_cvt(const float* __restrict__ src,
                                             u16* __restrict__ dst, int n) {
  int i = blockIdx.x * 256 + threadIdx.x;
  if (i < n) dst[i] = f2b(src[i]);
}

// ---------------- LayerNorm over C=256; INF=1 fp32 input, else bf16 ----------
template<int INF>
__global__ __launch_bounds__(256) void k_ln(const void* __restrict__ in,
                                            const float* __restrict__ g,
                                            const float* __restrict__ bta,
                                            u16* __restrict__ out) {
  int tid = threadIdx.x, lane = tid & 63;
  size_t token = (size_t)blockIdx.x * 4 + (tid >> 6);
  int c = lane * 4;
  float v[4];
  if (INF) {
    float4 f = *(const float4*)((const float*)in + token * Cch + c);
    v[0] = f.x; v[1] = f.y; v[2] = f.z; v[3] = f.w;
  } else {
    ushort4 u = *(const ushort4*)((const u16*)in + token * Cch + c);
    v[0] = b2f(u.x); v[1] = b2f(u.y); v[2] = b2f(u.z); v[3] = b2f(u.w);
  }
  float s = v[0] + v[1] + v[2] + v[3];
  #pragma unroll
  for (int m = 1; m < 64; m <<= 1) s += __shfl_xor(s, m);
  float mu = s * (1.0f / 256.0f);
  float q = 0.f;
  #pragma unroll
  for (int j = 0; j < 4; j++) { float d = v[j] - mu; q += d * d; }
  #pragma unroll
  for (int m = 1; m < 64; m <<= 1) q += __shfl_xor(q, m);
  float rs = rsqrtf(q * (1.0f / 256.0f) + EPSN);
  ushort4 o;
  o.x = f2b((v[0] - mu) * rs * g[c + 0] + bta[c + 0]);
  o.y = f2b((v[1] - mu) * rs * g[c + 1] + bta[c + 1]);
  o.z = f2b((v[2] - mu) * rs * g[c + 2] + bta[c + 2]);
  o.w = f2b((v[3] - mu) * rs * g[c + 3] + bta[c + 3]);
  *(ushort4*)(out + token * Cch + c) = o;
}

// ------- MFMA forward rDFT over W: Y[bh,w,c] -> T[bh,kw,c], kw<65 ------------
__global__ __launch_bounds__(256) void k_dftw_m(
    const u16* __restrict__ Yg,
    const u16* __restrict__ A0hi, const u16* __restrict__ A0lo,
    const u16* __restrict__ A1hi, const u16* __restrict__ A1lo,
    u16* __restrict__ Or, u16* __restrict__ Oi) {
  __shared__ u16 Bs[128][40];
  int tid = threadIdx.x;
  int bh = blockIdx.x;
  int c0 = blockIdx.y * 128;
  const u16* Ahi = blockIdx.z ? A1hi : A0hi;
  const u16* Alo = blockIdx.z ? A1lo : A0lo;
  u16* outp = blockIdx.z ? Oi : Or;
  int lane = tid & 63, w = tid >> 6;
  int wm = w >> 1, wn = w & 1;
  int rl = lane & 15, kq = (lane >> 4) * 8, rq = lane >> 4;
  f32x4 acc[4][4] = {};
  for (int k0 = 0; k0 < 128; k0 += 32) {
    __syncthreads();
    for (int idx = tid; idx < 1024; idx += 256) {
      int q = idx >> 5, c4 = (idx & 31) * 4;
      ushort4 v = *(const ushort4*)(Yg + ((size_t)bh * 128 + k0 + q) * 256 + c0 + c4);
      Bs[c4 + 0][q] = v.x; Bs[c4 + 1][q] = v.y;
      Bs[c4 + 2][q] = v.z; Bs[c4 + 3][q] = v.w;
    }
    __syncthreads();
    bf16x8 ah[4], al[4], bf[4];
    #pragma unroll
    for (int i = 0; i < 4; i++) {
      int off = (wm * 64 + i * 16 + rl) * 128 + k0 + kq;
      ah[i] = *(const bf16x8*)(Ahi + off);
      al[i] = *(const bf16x8*)(Alo + off);
    }
    #pragma unroll
    for (int j = 0; j < 4; j++)
      bf[j] = *(const bf16x8*)&Bs[wn * 64 + j * 16 + rl][kq];
    #pragma unroll
    for (int i = 0; i < 4; i++)
      #pragma unroll
      for (int j = 0; j < 4; j++) {
        acc[i][j] = __builtin_amdgcn_mfma_f32_16x16x32_bf16(ah[i], bf[j], acc[i][j], 0, 0, 0);
        acc[i][j] = __builtin_amdgcn_mfma_f32_16x16x32_bf16(al[i], bf[j], acc[i][j], 0, 0, 0);
      }
  }
  #pragma unroll
  for (int i = 0; i < 4; i++)
    #pragma unroll
    for (int j = 0; j < 4; j++)
      #pragma unroll
      for (int r = 0; r < 4; r++) {
        int p = wm * 64 + i * 16 + rq * 4 + r;
        if (p < 65) {
          int c = c0 + wn * 64 + j * 16 + rl;
          outp[((size_t)bh * 65 + p) * 256 + c] = f2b(acc[i][j][r]);
        }
      }
}

// ------- MFMA complex DFT over H for fixed (b,kw): O = C*B1 + Ssel*B2 --------
__global__ __launch_bounds__(256) void k_dfth_m(
    const u16* __restrict__ Br_g, const u16* __restrict__ Bi_g,
    const u16* __restrict__ Chi, const u16* __restrict__ Clo,
    const u16* __restrict__ SRhi, const u16* __restrict__ SRlo,
    const u16* __restrict__ SIhi, const u16* __restrict__ SIlo,
    u16* __restrict__ Or, u16* __restrict__ Oi) {
  __shared__ u16 B1s[128][40], B2s[128][40];
  int tid = threadIdx.x;
  int bk = blockIdx.x;
  int b = bk / 65, kw = bk % 65;
  int c0 = (blockIdx.y & 1) * 128;
  int outI = blockIdx.y >> 1;
  const u16* B1g = outI ? Bi_g : Br_g;
  const u16* B2g = outI ? Br_g : Bi_g;
  const u16* Shi = outI ? SIhi : SRhi;
  const u16* Slo = outI ? SIlo : SRlo;
  u16* outp = outI ? Oi : Or;
  int lane = tid & 63, w = tid >> 6;
  int wm = w >> 1, wn = w & 1;
  int rl = lane & 15, kq = (lane >> 4) * 8, rq = lane >> 4;
  f32x4 acc[4][4] = {};
  for (int k0 = 0; k0 < 128; k0 += 32) {
    __syncthreads();
    for (int idx = tid; idx < 1024; idx += 256) {
      int q = idx >> 5, c4 = (idx & 31) * 4;
      size_t g = (((size_t)b * 128 + k0 + q) * 65 + kw) * 256 + c0 + c4;
      ushort4 v1 = *(const ushort4*)(B1g + g);
      ushort4 v2 = *(const ushort4*)(B2g + g);
      B1s[c4 + 0][q] = v1.x; B1s[c4 + 1][q] = v1.y;
      B1s[c4 + 2][q] = v1.z; B1s[c4 + 3][q] = v1.w;
      B2s[c4 + 0][q] = v2.x; B2s[c4 + 1][q] = v2.y;
      B2s[c4 + 2][q] = v2.z; B2s[c4 + 3][q] = v2.w;
    }
    __syncthreads();
    bf16x8 aCh[4], aCl[4], aSh[4], aSl[4], b1[4], b2[4];
    #pragma unroll
    for (int i = 0; i < 4; i++) {
      int off = (wm * 64 + i * 16 + rl) * 128 + k0 + kq;
      aCh[i] = *(const bf16x8*)(Chi + off);
      aCl[i] = *(const bf16x8*)(Clo + off);
      aSh[i] = *(const bf16x8*)(Shi + off);
      aSl[i] = *(const bf16x8*)(Slo + off);
    }
    #pragma unroll
    for (int j = 0; j < 4; j++) {
      b1[j] = *(const bf16x8*)&B1s[wn * 64 + j * 16 + rl][kq];
      b2[j] = *(const bf16x8*)&B2s[wn * 64 + j * 16 + rl][kq];
    }
    #pragma unroll
    for (int i = 0; i < 4; i++)
      #pragma unroll
      for (int j = 0; j < 4; j++) {
        acc[i][j] = __builtin_amdgcn_mfma_f32_16x16x32_bf16(aCh[i], b1[j], acc[i][j], 0, 0, 0);
        acc[i][j] = __builtin_amdgcn_mfma_f32_16x16x32_bf16(aCl[i], b1[j], acc[i][j], 0, 0, 0);
        acc[i][j] = __builtin_amdgcn_mfma_f32_16x16x32_bf16(aSh[i], b2[j], acc[i][j], 0, 0, 0);
        acc[i][j] = __builtin_amdgcn_mfma_f32_16x16x32_bf16(aSl[i], b2[j], acc[i][j], 0, 0, 0);
      }
  }
  #pragma unroll
  for (int i = 0; i < 4; i++)
    #pragma unroll
    for (int j = 0; j < 4; j++)
      #pragma unroll
      for (int r = 0; r < 4; r++) {
        int p = wm * 64 + i * 16 + rq * 4 + r;
        int c = c0 + wn * 64 + j * 16 + rl;
        outp[(((size_t)b * 128 + p) * 65 + kw) * 256 + c] = f2b(acc[i][j][r]);
      }
}

// ------- MFMA inverse rDFT over W + x + ln1out -> X1. K=160 (65r+65i+pad) ----
__global__ __launch_bounds__(256) void k_irfft_m(
    const u16* __restrict__ Ur, const u16* __restrict__ Ui,
    const u16* __restrict__ Whi, const u16* __restrict__ Wlo,
    const float* __restrict__ x_in, const u16* __restrict__ lnout,
    u16* __restrict__ X1) {
  __shared__ u16 Bs[128][40];
  int tid = threadIdx.x;
  int bh = blockIdx.x;
  int c0 = blockIdx.y * 128;
  int lane = tid & 63, w = tid >> 6;
  int wm = w >> 1, wn = w & 1;
  int rl = lane & 15, kq = (lane >> 4) * 8, rq = lane >> 4;
  f32x4 acc[4][4] = {};
  for (int k0 = 0; k0 < 160; k0 += 32) {
    __syncthreads();
    for (int idx = tid; idx < 1024; idx += 256) {
      int q = idx >> 5, c4 = (idx & 31) * 4;
      int grow = k0 + q;
      ushort4 v;
      if (grow < 65)
        v = *(const ushort4*)(Ur + ((size_t)bh * 65 + grow) * 256 + c0 + c4);
      else if (grow < 130)
        v = *(const ushort4*)(Ui + ((size_t)bh * 65 + grow - 65) * 256 + c0 + c4);
      else
        v = make_ushort4(0, 0, 0, 0);
      Bs[c4 + 0][q] = v.x; Bs[c4 + 1][q] = v.y;
      Bs[c4 + 2][q] = v.z; Bs[c4 + 3][q] = v.w;
    }
    __syncthreads();
    bf16x8 ah[4], al[4], bf[4];
    #pragma unroll
    for (int i = 0; i < 4; i++) {
      int off = (wm * 64 + i * 16 + rl) * 160 + k0 + kq;
      ah[i] = *(const bf16x8*)(Whi + off);
      al[i] = *(const bf16x8*)(Wlo + off);
    }
    #pragma unroll
    for (int j = 0; j < 4; j++)
      bf[j] = *(const bf16x8*)&Bs[wn * 64 + j * 16 + rl][kq];
    #pragma unroll
    for (int i = 0; i < 4; i++)
      #pragma unroll
      for (int j = 0; j < 4; j++) {
        acc[i][j] = __builtin_amdgcn_mfma_f32_16x16x32_bf16(ah[i], bf[j], acc[i][j], 0, 0, 0);
        acc[i][j] = __builtin_amdgcn_mfma_f32_16x16x32_bf16(al[i], bf[j], acc[i][j], 0, 0, 0);
      }
  }
  #pragma unroll
  for (int i = 0; i < 4; i++)
    #pragma unroll
    for (int j = 0; j < 4; j++)
      #pragma unroll
      for (int r = 0; r < 4; r++) {
        int p = wm * 64 + i * 16 + rq * 4 + r;
        int c = c0 + wn * 64 + j * 16 + rl;
        size_t g = ((size_t)bh * 128 + p) * 256 + c;
        X1[g] = f2b(x_in[g] + b2f(lnout[g]) + acc[i][j][r]);
      }
}

// ------- fused AFNO MLP via MFMA -----------------------------------------
// block = (n, 64-pos tile). L1: O1[256,pos]=W1pack*Z^T; relu; L2: O2[32,pos].
__global__ __launch_bounds__(256) void k_afno_mfma(
    const u16* __restrict__ Zr, const u16* __restrict__ Zi,
    const u16* __restrict__ W1h, const u16* __restrict__ W1l,
    const u16* __restrict__ W2h, const u16* __restrict__ W2l,
    const float* __restrict__ b1, const float* __restrict__ b2,
    u16* __restrict__ Or, u16* __restrict__ Oi) {
  __shared__ u16 Zs[64][40];          // [pos][k=zr16|zi16]
  __shared__ u16 o1s[32 * 64 * 8];    // [kb][pos][e] : o1[k][pos], k=kb*8+e
  int tid = threadIdx.x;
  int n = blockIdx.x;
  int p0 = blockIdx.y * 64;
  int lane = tid & 63, w = tid >> 6;
  int rl = lane & 15, rq = lane >> 4;
  int kq = rq * 8;
  // stage Z
  for (int idx = tid; idx < 512; idx += 256) {
    int p = idx >> 3, q4 = (idx & 7) * 4;
    const u16* src = (q4 < 16) ? (Zr + (size_t)(p0 + p) * 256 + n * 16 + q4)
                               : (Zi + (size_t)(p0 + p) * 256 + n * 16 + q4 - 16);
    *(ushort4*)&Zs[p][q4] = *(const ushort4*)src;
  }
  __syncthreads();
  // layer 1: this wave does out rows [w*64, w*64+64), all 64 pos
  f32x4 a1[4][4] = {};
  bf16x8 bfr[4];
  #pragma unroll
  for (int j = 0; j < 4; j++) bfr[j] = *(const bf16x8*)&Zs[j * 16 + rl][kq];
  #pragma unroll
  for (int i = 0; i < 4; i++) {
    int out = w * 64 + i * 16 + rl;
    bf16x8 ah = *(const bf16x8*)(W1h + ((size_t)n * 256 + out) * 32 + kq);
    bf16x8 al = *(const bf16x8*)(W1l + ((size_t)n * 256 + out) * 32 + kq);
    #pragma unroll
    for (int j = 0; j < 4; j++) {
      a1[i][j] = __builtin_amdgcn_mfma_f32_16x16x32_bf16(ah, bfr[j], a1[i][j], 0, 0, 0);
      a1[i][j] = __builtin_amdgcn_mfma_f32_16x16x32_bf16(al, bfr[j], a1[i][j], 0, 0, 0);
    }
  }
  // bias + relu -> o1s
  #pragma unroll
  for (int i = 0; i < 4; i++) {
    float bv[4];
    #pragma unroll
    for (int r = 0; r < 4; r++) {
      int out = w * 64 + i * 16 + rq * 4 + r;
      bv[r] = (out < 128) ? b1[n * 128 + out] : b1[2048 + n * 128 + out - 128];
    }
    #pragma unroll
    for (int j = 0; j < 4; j++)
      #pragma unroll
      for (int r = 0; r < 4; r++) {
        int out = w * 64 + i * 16 + rq * 4 + r;
        int pos = j * 16 + rl;
        float v = fmaxf(a1[i][j][r] + bv[r], 0.0f);
        o1s[((out >> 3) * 64 + pos) * 8 + (out & 7)] = f2b(v);
      }
  }
  __syncthreads();
  // layer 2: this wave does pos tile w (16 pos), out2 rows 0..31
  f32x4 a2[2] = {};
  #pragma unroll
  for (int k0 = 0; k0 < 256; k0 += 32) {
    bf16x8 bb = *(const bf16x8*)&o1s[(((k0 + kq) >> 3) * 64 + w * 16 + rl) * 8];
    #pragma unroll
    for (int i = 0; i < 2; i++) {
      int out2 = i * 16 + rl;
      bf16x8 ah = *(const bf16x8*)(W2h + ((size_t)n * 32 + out2) * 256 + k0 + kq);
      bf16x8 al = *(const bf16x8*)(W2l + ((size_t)n * 32 + out2) * 256 + k0 + kq);
      a2[i] = __builtin_amdgcn_mfma_f32_16x16x32_bf16(ah, bb, a2[i], 0, 0, 0);
      a2[i] = __builtin_amdgcn_mfma_f32_16x16x32_bf16(al, bb, a2[i], 0, 0, 0);
    }
  }
  // bias + softshrink -> Or/Oi
  #pragma unroll
  for (int i = 0; i < 2; i++)
    #pragma unroll
    for (int r = 0; r < 4; r++) {
      int out2 = i * 16 + rq * 4 + r;
      float bv = (out2 < 16) ? b2[n * 16 + out2] : b2[256 + n * 16 + out2 - 16];
      float v = a2[i][r] + bv;
      v = copysignf(fmaxf(fabsf(v) - LAM, 0.0f), v);
      size_t g = (size_t)(p0 + w * 16 + rl) * 256 + n * 16 + ((out2 < 16) ? out2 : out2 - 16);
      if (out2 < 16) Or[g] = f2b(v);
      else Oi[g] = f2b(v);
    }
}

// ------- MFMA GEMM: C[m,n] = act(A[m,k]*B[n,k] + bias[n]) (+resid) -----------
template<int ACT, int RT, int OUTF>
__global__ __launch_bounds__(256) void k_mgemm(const u16* __restrict__ Ap,
                                               const u16* __restrict__ Bp,
                                               const float* __restrict__ bias,
                                               const u16* __restrict__ resid,
                                               void* __restrict__ Cp,
                                               int M, int N, int K) {
  __shared__ u16 As[128][40];
  __shared__ u16 Bs[128][40];
  int tid = threadIdx.x;
  int lane = tid & 63, w = tid >> 6;
  int wm = w >> 1, wn = w & 1;
  int m0 = blockIdx.x * 128, n0 = blockIdx.y * 128;
  int srow = tid >> 1, sseg = tid & 1;
  const u16* ag = Ap + (size_t)(m0 + srow) * K + sseg * 16;
  const u16* bg = Bp + (size_t)(n0 + srow) * K + sseg * 16;
  int rl = lane & 15, kq = (lane >> 4) * 8;
  f32x4 acc[4][4] = {};
  for (int k0 = 0; k0 < K; k0 += 32) {
    __syncthreads();
    *(u16x8*)&As[srow][sseg * 16]     = *(const u16x8*)(ag + k0);
    *(u16x8*)&As[srow][sseg * 16 + 8] = *(const u16x8*)(ag + k0 + 8);
    *(u16x8*)&Bs[srow][sseg * 16]     = *(const u16x8*)(bg + k0);
    *(u16x8*)&Bs[srow][sseg * 16 + 8] = *(const u16x8*)(bg + k0 + 8);
    __syncthreads();
    bf16x8 af[4], bf[4];
    #pragma unroll
    for (int i = 0; i < 4; i++) {
      af[i] = *(const bf16x8*)&As[wm * 64 + i * 16 + rl][kq];
      bf[i] = *(const bf16x8*)&Bs[wn * 64 + i * 16 + rl][kq];
    }
    #pragma unroll
    for (int i = 0; i < 4; i++)
      #pragma unroll
      for (int j = 0; j < 4; j++)
        acc[i][j] = __builtin_amdgcn_mfma_f32_16x16x32_bf16(af[i], bf[j], acc[i][j], 0, 0, 0);
  }
  int rq = lane >> 4;
  #pragma unroll
  for (int i = 0; i < 4; i++) {
    #pragma unroll
    for (int j = 0; j < 4; j++) {
      #pragma unroll
      for (int r = 0; r < 4; r++) {
        int m = m0 + wm * 64 + i * 16 + rq * 4 + r;
        int n = n0 + wn * 64 + j * 16 + rl;
        float v = acc[i][j][r] + bias[n];
        if (ACT) v = 0.5f * v * (1.0f + erff(v * 0.70710678118654752f));
        if (RT) v += b2f(resid[(size_t)m * N + n]);
        if (OUTF) ((float*)Cp)[(size_t)m * N + n] = v;
        else ((u16*)Cp)[(size_t)m * N + n] = f2b(v);
      }
    }
  }
}

// ---------------- per-head LN over DH=32, bf16 in-place ----------------------
__global__ __launch_bounds__(256) void k_lnhead(u16* __restrict__ X,
                                                const float* __restrict__ g,
                                                const float* __restrict__ bta) {
  int tid = threadIdx.x, lane = tid & 63;
  size_t token = (size_t)blockIdx.x * 4 + (tid >> 6);
  int c = lane * 4;
  ushort4 u = *(const ushort4*)(X + token * Cch + c);
  float v[4] = {b2f(u.x), b2f(u.y), b2f(u.z), b2f(u.w)};
  float s = v[0] + v[1] + v[2] + v[3];
  s += __shfl_xor(s, 1); s += __shfl_xor(s, 2); s += __shfl_xor(s, 4);
  float mu = s * (1.0f / 32.0f);
  float q = 0.f;
  #pragma unroll
  for (int j = 0; j < 4; j++) { float d = v[j] - mu; q += d * d; }
  q += __shfl_xor(q, 1); q += __shfl_xor(q, 2); q += __shfl_xor(q, 4);
  float rs = rsqrtf(q * (1.0f / 32.0f) + EPSN);
  ushort4 o;
  o.x = f2b((v[0] - mu) * rs * g[c + 0] + bta[c + 0]);
  o.y = f2b((v[1] - mu) * rs * g[c + 1] + bta[c + 1]);
  o.z = f2b((v[2] - mu) * rs * g[c + 2] + bta[c + 2]);
  o.w = f2b((v[3] - mu) * rs * g[c + 3] + bta[c + 3]);
  *(ushort4*)(X + token * Cch + c) = o;
}

// ---------------- kv partial sums over 16 chunks of 1024 tokens --------------
__global__ __launch_bounds__(256) void k_kv_partial(const u16* __restrict__ Kb,
                                                    const u16* __restrict__ Vb,
                                                    float* __restrict__ part) {
  __shared__ float kl[64][33], vl[64][33];
  int tid = threadIdx.x;
  int bh = blockIdx.x;
  int b = bh >> 3, h = bh & 7;
  int n0 = blockIdx.y * 1024;
  int d = tid >> 3, eg = tid & 7;
  float acc[4] = {0.f, 0.f, 0.f, 0.f};
  for (int sub = 0; sub < 16; sub++) {
    __syncthreads();
    for (int idx = tid; idx < 64 * 32; idx += 256) {
      int nn = idx >> 5, c = idx & 31;
      size_t o = ((size_t)(b * 16384 + n0 + sub * 64 + nn)) * Cch + h * 32 + c;
      kl[nn][c] = b2f(Kb[o]); vl[nn][c] = b2f(Vb[o]);
    }
    __syncthreads();
    #pragma unroll 4
    for (int nn = 0; nn < 64; nn++) {
      float kd = kl[nn][d];
      #pragma unroll
      for (int j = 0; j < 4; j++) acc[j] += kd * vl[nn][eg * 4 + j];
    }
  }
  size_t base = ((size_t)bh * 16 + blockIdx.y) * 1024 + d * 32 + eg * 4;
  #pragma unroll
  for (int j = 0; j < 4; j++) part[base + j] = acc[j];
}

__global__ __launch_bounds__(1024) void k_kv_reduce(const float* __restrict__ part,
                                                    float* __restrict__ kv) {
  int bh = blockIdx.x, o = threadIdx.x;
  float s = 0.f;
  #pragma unroll
  for (int p = 0; p < 16; p++) s += part[((size_t)bh * 16 + p) * 1024 + o];
  kv[(size_t)bh * 1024 + o] = s * (1.0f / 16384.0f);
}

// ------- attn: ATT[b,n,h*32+e] = sum_d Q[b,n,h*32+d] * kv[b,h,d,e] -----------
__global__ __launch_bounds__(256) void k_attn(const u16* __restrict__ Q,
                                              const float* __restrict__ kv,
                                              u16* __restrict__ ATT) {
  __shared__ float kvl[8][32][32];
  __shared__ float qrow[256];
  int tid = threadIdx.x;
  int b = blockIdx.x;
  int t0 = blockIdx.y * 128;
  for (int idx = tid; idx < 8192; idx += 256)
    kvl[idx >> 10][(idx >> 5) & 31][idx & 31] = kv[(size_t)b * 8192 + idx];
  int h = tid >> 5, e = tid & 31;
  for (int t = 0; t < 128; t++) {
    __syncthreads();
    qrow[tid] = b2f(Q[((size_t)b * 16384 + t0 + t) * Cch + tid]);
    __syncthreads();
    float s = 0.f;
    #pragma unroll 8
    for (int d = 0; d < 32; d++) s += qrow[h * 32 + d] * kvl[h][d][e];
    ATT[((size_t)b * 16384 + t0 + t) * Cch + tid] = f2b(s);
  }
}

extern "C" void kernel_launch(void* const* d_in, const int* in_sizes, int n_in,
                              void* d_out, int out_size, void* d_ws, size_t ws_size,
                              hipStream_t stream) {
  (void)in_sizes; (void)n_in; (void)out_size; (void)ws_size;
  const float* x    = (const float*)d_in[0];
  const float* w1   = (const float*)d_in[1];
  const float* b1   = (const float*)d_in[2];
  const float* w2   = (const float*)d_in[3];
  const float* b2   = (const float*)d_in[4];
  const float* wq   = (const float*)d_in[5];
  const float* bq   = (const float*)d_in[6];
  const float* wk   = (const float*)d_in[7];
  const float* bk   = (const float*)d_in[8];
  const float* wv   = (const float*)d_in[9];
  const float* bv   = (const float*)d_in[10];
  const float* lnkg = (const float*)d_in[11];
  const float* lnkb = (const float*)d_in[12];
  const float* lnvg = (const float*)d_in[13];
  const float* lnvb = (const float*)d_in[14];
  const float* wo   = (const float*)d_in[15];
  const float* bo   = (const float*)d_in[16];
  const float* wup  = (const float*)d_in[17];
  const float* bup  = (const float*)d_in[18];
  const float* wdn  = (const float*)d_in[19];
  const float* bdn  = (const float*)d_in[20];
  const float* n1g  = (const float*)d_in[21];
  const float* n1b  = (const float*)d_in[22];
  const float* n2g  = (const float*)d_in[23];
  const float* n2b  = (const float*)d_in[24];
  const float* n3g  = (const float*)d_in[25];
  const float* n3b  = (const float*)d_in[26];

  // ws layout unchanged (max 51,970,048). MLP weight packs live in d_out
  // (scratch until the FFN overwrites every byte of it).
  char* ws = (char*)d_ws;
  u16* A    = (u16*)(ws + 0);
  u16* S1r  = (u16*)(ws + 16777216);
  u16* S1i  = (u16*)(ws + 25296896);
  u16* S2r  = (u16*)(ws + 33816576);
  u16* S2i  = (u16*)(ws + 42336256);
  u16* X1   = (u16*)(ws + 16777216);
  u16* Vb   = (u16*)(ws + 16777216);
  u16* Qb   = (u16*)(ws + 16777216);
  u16* X2   = (u16*)(ws + 16777216);
  u16* Kb   = (u16*)(ws + 33816576);
  u16* ATT  = (u16*)(ws + 33816576);
  u16* UP   = (u16*)(ws + 33816576);
  u16* wq_b = (u16*)(ws + 33554432);
  u16* wk_b = (u16*)(ws + 33685504);
  u16* wv_b = (u16*)(ws + 50593792);
  u16* wo_b = (u16*)(ws + 50724864);
  u16* wup_b = (u16*)(ws + 16777216);
  u16* wdn_b = (u16*)(ws + 17825792);
  u16* TW   = (u16*)(ws + 50855936);
  float* KVp = (float*)(ws + 50855936);
  float* KVb = (float*)(ws + 51904512);
  float* outp = (float*)d_out;
  u16* W1h = (u16*)d_out;
  u16* W1l = W1h + 131072;
  u16* W2h = W1h + 262144;
  u16* W2l = W1h + 393216;

  u16 *Cf_h = TW + 0 * 16384, *Cf_l = TW + 1 * 16384;
  u16 *Sf_h = TW + 2 * 16384, *Sf_l = TW + 3 * 16384;
  u16 *Snf_h = TW + 4 * 16384, *Snf_l = TW + 5 * 16384;
  u16 *Cu_h = TW + 6 * 16384, *Cu_l = TW + 7 * 16384;
  u16 *Su_h = TW + 8 * 16384, *Su_l = TW + 9 * 16384;
  u16 *Snu_h = TW + 10 * 16384, *Snu_l = TW + 11 * 16384;
  u16 *Wm_h = TW + 196608, *Wm_l = TW + 217088;

  k_twid<<<128, 128, 0, stream>>>(TW);
  k_wpack<<<1024, 256, 0, stream>>>(w1, w2, W1h, W1l, W2h, W2l);

  // ---- AFNO: x1 = x + ln1(x) + irfft2(shrink(mlp(rfft2(ln1(x))))) ----
  k_ln<1><<<8192, 256, 0, stream>>>((const void*)x, n1g, n1b, A);
  k_dftw_m<<<dim3(256, 2, 2), 256, 0, stream>>>(A, Cu_h, Cu_l, Snu_h, Snu_l, S1r, S1i);
  k_dfth_m<<<dim3(130, 4), 256, 0, stream>>>(S1r, S1i, Cf_h, Cf_l, Sf_h, Sf_l, Snf_h, Snf_l, S2r, S2i);
  k_afno_mfma<<<dim3(16, 260), 256, 0, stream>>>(S2r, S2i, W1h, W1l, W2h, W2l, b1, b2, S1r, S1i);
  k_dfth_m<<<dim3(130, 4), 256, 0, stream>>>(S1r, S1i, Cu_h, Cu_l, Snu_h, Snu_l, Su_h, Su_l, S2r, S2i);
  k_irfft_m<<<dim3(256, 2), 256, 0, stream>>>(S2r, S2i, Wm_h, Wm_l, x, A, X1);

  // ---- convert QKV/O weights to bf16 (dead S1i/S2i slack) ----
  k_cvt<<<256, 256, 0, stream>>>(wq, wq_b, 65536);
  k_cvt<<<256, 256, 0, stream>>>(wk, wk_b, 65536);
  k_cvt<<<256, 256, 0, stream>>>(wv, wv_b, 65536);
  k_cvt<<<256, 256, 0, stream>>>(wo, wo_b, 65536);

  // ---- Galerkin: x2 = ln2(x1) + wo(attn) ; residual = LN2 OUTPUT ----
  k_ln<0><<<8192, 256, 0, stream>>>((const void*)X1, n2g, n2b, A);
  k_mgemm<0, 0, 0><<<dim3(256, 2), 256, 0, stream>>>(A, wk_b, bk, nullptr, (void*)Kb, 32768, 256, 256);
  k_mgemm<0, 0, 0><<<dim3(256, 2), 256, 0, stream>>>(A, wv_b, bv, nullptr, (void*)Vb, 32768, 256, 256);
  k_lnhead<<<8192, 256, 0, stream>>>(Kb, lnkg, lnkb);
  k_lnhead<<<8192, 256, 0, stream>>>(Vb, lnvg, lnvb);
  k_kv_partial<<<dim3(16, 16), 256, 0, stream>>>(Kb, Vb, KVp);
  k_kv_reduce<<<16, 1024, 0, stream>>>(KVp, KVb);
  k_mgemm<0, 0, 0><<<dim3(256, 2), 256, 0, stream>>>(A, wq_b, bq, nullptr, (void*)Qb, 32768, 256, 256);
  k_attn<<<dim3(2, 128), 256, 0, stream>>>(Qb, KVb, ATT);
  k_mgemm<0, 1, 0><<<dim3(256, 2), 256, 0, stream>>>(ATT, wo_b, bo, A, (void*)X2, 32768, 256, 256);

  // ---- FFN: out = ln3(x2) + down(gelu(up(ln3))) ; residual = LN3 OUTPUT ----
  k_ln<0><<<8192, 256, 0, stream>>>((const void*)X2, n3g, n3b, A);
  k_cvt<<<2048, 256, 0, stream>>>(wup, wup_b, 524288);
  k_cvt<<<2048, 256, 0, stream>>>(wdn, wdn_b, 524288);
  for (int c = 0; c < 8; c++) {
    const u16* Ac = A + (size_t)c * 4096 * 256;
    k_mgemm<1, 0, 0><<<dim3(32, 16), 256, 0, stream>>>(Ac, wup_b, bup, nullptr, (void*)UP, 4096, 2048, 256);
    k_mgemm<0, 1, 1><<<dim3(32, 2), 256, 0, stream>>>(UP, wdn_b, bdn, Ac, (void*)(outp + (size_t)c * 4096 * 256), 4096, 256, 2048);
  }
}

// Round 11
// 948.577 us; speedup vs baseline: 3.3696x; 1.0815x over previous
//
#include <hip/hip_runtime.h>

// InvariantBlock: AFNO spectral block + Galerkin linear attention + GELU FFN
// B=2 H=128 W=128 C=256; tokens 32768; KW=65; HEADS=8 DH=32; NB=16 BS=16 HID=128
// d_in / d_out FP32; intermediates bf16 in ws. Accumulation fp32.
// R10->R11: k_attn -> MFMA (k_attn_m): A=Q direct-global, B=kvT hi/lo bf16
// (fp32-accurate), no LDS/barriers, grid 4096 blocks. kv_reduce emits kvT.

typedef unsigned short u16;
typedef unsigned int u32;
typedef __attribute__((ext_vector_type(8))) short bf16x8;
typedef __attribute__((ext_vector_type(8))) unsigned short u16x8;
typedef __attribute__((ext_vector_type(4))) float f32x4;
#define DEV __device__ __forceinline__

constexpr int Cch = 256;
constexpr float EPSN = 1e-5f, LAM = 0.01f;
constexpr float TWO_PI = 6.283185307179586f;

DEV float b2f(u16 u) { return __uint_as_float(((u32)u) << 16); }
DEV u16 f2b(float f) {
  u32 x = __float_as_uint(f);
  return (u16)((x + 0x7FFFu + ((x >> 16) & 1u)) >> 16);
}

// ---------------- twiddle matrices (hi/lo split bf16) ------------------------
DEV void put2(u16* tw, int m, int idx, float v) {
  u16 hi = f2b(v);
  tw[m * 16384 + idx] = hi;
  tw[(m + 1) * 16384 + idx] = f2b(v - b2f(hi));
}

__global__ __launch_bounds__(128) void k_twid(u16* __restrict__ tw) {
  int p = blockIdx.x, q = threadIdx.x;
  int idx = p * 128 + q;
  float ang = TWO_PI * (float)((p * q) & 127) * (1.0f / 128.0f);
  float c = cosf(ang), s = sinf(ang);
  put2(tw, 0, idx, c * (1.0f / 128.0f));
  put2(tw, 2, idx, s * (1.0f / 128.0f));
  put2(tw, 4, idx, -s * (1.0f / 128.0f));
  put2(tw, 6, idx, c);
  put2(tw, 8, idx, s);
  put2(tw, 10, idx, -s);
  u16* wmh = tw + 196608;
  u16* wml = tw + 217088;
  for (int k = q; k < 160; k += 128) {
    float v = 0.0f;
    if (k < 65) {
      float sc = (k == 0 || k == 64) ? 1.0f : 2.0f;
      v = sc * cosf(TWO_PI * (float)((p * k) & 127) * (1.0f / 128.0f)) * (1.0f / 128.0f);
    } else if (k < 130) {
      int kk = k - 65;
      float sc = (kk == 0 || kk == 64) ? 1.0f : 2.0f;
      v = -sc * sinf(TWO_PI * (float)((p * kk) & 127) * (1.0f / 128.0f)) * (1.0f / 128.0f);
    }
    u16 hi = f2b(v);
    wmh[p * 160 + k] = hi;
    wml[p * 160 + k] = f2b(v - b2f(hi));
  }
}

// ------- pack AFNO MLP weights as hi/lo bf16 GEMM operands -------------------
__global__ __launch_bounds__(256) void k_wpack(const float* __restrict__ w1,
                                               const float* __restrict__ w2,
                                               u16* __restrict__ W1h, u16* __restrict__ W1l,
                                               u16* __restrict__ W2h, u16* __restrict__ W2l) {
  int idx = blockIdx.x * 256 + threadIdx.x;
  if (idx < 131072) {
    int n = idx >> 13, rem = idx & 8191;
    int out = rem >> 5, k = rem & 31;
    float v;
    if (out < 128)
      v = (k < 16) ? w1[((size_t)n * 16 + k) * 128 + out]
                   : -w1[((size_t)(16 + n) * 16 + (k - 16)) * 128 + out];
    else {
      int o = out - 128;
      v = (k < 16) ? w1[((size_t)(16 + n) * 16 + k) * 128 + o]
                   : w1[((size_t)n * 16 + (k - 16)) * 128 + o];
    }
    u16 hi = f2b(v);
    W1h[idx] = hi; W1l[idx] = f2b(v - b2f(hi));
  } else if (idx < 262144) {
    int id2 = idx - 131072;
    int n = id2 >> 13, rem = id2 & 8191;
    int out2 = rem >> 8, k = rem & 255;
    float v;
    if (out2 < 16)
      v = (k < 128) ? w2[((size_t)n * 128 + k) * 16 + out2]
                    : -w2[((size_t)(16 + n) * 128 + (k - 128)) * 16 + out2];
    else {
      int o = out2 - 16;
      v = (k < 128) ? w2[((size_t)(16 + n) * 128 + k) * 16 + o]
                    : w2[((size_t)n * 128 + (k - 128)) * 16 + o];
    }
    u16 hi = f2b(v);
    W2h[id2] = hi; W2l[id2] = f2b(v - b2f(hi));
  }
}

// ---------------- fp32 -> bf16 weight convert --------------------------------
__global__ __launch_bounds__(256) void k_cvt(const float* __restrict__ src,
                                             u16* __restrict__ dst, int n) {
  int i = blockIdx.x * 256 + threadIdx.x;
  if (i < n) dst[i] = f2b(src[i]);
}

// ---------------- LayerNorm over C=256; INF=1 fp32 input, else bf16 ----------
template<int INF>
__global__ __launch_bounds__(256) void k_ln(const void* __restrict__ in,
                                            const float* __restrict__ g,
                                            const float* __restrict__ bta,
                                            u16* __restrict__ out) {
  int tid = threadIdx.x, lane = tid & 63;
  size_t token = (size_t)blockIdx.x * 4 + (tid >> 6);
  int c = lane * 4;
  float v[4];
  if (INF) {
    float4 f = *(const float4*)((const float*)in + token * Cch + c);
    v[0] = f.x; v[1] = f.y; v[2] = f.z; v[3] = f.w;
  } else {
    ushort4 u = *(const ushort4*)((const u16*)in + token * Cch + c);
    v[0] = b2f(u.x); v[1] = b2f(u.y); v[2] = b2f(u.z); v[3] = b2f(u.w);
  }
  float s = v[0] + v[1] + v[2] + v[3];
  #pragma unroll
  for (int m = 1; m < 64; m <<= 1) s += __shfl_xor(s, m);
  float mu = s * (1.0f / 256.0f);
  float q = 0.f;
  #pragma unroll
  for (int j = 0; j < 4; j++) { float d = v[j] - mu; q += d * d; }
  #pragma unroll
  for (int m = 1; m < 64; m <<= 1) q += __shfl_xor(q, m);
  float rs = rsqrtf(q * (1.0f / 256.0f) + EPSN);
  ushort4 o;
  o.x = f2b((v[0] - mu) * rs * g[c + 0] + bta[c + 0]);
  o.y = f2b((v[1] - mu) * rs * g[c + 1] + bta[c + 1]);
  o.z = f2b((v[2] - mu) * rs * g[c + 2] + bta[c + 2]);
  o.w = f2b((v[3] - mu) * rs * g[c + 3] + bta[c + 3]);
  *(ushort4*)(out + token * Cch + c) = o;
}

// ------- MFMA forward rDFT over W: Y[bh,w,c] -> T[bh,kw,c], kw<65 ------------
__global__ __launch_bounds__(256) void k_dftw_m(
    const u16* __restrict__ Yg,
    const u16* __restrict__ A0hi, const u16* __restrict__ A0lo,
    const u16* __restrict__ A1hi, const u16* __restrict__ A1lo,
    u16* __restrict__ Or, u16* __restrict__ Oi) {
  __shared__ u16 Bs[128][40];
  int tid = threadIdx.x;
  int bh = blockIdx.x;
  int c0 = blockIdx.y * 128;
  const u16* Ahi = blockIdx.z ? A1hi : A0hi;
  const u16* Alo = blockIdx.z ? A1lo : A0lo;
  u16* outp = blockIdx.z ? Oi : Or;
  int lane = tid & 63, w = tid >> 6;
  int wm = w >> 1, wn = w & 1;
  int rl = lane & 15, kq = (lane >> 4) * 8, rq = lane >> 4;
  f32x4 acc[4][4] = {};
  for (int k0 = 0; k0 < 128; k0 += 32) {
    __syncthreads();
    for (int idx = tid; idx < 1024; idx += 256) {
      int q = idx >> 5, c4 = (idx & 31) * 4;
      ushort4 v = *(const ushort4*)(Yg + ((size_t)bh * 128 + k0 + q) * 256 + c0 + c4);
      Bs[c4 + 0][q] = v.x; Bs[c4 + 1][q] = v.y;
      Bs[c4 + 2][q] = v.z; Bs[c4 + 3][q] = v.w;
    }
    __syncthreads();
    bf16x8 ah[4], al[4], bf[4];
    #pragma unroll
    for (int i = 0; i < 4; i++) {
      int off = (wm * 64 + i * 16 + rl) * 128 + k0 + kq;
      ah[i] = *(const bf16x8*)(Ahi + off);
      al[i] = *(const bf16x8*)(Alo + off);
    }
    #pragma unroll
    for (int j = 0; j < 4; j++)
      bf[j] = *(const bf16x8*)&Bs[wn * 64 + j * 16 + rl][kq];
    #pragma unroll
    for (int i = 0; i < 4; i++)
      #pragma unroll
      for (int j = 0; j < 4; j++) {
        acc[i][j] = __builtin_amdgcn_mfma_f32_16x16x32_bf16(ah[i], bf[j], acc[i][j], 0, 0, 0);
        acc[i][j] = __builtin_amdgcn_mfma_f32_16x16x32_bf16(al[i], bf[j], acc[i][j], 0, 0, 0);
      }
  }
  #pragma unroll
  for (int i = 0; i < 4; i++)
    #pragma unroll
    for (int j = 0; j < 4; j++)
      #pragma unroll
      for (int r = 0; r < 4; r++) {
        int p = wm * 64 + i * 16 + rq * 4 + r;
        if (p < 65) {
          int c = c0 + wn * 64 + j * 16 + rl;
          outp[((size_t)bh * 65 + p) * 256 + c] = f2b(acc[i][j][r]);
        }
      }
}

// ------- MFMA complex DFT over H for fixed (b,kw): O = C*B1 + Ssel*B2 --------
__global__ __launch_bounds__(256) void k_dfth_m(
    const u16* __restrict__ Br_g, const u16* __restrict__ Bi_g,
    const u16* __restrict__ Chi, const u16* __restrict__ Clo,
    const u16* __restrict__ SRhi, const u16* __restrict__ SRlo,
    const u16* __restrict__ SIhi, const u16* __restrict__ SIlo,
    u16* __restrict__ Or, u16* __restrict__ Oi) {
  __shared__ u16 B1s[128][40], B2s[128][40];
  int tid = threadIdx.x;
  int bk = blockIdx.x;
  int b = bk / 65, kw = bk % 65;
  int c0 = (blockIdx.y & 1) * 128;
  int outI = blockIdx.y >> 1;
  const u16* B1g = outI ? Bi_g : Br_g;
  const u16* B2g = outI ? Br_g : Bi_g;
  const u16* Shi = outI ? SIhi : SRhi;
  const u16* Slo = outI ? SIlo : SRlo;
  u16* outp = outI ? Oi : Or;
  int lane = tid & 63, w = tid >> 6;
  int wm = w >> 1, wn = w & 1;
  int rl = lane & 15, kq = (lane >> 4) * 8, rq = lane >> 4;
  f32x4 acc[4][4] = {};
  for (int k0 = 0; k0 < 128; k0 += 32) {
    __syncthreads();
    for (int idx = tid; idx < 1024; idx += 256) {
      int q = idx >> 5, c4 = (idx & 31) * 4;
      size_t g = (((size_t)b * 128 + k0 + q) * 65 + kw) * 256 + c0 + c4;
      ushort4 v1 = *(const ushort4*)(B1g + g);
      ushort4 v2 = *(const ushort4*)(B2g + g);
      B1s[c4 + 0][q] = v1.x; B1s[c4 + 1][q] = v1.y;
      B1s[c4 + 2][q] = v1.z; B1s[c4 + 3][q] = v1.w;
      B2s[c4 + 0][q] = v2.x; B2s[c4 + 1][q] = v2.y;
      B2s[c4 + 2][q] = v2.z; B2s[c4 + 3][q] = v2.w;
    }
    __syncthreads();
    bf16x8 aCh[4], aCl[4], aSh[4], aSl[4], b1[4], b2[4];
    #pragma unroll
    for (int i = 0; i < 4; i++) {
      int off = (wm * 64 + i * 16 + rl) * 128 + k0 + kq;
      aCh[i] = *(const bf16x8*)(Chi + off);
      aCl[i] = *(const bf16x8*)(Clo + off);
      aSh[i] = *(const bf16x8*)(Shi + off);
      aSl[i] = *(const bf16x8*)(Slo + off);
    }
    #pragma unroll
    for (int j = 0; j < 4; j++) {
      b1[j] = *(const bf16x8*)&B1s[wn * 64 + j * 16 + rl][kq];
      b2[j] = *(const bf16x8*)&B2s[wn * 64 + j * 16 + rl][kq];
    }
    #pragma unroll
    for (int i = 0; i < 4; i++)
      #pragma unroll
      for (int j = 0; j < 4; j++) {
        acc[i][j] = __builtin_amdgcn_mfma_f32_16x16x32_bf16(aCh[i], b1[j], acc[i][j], 0, 0, 0);
        acc[i][j] = __builtin_amdgcn_mfma_f32_16x16x32_bf16(aCl[i], b1[j], acc[i][j], 0, 0, 0);
        acc[i][j] = __builtin_amdgcn_mfma_f32_16x16x32_bf16(aSh[i], b2[j], acc[i][j], 0, 0, 0);
        acc[i][j] = __builtin_amdgcn_mfma_f32_16x16x32_bf16(aSl[i], b2[j], acc[i][j], 0, 0, 0);
      }
  }
  #pragma unroll
  for (int i = 0; i < 4; i++)
    #pragma unroll
    for (int j = 0; j < 4; j++)
      #pragma unroll
      for (int r = 0; r < 4; r++) {
        int p = wm * 64 + i * 16 + rq * 4 + r;
        int c = c0 + wn * 64 + j * 16 + rl;
        outp[(((size_t)b * 128 + p) * 65 + kw) * 256 + c] = f2b(acc[i][j][r]);
      }
}

// ------- MFMA inverse rDFT over W + x + ln1out -> X1. K=160 (65r+65i+pad) ----
__global__ __launch_bounds__(256) void k_irfft_m(
    const u16* __restrict__ Ur, const u16* __restrict__ Ui,
    const u16* __restrict__ Whi, const u16* __restrict__ Wlo,
    const float* __restrict__ x_in, const u16* __restrict__ lnout,
    u16* __restrict__ X1) {
  __shared__ u16 Bs[128][40];
  int tid = threadIdx.x;
  int bh = blockIdx.x;
  int c0 = blockIdx.y * 128;
  int lane = tid & 63, w = tid >> 6;
  int wm = w >> 1, wn = w & 1;
  int rl = lane & 15, kq = (lane >> 4) * 8, rq = lane >> 4;
  f32x4 acc[4][4] = {};
  for (int k0 = 0; k0 < 160; k0 += 32) {
    __syncthreads();
    for (int idx = tid; idx < 1024; idx += 256) {
      int q = idx >> 5, c4 = (idx & 31) * 4;
      int grow = k0 + q;
      ushort4 v;
      if (grow < 65)
        v = *(const ushort4*)(Ur + ((size_t)bh * 65 + grow) * 256 + c0 + c4);
      else if (grow < 130)
        v = *(const ushort4*)(Ui + ((size_t)bh * 65 + grow - 65) * 256 + c0 + c4);
      else
        v = make_ushort4(0, 0, 0, 0);
      Bs[c4 + 0][q] = v.x; Bs[c4 + 1][q] = v.y;
      Bs[c4 + 2][q] = v.z; Bs[c4 + 3][q] = v.w;
    }
    __syncthreads();
    bf16x8 ah[4], al[4], bf[4];
    #pragma unroll
    for (int i = 0; i < 4; i++) {
      int off = (wm * 64 + i * 16 + rl) * 160 + k0 + kq;
      ah[i] = *(const bf16x8*)(Whi + off);
      al[i] = *(const bf16x8*)(Wlo + off);
    }
    #pragma unroll
    for (int j = 0; j < 4; j++)
      bf[j] = *(const bf16x8*)&Bs[wn * 64 + j * 16 + rl][kq];
    #pragma unroll
    for (int i = 0; i < 4; i++)
      #pragma unroll
      for (int j = 0; j < 4; j++) {
        acc[i][j] = __builtin_amdgcn_mfma_f32_16x16x32_bf16(ah[i], bf[j], acc[i][j], 0, 0, 0);
        acc[i][j] = __builtin_amdgcn_mfma_f32_16x16x32_bf16(al[i], bf[j], acc[i][j], 0, 0, 0);
      }
  }
  #pragma unroll
  for (int i = 0; i < 4; i++)
    #pragma unroll
    for (int j = 0; j < 4; j++)
      #pragma unroll
      for (int r = 0; r < 4; r++) {
        int p = wm * 64 + i * 16 + rq * 4 + r;
        int c = c0 + wn * 64 + j * 16 + rl;
        size_t g = ((size_t)bh * 128 + p) * 256 + c;
        X1[g] = f2b(x_in[g] + b2f(lnout[g]) + acc[i][j][r]);
      }
}

// ------- fused AFNO MLP via MFMA -----------------------------------------
__global__ __launch_bounds__(256) void k_afno_mfma(
    const u16* __restrict__ Zr, const u16* __restrict__ Zi,
    const u16* __restrict__ W1h, const u16* __restrict__ W1l,
    const u16* __restrict__ W2h, const u16* __restrict__ W2l,
    const float* __restrict__ b1, const float* __restrict__ b2,
    u16* __restrict__ Or, u16* __restrict__ Oi) {
  __shared__ u16 Zs[64][40];
  __shared__ u16 o1s[32 * 64 * 8];
  int tid = threadIdx.x;
  int n = blockIdx.x;
  int p0 = blockIdx.y * 64;
  int lane = tid & 63, w = tid >> 6;
  int rl = lane & 15, rq = lane >> 4;
  int kq = rq * 8;
  for (int idx = tid; idx < 512; idx += 256) {
    int p = idx >> 3, q4 = (idx & 7) * 4;
    const u16* src = (q4 < 16) ? (Zr + (size_t)(p0 + p) * 256 + n * 16 + q4)
                               : (Zi + (size_t)(p0 + p) * 256 + n * 16 + q4 - 16);
    *(ushort4*)&Zs[p][q4] = *(const ushort4*)src;
  }
  __syncthreads();
  f32x4 a1[4][4] = {};
  bf16x8 bfr[4];
  #pragma unroll
  for (int j = 0; j < 4; j++) bfr[j] = *(const bf16x8*)&Zs[j * 16 + rl][kq];
  #pragma unroll
  for (int i = 0; i < 4; i++) {
    int out = w * 64 + i * 16 + rl;
    bf16x8 ah = *(const bf16x8*)(W1h + ((size_t)n * 256 + out) * 32 + kq);
    bf16x8 al = *(const bf16x8*)(W1l + ((size_t)n * 256 + out) * 32 + kq);
    #pragma unroll
    for (int j = 0; j < 4; j++) {
      a1[i][j] = __builtin_amdgcn_mfma_f32_16x16x32_bf16(ah, bfr[j], a1[i][j], 0, 0, 0);
      a1[i][j] = __builtin_amdgcn_mfma_f32_16x16x32_bf16(al, bfr[j], a1[i][j], 0, 0, 0);
    }
  }
  #pragma unroll
  for (int i = 0; i < 4; i++) {
    float bv[4];
    #pragma unroll
    for (int r = 0; r < 4; r++) {
      int out = w * 64 + i * 16 + rq * 4 + r;
      bv[r] = (out < 128) ? b1[n * 128 + out] : b1[2048 + n * 128 + out - 128];
    }
    #pragma unroll
    for (int j = 0; j < 4; j++)
      #pragma unroll
      for (int r = 0; r < 4; r++) {
        int out = w * 64 + i * 16 + rq * 4 + r;
        int pos = j * 16 + rl;
        float v = fmaxf(a1[i][j][r] + bv[r], 0.0f);
        o1s[((out >> 3) * 64 + pos) * 8 + (out & 7)] = f2b(v);
      }
  }
  __syncthreads();
  f32x4 a2[2] = {};
  #pragma unroll
  for (int k0 = 0; k0 < 256; k0 += 32) {
    bf16x8 bb = *(const bf16x8*)&o1s[(((k0 + kq) >> 3) * 64 + w * 16 + rl) * 8];
    #pragma unroll
    for (int i = 0; i < 2; i++) {
      int out2 = i * 16 + rl;
      bf16x8 ah = *(const bf16x8*)(W2h + ((size_t)n * 32 + out2) * 256 + k0 + kq);
      bf16x8 al = *(const bf16x8*)(W2l + ((size_t)n * 32 + out2) * 256 + k0 + kq);
      a2[i] = __builtin_amdgcn_mfma_f32_16x16x32_bf16(ah, bb, a2[i], 0, 0, 0);
      a2[i] = __builtin_amdgcn_mfma_f32_16x16x32_bf16(al, bb, a2[i], 0, 0, 0);
    }
  }
  #pragma unroll
  for (int i = 0; i < 2; i++)
    #pragma unroll
    for (int r = 0; r < 4; r++) {
      int out2 = i * 16 + rq * 4 + r;
      float bv = (out2 < 16) ? b2[n * 16 + out2] : b2[256 + n * 16 + out2 - 16];
      float v = a2[i][r] + bv;
      v = copysignf(fmaxf(fabsf(v) - LAM, 0.0f), v);
      size_t g = (size_t)(p0 + w * 16 + rl) * 256 + n * 16 + ((out2 < 16) ? out2 : out2 - 16);
      if (out2 < 16) Or[g] = f2b(v);
      else Oi[g] = f2b(v);
    }
}

// ------- MFMA GEMM: C[m,n] = act(A[m,k]*B[n,k] + bias[n]) (+resid) -----------
template<int ACT, int RT, int OUTF>
__global__ __launch_bounds__(256) void k_mgemm(const u16* __restrict__ Ap,
                                               const u16* __restrict__ Bp,
                                               const float* __restrict__ bias,
                                               const u16* __restrict__ resid,
                                               void* __restrict__ Cp,
                                               int M, int N, int K) {
  __shared__ u16 As[128][40];
  __shared__ u16 Bs[128][40];
  int tid = threadIdx.x;
  int lane = tid & 63, w = tid >> 6;
  int wm = w >> 1, wn = w & 1;
  int m0 = blockIdx.x * 128, n0 = blockIdx.y * 128;
  int srow = tid >> 1, sseg = tid & 1;
  const u16* ag = Ap + (size_t)(m0 + srow) * K + sseg * 16;
  const u16* bg = Bp + (size_t)(n0 + srow) * K + sseg * 16;
  int rl = lane & 15, kq = (lane >> 4) * 8;
  f32x4 acc[4][4] = {};
  for (int k0 = 0; k0 < K; k0 += 32) {
    __syncthreads();
    *(u16x8*)&As[srow][sseg * 16]     = *(const u16x8*)(ag + k0);
    *(u16x8*)&As[srow][sseg * 16 + 8] = *(const u16x8*)(ag + k0 + 8);
    *(u16x8*)&Bs[srow][sseg * 16]     = *(const u16x8*)(bg + k0);
    *(u16x8*)&Bs[srow][sseg * 16 + 8] = *(const u16x8*)(bg + k0 + 8);
    __syncthreads();
    bf16x8 af[4], bf[4];
    #pragma unroll
    for (int i = 0; i < 4; i++) {
      af[i] = *(const bf16x8*)&As[wm * 64 + i * 16 + rl][kq];
      bf[i] = *(const bf16x8*)&Bs[wn * 64 + i * 16 + rl][kq];
    }
    #pragma unroll
    for (int i = 0; i < 4; i++)
      #pragma unroll
      for (int j = 0; j < 4; j++)
        acc[i][j] = __builtin_amdgcn_mfma_f32_16x16x32_bf16(af[i], bf[j], acc[i][j], 0, 0, 0);
  }
  int rq = lane >> 4;
  #pragma unroll
  for (int i = 0; i < 4; i++) {
    #pragma unroll
    for (int j = 0; j < 4; j++) {
      #pragma unroll
      for (int r = 0; r < 4; r++) {
        int m = m0 + wm * 64 + i * 16 + rq * 4 + r;
        int n = n0 + wn * 64 + j * 16 + rl;
        float v = acc[i][j][r] + bias[n];
        if (ACT) v = 0.5f * v * (1.0f + erff(v * 0.70710678118654752f));
        if (RT) v += b2f(resid[(size_t)m * N + n]);
        if (OUTF) ((float*)Cp)[(size_t)m * N + n] = v;
        else ((u16*)Cp)[(size_t)m * N + n] = f2b(v);
      }
    }
  }
}

// ---------------- per-head LN over DH=32, bf16 in-place ----------------------
__global__ __launch_bounds__(256) void k_lnhead(u16* __restrict__ X,
                                                const float* __restrict__ g,
                                                const float* __restrict__ bta) {
  int tid = threadIdx.x, lane = tid & 63;
  size_t token = (size_t)blockIdx.x * 4 + (tid >> 6);
  int c = lane * 4;
  ushort4 u = *(const ushort4*)(X + token * Cch + c);
  float v[4] = {b2f(u.x), b2f(u.y), b2f(u.z), b2f(u.w)};
  float s = v[0] + v[1] + v[2] + v[3];
  s += __shfl_xor(s, 1); s += __shfl_xor(s, 2); s += __shfl_xor(s, 4);
  float mu = s * (1.0f / 32.0f);
  float q = 0.f;
  #pragma unroll
  for (int j = 0; j < 4; j++) { float d = v[j] - mu; q += d * d; }
  q += __shfl_xor(q, 1); q += __shfl_xor(q, 2); q += __shfl_xor(q, 4);
  float rs = rsqrtf(q * (1.0f / 32.0f) + EPSN);
  ushort4 o;
  o.x = f2b((v[0] - mu) * rs * g[c + 0] + bta[c + 0]);
  o.y = f2b((v[1] - mu) * rs * g[c + 1] + bta[c + 1]);
  o.z = f2b((v[2] - mu) * rs * g[c + 2] + bta[c + 2]);
  o.w = f2b((v[3] - mu) * rs * g[c + 3] + bta[c + 3]);
  *(ushort4*)(X + token * Cch + c) = o;
}

// ---------------- kv partial sums over 16 chunks of 1024 tokens --------------
__global__ __launch_bounds__(256) void k_kv_partial(const u16* __restrict__ Kb,
                                                    const u16* __restrict__ Vb,
                                                    float* __restrict__ part) {
  __shared__ float kl[64][33], vl[64][33];
  int tid = threadIdx.x;
  int bh = blockIdx.x;
  int b = bh >> 3, h = bh & 7;
  int n0 = blockIdx.y * 1024;
  int d = tid >> 3, eg = tid & 7;
  float acc[4] = {0.f, 0.f, 0.f, 0.f};
  for (int sub = 0; sub < 16; sub++) {
    __syncthreads();
    for (int idx = tid; idx < 64 * 32; idx += 256) {
      int nn = idx >> 5, c = idx & 31;
      size_t o = ((size_t)(b * 16384 + n0 + sub * 64 + nn)) * Cch + h * 32 + c;
      kl[nn][c] = b2f(Kb[o]); vl[nn][c] = b2f(Vb[o]);
    }
    __syncthreads();
    #pragma unroll 4
    for (int nn = 0; nn < 64; nn++) {
      float kd = kl[nn][d];
      #pragma unroll
      for (int j = 0; j < 4; j++) acc[j] += kd * vl[nn][eg * 4 + j];
    }
  }
  size_t base = ((size_t)bh * 16 + blockIdx.y) * 1024 + d * 32 + eg * 4;
  #pragma unroll
  for (int j = 0; j < 4; j++) part[base + j] = acc[j];
}

// reduce partials -> kvT (transposed [e][d]) hi/lo bf16, fp32-accurate pair
__global__ __launch_bounds__(1024) void k_kv_reduce(const float* __restrict__ part,
                                                    u16* __restrict__ kvTh,
                                                    u16* __restrict__ kvTl) {
  int bh = blockIdx.x, o = threadIdx.x;   // o = d*32+e
  float s = 0.f;
  #pragma unroll
  for (int p = 0; p < 16; p++) s += part[((size_t)bh * 16 + p) * 1024 + o];
  s *= (1.0f / 16384.0f);
  int d = o >> 5, e = o & 31;
  u16 hi = f2b(s);
  kvTh[(size_t)bh * 1024 + e * 32 + d] = hi;
  kvTl[(size_t)bh * 1024 + e * 32 + d] = f2b(s - b2f(hi));
}

// ------- MFMA attn: ATT[t, h*32+e] = sum_d Q[t, h*32+d] * kvT[b,h][e][d] ----
__global__ __launch_bounds__(256) void k_attn_m(const u16* __restrict__ Q,
                                                const u16* __restrict__ kvTh,
                                                const u16* __restrict__ kvTl,
                                                u16* __restrict__ ATT) {
  int tid = threadIdx.x;
  int lane = tid & 63, w = tid >> 6;
  int h = blockIdx.y;
  int t0 = blockIdx.x * 64 + w * 16;
  int b = t0 >> 14;
  int rl = lane & 15, rq = lane >> 4, kq = rq * 8;
  bf16x8 a = *(const bf16x8*)(Q + (size_t)(t0 + rl) * 256 + h * 32 + kq);
  const u16* kh = kvTh + (size_t)(b * 8 + h) * 1024;
  const u16* kl = kvTl + (size_t)(b * 8 + h) * 1024;
  f32x4 acc[2] = {};
  #pragma unroll
  for (int j = 0; j < 2; j++) {
    bf16x8 bh_ = *(const bf16x8*)(kh + (j * 16 + rl) * 32 + kq);
    bf16x8 bl_ = *(const bf16x8*)(kl + (j * 16 + rl) * 32 + kq);
    acc[j] = __builtin_amdgcn_mfma_f32_16x16x32_bf16(a, bh_, acc[j], 0, 0, 0);
    acc[j] = __builtin_amdgcn_mfma_f32_16x16x32_bf16(a, bl_, acc[j], 0, 0, 0);
  }
  #pragma unroll
  for (int j = 0; j < 2; j++)
    #pragma unroll
    for (int r = 0; r < 4; r++)
      ATT[(size_t)(t0 + rq * 4 + r) * 256 + h * 32 + j * 16 + rl] = f2b(acc[j][r]);
}

extern "C" void kernel_launch(void* const* d_in, const int* in_sizes, int n_in,
                              void* d_out, int out_size, void* d_ws, size_t ws_size,
                              hipStream_t stream) {
  (void)in_sizes; (void)n_in; (void)out_size; (void)ws_size;
  const float* x    = (const float*)d_in[0];
  const float* w1   = (const float*)d_in[1];
  const float* b1   = (const float*)d_in[2];
  const float* w2   = (const float*)d_in[3];
  const float* b2   = (const float*)d_in[4];
  const float* wq   = (const float*)d_in[5];
  const float* bq   = (const float*)d_in[6];
  const float* wk   = (const float*)d_in[7];
  const float* bk   = (const float*)d_in[8];
  const float* wv   = (const float*)d_in[9];
  const float* bv   = (const float*)d_in[10];
  const float* lnkg = (const float*)d_in[11];
  const float* lnkb = (const float*)d_in[12];
  const float* lnvg = (const float*)d_in[13];
  const float* lnvb = (const float*)d_in[14];
  const float* wo   = (const float*)d_in[15];
  const float* bo   = (const float*)d_in[16];
  const float* wup  = (const float*)d_in[17];
  const float* bup  = (const float*)d_in[18];
  const float* wdn  = (const float*)d_in[19];
  const float* bdn  = (const float*)d_in[20];
  const float* n1g  = (const float*)d_in[21];
  const float* n1b  = (const float*)d_in[22];
  const float* n2g  = (const float*)d_in[23];
  const float* n2b  = (const float*)d_in[24];
  const float* n3g  = (const float*)d_in[25];
  const float* n3b  = (const float*)d_in[26];

  // ws layout unchanged (max 51,970,048 proven safe). kvT hi/lo fills the
  // 64KB KVb window exactly. MLP packs in d_out (overwritten by FFN).
  char* ws = (char*)d_ws;
  u16* A    = (u16*)(ws + 0);
  u16* S1r  = (u16*)(ws + 16777216);
  u16* S1i  = (u16*)(ws + 25296896);
  u16* S2r  = (u16*)(ws + 33816576);
  u16* S2i  = (u16*)(ws + 42336256);
  u16* X1   = (u16*)(ws + 16777216);
  u16* Vb   = (u16*)(ws + 16777216);
  u16* Qb   = (u16*)(ws + 16777216);
  u16* X2   = (u16*)(ws + 16777216);
  u16* Kb   = (u16*)(ws + 33816576);
  u16* ATT  = (u16*)(ws + 33816576);
  u16* UP   = (u16*)(ws + 33816576);
  u16* wq_b = (u16*)(ws + 33554432);
  u16* wk_b = (u16*)(ws + 33685504);
  u16* wv_b = (u16*)(ws + 50593792);
  u16* wo_b = (u16*)(ws + 50724864);
  u16* wup_b = (u16*)(ws + 16777216);
  u16* wdn_b = (u16*)(ws + 17825792);
  u16* TW   = (u16*)(ws + 50855936);
  float* KVp = (float*)(ws + 50855936);
  u16* kvTh = (u16*)(ws + 51904512);
  u16* kvTl = (u16*)(ws + 51937280);
  float* outp = (float*)d_out;
  u16* W1h = (u16*)d_out;
  u16* W1l = W1h + 131072;
  u16* W2h = W1h + 262144;
  u16* W2l = W1h + 393216;

  u16 *Cf_h = TW + 0 * 16384, *Cf_l = TW + 1 * 16384;
  u16 *Sf_h = TW + 2 * 16384, *Sf_l = TW + 3 * 16384;
  u16 *Snf_h = TW + 4 * 16384, *Snf_l = TW + 5 * 16384;
  u16 *Cu_h = TW + 6 * 16384, *Cu_l = TW + 7 * 16384;
  u16 *Su_h = TW + 8 * 16384, *Su_l = TW + 9 * 16384;
  u16 *Snu_h = TW + 10 * 16384, *Snu_l = TW + 11 * 16384;
  u16 *Wm_h = TW + 196608, *Wm_l = TW + 217088;

  k_twid<<<128, 128, 0, stream>>>(TW);
  k_wpack<<<1024, 256, 0, stream>>>(w1, w2, W1h, W1l, W2h, W2l);

  // ---- AFNO: x1 = x + ln1(x) + irfft2(shrink(mlp(rfft2(ln1(x))))) ----
  k_ln<1><<<8192, 256, 0, stream>>>((const void*)x, n1g, n1b, A);
  k_dftw_m<<<dim3(256, 2, 2), 256, 0, stream>>>(A, Cu_h, Cu_l, Snu_h, Snu_l, S1r, S1i);
  k_dfth_m<<<dim3(130, 4), 256, 0, stream>>>(S1r, S1i, Cf_h, Cf_l, Sf_h, Sf_l, Snf_h, Snf_l, S2r, S2i);
  k_afno_mfma<<<dim3(16, 260), 256, 0, stream>>>(S2r, S2i, W1h, W1l, W2h, W2l, b1, b2, S1r, S1i);
  k_dfth_m<<<dim3(130, 4), 256, 0, stream>>>(S1r, S1i, Cu_h, Cu_l, Snu_h, Snu_l, Su_h, Su_l, S2r, S2i);
  k_irfft_m<<<dim3(256, 2), 256, 0, stream>>>(S2r, S2i, Wm_h, Wm_l, x, A, X1);

  // ---- convert QKV/O weights to bf16 (dead S1i/S2i slack) ----
  k_cvt<<<256, 256, 0, stream>>>(wq, wq_b, 65536);
  k_cvt<<<256, 256, 0, stream>>>(wk, wk_b, 65536);
  k_cvt<<<256, 256, 0, stream>>>(wv, wv_b, 65536);
  k_cvt<<<256, 256, 0, stream>>>(wo, wo_b, 65536);

  // ---- Galerkin: x2 = ln2(x1) + wo(attn) ; residual = LN2 OUTPUT ----
  k_ln<0><<<8192, 256, 0, stream>>>((const void*)X1, n2g, n2b, A);
  k_mgemm<0, 0, 0><<<dim3(256, 2), 256, 0, stream>>>(A, wk_b, bk, nullptr, (void*)Kb, 32768, 256, 256);
  k_mgemm<0, 0, 0><<<dim3(256, 2), 256, 0, stream>>>(A, wv_b, bv, nullptr, (void*)Vb, 32768, 256, 256);
  k_lnhead<<<8192, 256, 0, stream>>>(Kb, lnkg, lnkb);
  k_lnhead<<<8192, 256, 0, stream>>>(Vb, lnvg, lnvb);
  k_kv_partial<<<dim3(16, 16), 256, 0, stream>>>(Kb, Vb, KVp);
  k_kv_reduce<<<16, 1024, 0, stream>>>(KVp, kvTh, kvTl);
  k_mgemm<0, 0, 0><<<dim3(256, 2), 256, 0, stream>>>(A, wq_b, bq, nullptr, (void*)Qb, 32768, 256, 256);
  k_attn_m<<<dim3(512, 8), 256, 0, stream>>>(Qb, kvTh, kvTl, ATT);
  k_mgemm<0, 1, 0><<<dim3(256, 2), 256, 0, stream>>>(ATT, wo_b, bo, A, (void*)X2, 32768, 256, 256);

  // ---- FFN: out = ln3(x2) + down(gelu(up(ln3))) ; residual = LN3 OUTPUT ----
  k_ln<0><<<8192, 256, 0, stream>>>((const void*)X2, n3g, n3b, A);
  k_cvt<<<2048, 256, 0, stream>>>(wup, wup_b, 524288);
  k_cvt<<<2048, 256, 0, stream>>>(wdn, wdn_b, 524288);
  for (int c = 0; c < 8; c++) {
    const u16* Ac = A + (size_t)c * 4096 * 256;
    k_mgemm<1, 0, 0><<<dim3(32, 16), 256, 0, stream>>>(Ac, wup_b, bup, nullptr, (void*)UP, 4096, 2048, 256);
    k_mgemm<0, 1, 1><<<dim3(32, 2), 256, 0, stream>>>(UP, wdn_b, bdn, Ac, (void*)(outp + (size_t)c * 4096 * 256), 4096, 256, 2048);
  }
}

// Round 12
// 902.667 us; speedup vs baseline: 3.5410x; 1.0509x over previous
//
#include <hip/hip_runtime.h>

// InvariantBlock: AFNO spectral block + Galerkin linear attention + GELU FFN
// B=2 H=128 W=128 C=256; tokens 32768; KW=65; HEADS=8 DH=32; NB=16 BS=16 HID=128
// d_in / d_out FP32; intermediates bf16 in ws. Accumulation fp32.
// R11->R12: k_afno_mfma rewritten barrier-free (wave-per-n, direct-global
// frags, wave-private padded o1 buffer); k_dftw_m computes cos+sin from one
// staged tile (grid halved); cvt launches merged.

typedef unsigned short u16;
typedef unsigned int u32;
typedef __attribute__((ext_vector_type(8))) short bf16x8;
typedef __attribute__((ext_vector_type(8))) unsigned short u16x8;
typedef __attribute__((ext_vector_type(4))) float f32x4;
#define DEV __device__ __forceinline__

constexpr int Cch = 256;
constexpr float EPSN = 1e-5f, LAM = 0.01f;
constexpr float TWO_PI = 6.283185307179586f;

DEV float b2f(u16 u) { return __uint_as_float(((u32)u) << 16); }
DEV u16 f2b(float f) {
  u32 x = __float_as_uint(f);
  return (u16)((x + 0x7FFFu + ((x >> 16) & 1u)) >> 16);
}

// ---------------- twiddle matrices (hi/lo split bf16) ------------------------
DEV void put2(u16* tw, int m, int idx, float v) {
  u16 hi = f2b(v);
  tw[m * 16384 + idx] = hi;
  tw[(m + 1) * 16384 + idx] = f2b(v - b2f(hi));
}

__global__ __launch_bounds__(128) void k_twid(u16* __restrict__ tw) {
  int p = blockIdx.x, q = threadIdx.x;
  int idx = p * 128 + q;
  float ang = TWO_PI * (float)((p * q) & 127) * (1.0f / 128.0f);
  float c = cosf(ang), s = sinf(ang);
  put2(tw, 0, idx, c * (1.0f / 128.0f));
  put2(tw, 2, idx, s * (1.0f / 128.0f));
  put2(tw, 4, idx, -s * (1.0f / 128.0f));
  put2(tw, 6, idx, c);
  put2(tw, 8, idx, s);
  put2(tw, 10, idx, -s);
  u16* wmh = tw + 196608;
  u16* wml = tw + 217088;
  for (int k = q; k < 160; k += 128) {
    float v = 0.0f;
    if (k < 65) {
      float sc = (k == 0 || k == 64) ? 1.0f : 2.0f;
      v = sc * cosf(TWO_PI * (float)((p * k) & 127) * (1.0f / 128.0f)) * (1.0f / 128.0f);
    } else if (k < 130) {
      int kk = k - 65;
      float sc = (kk == 0 || kk == 64) ? 1.0f : 2.0f;
      v = -sc * sinf(TWO_PI * (float)((p * kk) & 127) * (1.0f / 128.0f)) * (1.0f / 128.0f);
    }
    u16 hi = f2b(v);
    wmh[p * 160 + k] = hi;
    wml[p * 160 + k] = f2b(v - b2f(hi));
  }
}

// ------- pack AFNO MLP weights as hi/lo bf16 GEMM operands -------------------
__global__ __launch_bounds__(256) void k_wpack(const float* __restrict__ w1,
                                               const float* __restrict__ w2,
                                               u16* __restrict__ W1h, u16* __restrict__ W1l,
                                               u16* __restrict__ W2h, u16* __restrict__ W2l) {
  int idx = blockIdx.x * 256 + threadIdx.x;
  if (idx < 131072) {
    int n = idx >> 13, rem = idx & 8191;
    int out = rem >> 5, k = rem & 31;
    float v;
    if (out < 128)
      v = (k < 16) ? w1[((size_t)n * 16 + k) * 128 + out]
                   : -w1[((size_t)(16 + n) * 16 + (k - 16)) * 128 + out];
    else {
      int o = out - 128;
      v = (k < 16) ? w1[((size_t)(16 + n) * 16 + k) * 128 + o]
                   : w1[((size_t)n * 16 + (k - 16)) * 128 + o];
    }
    u16 hi = f2b(v);
    W1h[idx] = hi; W1l[idx] = f2b(v - b2f(hi));
  } else if (idx < 262144) {
    int id2 = idx - 131072;
    int n = id2 >> 13, rem = id2 & 8191;
    int out2 = rem >> 8, k = rem & 255;
    float v;
    if (out2 < 16)
      v = (k < 128) ? w2[((size_t)n * 128 + k) * 16 + out2]
                    : -w2[((size_t)(16 + n) * 128 + (k - 128)) * 16 + out2];
    else {
      int o = out2 - 16;
      v = (k < 128) ? w2[((size_t)(16 + n) * 128 + k) * 16 + o]
                    : w2[((size_t)n * 128 + (k - 128)) * 16 + o];
    }
    u16 hi = f2b(v);
    W2h[id2] = hi; W2l[id2] = f2b(v - b2f(hi));
  }
}

// ---------------- fp32 -> bf16 weight convert (two arrays) -------------------
__global__ __launch_bounds__(256) void k_cvt2(const float* __restrict__ s0,
                                              const float* __restrict__ s1,
                                              u16* __restrict__ d0,
                                              u16* __restrict__ d1, int n) {
  int i = blockIdx.x * 256 + threadIdx.x;
  if (i < n) { d0[i] = f2b(s0[i]); d1[i] = f2b(s1[i]); }
}

// ---------------- LayerNorm over C=256; INF=1 fp32 input, else bf16 ----------
template<int INF>
__global__ __launch_bounds__(256) void k_ln(const void* __restrict__ in,
                                            const float* __restrict__ g,
                                            const float* __restrict__ bta,
                                            u16* __restrict__ out) {
  int tid = threadIdx.x, lane = tid & 63;
  size_t token = (size_t)blockIdx.x * 4 + (tid >> 6);
  int c = lane * 4;
  float v[4];
  if (INF) {
    float4 f = *(const float4*)((const float*)in + token * Cch + c);
    v[0] = f.x; v[1] = f.y; v[2] = f.z; v[3] = f.w;
  } else {
    ushort4 u = *(const ushort4*)((const u16*)in + token * Cch + c);
    v[0] = b2f(u.x); v[1] = b2f(u.y); v[2] = b2f(u.z); v[3] = b2f(u.w);
  }
  float s = v[0] + v[1] + v[2] + v[3];
  #pragma unroll
  for (int m = 1; m < 64; m <<= 1) s += __shfl_xor(s, m);
  float mu = s * (1.0f / 256.0f);
  float q = 0.f;
  #pragma unroll
  for (int j = 0; j < 4; j++) { float d = v[j] - mu; q += d * d; }
  #pragma unroll
  for (int m = 1; m < 64; m <<= 1) q += __shfl_xor(q, m);
  float rs = rsqrtf(q * (1.0f / 256.0f) + EPSN);
  ushort4 o;
  o.x = f2b((v[0] - mu) * rs * g[c + 0] + bta[c + 0]);
  o.y = f2b((v[1] - mu) * rs * g[c + 1] + bta[c + 1]);
  o.z = f2b((v[2] - mu) * rs * g[c + 2] + bta[c + 2]);
  o.w = f2b((v[3] - mu) * rs * g[c + 3] + bta[c + 3]);
  *(ushort4*)(out + token * Cch + c) = o;
}

// ------- MFMA forward rDFT over W (cos+sin from one staged tile) -------------
// Or = Cu * Y ; Oi = Snu * Y.  M=128 (pad of 65), K=128. grid (256, 2)
__global__ __launch_bounds__(256) void k_dftw_m(
    const u16* __restrict__ Yg,
    const u16* __restrict__ Chi_, const u16* __restrict__ Clo_,
    const u16* __restrict__ Shi_, const u16* __restrict__ Slo_,
    u16* __restrict__ Or, u16* __restrict__ Oi) {
  __shared__ u16 Bs[128][40];
  int tid = threadIdx.x;
  int bh = blockIdx.x;
  int c0 = blockIdx.y * 128;
  int lane = tid & 63, w = tid >> 6;
  int wm = w >> 1, wn = w & 1;
  int rl = lane & 15, kq = (lane >> 4) * 8, rq = lane >> 4;
  f32x4 accC[4][4] = {};
  f32x4 accS[4][4] = {};
  for (int k0 = 0; k0 < 128; k0 += 32) {
    __syncthreads();
    for (int idx = tid; idx < 1024; idx += 256) {
      int q = idx >> 5, c4 = (idx & 31) * 4;
      ushort4 v = *(const ushort4*)(Yg + ((size_t)bh * 128 + k0 + q) * 256 + c0 + c4);
      Bs[c4 + 0][q] = v.x; Bs[c4 + 1][q] = v.y;
      Bs[c4 + 2][q] = v.z; Bs[c4 + 3][q] = v.w;
    }
    __syncthreads();
    bf16x8 aCh[4], aCl[4], aSh[4], aSl[4], bf[4];
    #pragma unroll
    for (int i = 0; i < 4; i++) {
      int off = (wm * 64 + i * 16 + rl) * 128 + k0 + kq;
      aCh[i] = *(const bf16x8*)(Chi_ + off);
      aCl[i] = *(const bf16x8*)(Clo_ + off);
      aSh[i] = *(const bf16x8*)(Shi_ + off);
      aSl[i] = *(const bf16x8*)(Slo_ + off);
    }
    #pragma unroll
    for (int j = 0; j < 4; j++)
      bf[j] = *(const bf16x8*)&Bs[wn * 64 + j * 16 + rl][kq];
    #pragma unroll
    for (int i = 0; i < 4; i++)
      #pragma unroll
      for (int j = 0; j < 4; j++) {
        accC[i][j] = __builtin_amdgcn_mfma_f32_16x16x32_bf16(aCh[i], bf[j], accC[i][j], 0, 0, 0);
        accC[i][j] = __builtin_amdgcn_mfma_f32_16x16x32_bf16(aCl[i], bf[j], accC[i][j], 0, 0, 0);
        accS[i][j] = __builtin_amdgcn_mfma_f32_16x16x32_bf16(aSh[i], bf[j], accS[i][j], 0, 0, 0);
        accS[i][j] = __builtin_amdgcn_mfma_f32_16x16x32_bf16(aSl[i], bf[j], accS[i][j], 0, 0, 0);
      }
  }
  #pragma unroll
  for (int i = 0; i < 4; i++)
    #pragma unroll
    for (int j = 0; j < 4; j++)
      #pragma unroll
      for (int r = 0; r < 4; r++) {
        int p = wm * 64 + i * 16 + rq * 4 + r;
        if (p < 65) {
          int c = c0 + wn * 64 + j * 16 + rl;
          size_t g = ((size_t)bh * 65 + p) * 256 + c;
          Or[g] = f2b(accC[i][j][r]);
          Oi[g] = f2b(accS[i][j][r]);
        }
      }
}

// ------- MFMA complex DFT over H for fixed (b,kw): O = C*B1 + Ssel*B2 --------
__global__ __launch_bounds__(256) void k_dfth_m(
    const u16* __restrict__ Br_g, const u16* __restrict__ Bi_g,
    const u16* __restrict__ Chi, const u16* __restrict__ Clo,
    const u16* __restrict__ SRhi, const u16* __restrict__ SRlo,
    const u16* __restrict__ SIhi, const u16* __restrict__ SIlo,
    u16* __restrict__ Or, u16* __restrict__ Oi) {
  __shared__ u16 B1s[128][40], B2s[128][40];
  int tid = threadIdx.x;
  int bk = blockIdx.x;
  int b = bk / 65, kw = bk % 65;
  int c0 = (blockIdx.y & 1) * 128;
  int outI = blockIdx.y >> 1;
  const u16* B1g = outI ? Bi_g : Br_g;
  const u16* B2g = outI ? Br_g : Bi_g;
  const u16* Shi = outI ? SIhi : SRhi;
  const u16* Slo = outI ? SIlo : SRlo;
  u16* outp = outI ? Oi : Or;
  int lane = tid & 63, w = tid >> 6;
  int wm = w >> 1, wn = w & 1;
  int rl = lane & 15, kq = (lane >> 4) * 8, rq = lane >> 4;
  f32x4 acc[4][4] = {};
  for (int k0 = 0; k0 < 128; k0 += 32) {
    __syncthreads();
    for (int idx = tid; idx < 1024; idx += 256) {
      int q = idx >> 5, c4 = (idx & 31) * 4;
      size_t g = (((size_t)b * 128 + k0 + q) * 65 + kw) * 256 + c0 + c4;
      ushort4 v1 = *(const ushort4*)(B1g + g);
      ushort4 v2 = *(const ushort4*)(B2g + g);
      B1s[c4 + 0][q] = v1.x; B1s[c4 + 1][q] = v1.y;
      B1s[c4 + 2][q] = v1.z; B1s[c4 + 3][q] = v1.w;
      B2s[c4 + 0][q] = v2.x; B2s[c4 + 1][q] = v2.y;
      B2s[c4 + 2][q] = v2.z; B2s[c4 + 3][q] = v2.w;
    }
    __syncthreads();
    bf16x8 aCh[4], aCl[4], aSh[4], aSl[4], b1[4], b2[4];
    #pragma unroll
    for (int i = 0; i < 4; i++) {
      int off = (wm * 64 + i * 16 + rl) * 128 + k0 + kq;
      aCh[i] = *(const bf16x8*)(Chi + off);
      aCl[i] = *(const bf16x8*)(Clo + off);
      aSh[i] = *(const bf16x8*)(Shi + off);
      aSl[i] = *(const bf16x8*)(Slo + off);
    }
    #pragma unroll
    for (int j = 0; j < 4; j++) {
      b1[j] = *(const bf16x8*)&B1s[wn * 64 + j * 16 + rl][kq];
      b2[j] = *(const bf16x8*)&B2s[wn * 64 + j * 16 + rl][kq];
    }
    #pragma unroll
    for (int i = 0; i < 4; i++)
      #pragma unroll
      for (int j = 0; j < 4; j++) {
        acc[i][j] = __builtin_amdgcn_mfma_f32_16x16x32_bf16(aCh[i], b1[j], acc[i][j], 0, 0, 0);
        acc[i][j] = __builtin_amdgcn_mfma_f32_16x16x32_bf16(aCl[i], b1[j], acc[i][j], 0, 0, 0);
        acc[i][j] = __builtin_amdgcn_mfma_f32_16x16x32_bf16(aSh[i], b2[j], acc[i][j], 0, 0, 0);
        acc[i][j] = __builtin_amdgcn_mfma_f32_16x16x32_bf16(aSl[i], b2[j], acc[i][j], 0, 0, 0);
      }
  }
  #pragma unroll
  for (int i = 0; i < 4; i++)
    #pragma unroll
    for (int j = 0; j < 4; j++)
      #pragma unroll
      for (int r = 0; r < 4; r++) {
        int p = wm * 64 + i * 16 + rq * 4 + r;
        int c = c0 + wn * 64 + j * 16 + rl;
        outp[(((size_t)b * 128 + p) * 65 + kw) * 256 + c] = f2b(acc[i][j][r]);
      }
}

// ------- MFMA inverse rDFT over W + x + ln1out -> X1. K=160 (65r+65i+pad) ----
__global__ __launch_bounds__(256) void k_irfft_m(
    const u16* __restrict__ Ur, const u16* __restrict__ Ui,
    const u16* __restrict__ Whi, const u16* __restrict__ Wlo,
    const float* __restrict__ x_in, const u16* __restrict__ lnout,
    u16* __restrict__ X1) {
  __shared__ u16 Bs[128][40];
  int tid = threadIdx.x;
  int bh = blockIdx.x;
  int c0 = blockIdx.y * 128;
  int lane = tid & 63, w = tid >> 6;
  int wm = w >> 1, wn = w & 1;
  int rl = lane & 15, kq = (lane >> 4) * 8, rq = lane >> 4;
  f32x4 acc[4][4] = {};
  for (int k0 = 0; k0 < 160; k0 += 32) {
    __syncthreads();
    for (int idx = tid; idx < 1024; idx += 256) {
      int q = idx >> 5, c4 = (idx & 31) * 4;
      int grow = k0 + q;
      ushort4 v;
      if (grow < 65)
        v = *(const ushort4*)(Ur + ((size_t)bh * 65 + grow) * 256 + c0 + c4);
      else if (grow < 130)
        v = *(const ushort4*)(Ui + ((size_t)bh * 65 + grow - 65) * 256 + c0 + c4);
      else
        v = make_ushort4(0, 0, 0, 0);
      Bs[c4 + 0][q] = v.x; Bs[c4 + 1][q] = v.y;
      Bs[c4 + 2][q] = v.z; Bs[c4 + 3][q] = v.w;
    }
    __syncthreads();
    bf16x8 ah[4], al[4], bf[4];
    #pragma unroll
    for (int i = 0; i < 4; i++) {
      int off = (wm * 64 + i * 16 + rl) * 160 + k0 + kq;
      ah[i] = *(const bf16x8*)(Whi + off);
      al[i] = *(const bf16x8*)(Wlo + off);
    }
    #pragma unroll
    for (int j = 0; j < 4; j++)
      bf[j] = *(const bf16x8*)&Bs[wn * 64 + j * 16 + rl][kq];
    #pragma unroll
    for (int i = 0; i < 4; i++)
      #pragma unroll
      for (int j = 0; j < 4; j++) {
        acc[i][j] = __builtin_amdgcn_mfma_f32_16x16x32_bf16(ah[i], bf[j], acc[i][j], 0, 0, 0);
        acc[i][j] = __builtin_amdgcn_mfma_f32_16x16x32_bf16(al[i], bf[j], acc[i][j], 0, 0, 0);
      }
  }
  #pragma unroll
  for (int i = 0; i < 4; i++)
    #pragma unroll
    for (int j = 0; j < 4; j++)
      #pragma unroll
      for (int r = 0; r < 4; r++) {
        int p = wm * 64 + i * 16 + rq * 4 + r;
        int c = c0 + wn * 64 + j * 16 + rl;
        size_t g = ((size_t)bh * 128 + p) * 256 + c;
        X1[g] = f2b(x_in[g] + b2f(lnout[g]) + acc[i][j][r]);
      }
}

// ------- fused AFNO MLP, barrier-free: wave = (one n, 64 positions) ----------
// L1 in 4 out-chunks of 64 -> wave-private padded o1buf -> L2 partial accum.
// All weight/Z fragments read direct from global (L2-resident).
__global__ __launch_bounds__(256) void k_afno_mfma(
    const u16* __restrict__ Zr, const u16* __restrict__ Zi,
    const u16* __restrict__ W1h, const u16* __restrict__ W1l,
    const u16* __restrict__ W2h, const u16* __restrict__ W2l,
    const float* __restrict__ b1, const float* __restrict__ b2,
    u16* __restrict__ Or, u16* __restrict__ Oi) {
  __shared__ u16 o1buf[4][64][74];   // [wave][pos][k_local], 148B rows (37 banks)
  int tid = threadIdx.x;
  int lane = tid & 63, w = tid >> 6;
  int n = blockIdx.x * 4 + w;
  int p0 = blockIdx.y * 64;
  int rl = lane & 15, rq = lane >> 4, kq = rq * 8;
  // Z B-fragments (pos tiles j=0..3), loaded once, reused for all out-chunks
  bf16x8 bfr[4];
  #pragma unroll
  for (int j = 0; j < 4; j++) {
    int p = p0 + j * 16 + rl;
    const u16* src = (kq < 16) ? (Zr + (size_t)p * 256 + n * 16 + kq)
                               : (Zi + (size_t)p * 256 + n * 16 + kq - 16);
    bfr[j] = *(const bf16x8*)src;
  }
  f32x4 acc2[2][4] = {};
  for (int c = 0; c < 4; c++) {
    f32x4 a1[4][4] = {};
    #pragma unroll
    for (int i = 0; i < 4; i++) {
      int out = c * 64 + i * 16 + rl;
      bf16x8 ah = *(const bf16x8*)(W1h + ((size_t)n * 256 + out) * 32 + kq);
      bf16x8 al = *(const bf16x8*)(W1l + ((size_t)n * 256 + out) * 32 + kq);
      #pragma unroll
      for (int j = 0; j < 4; j++) {
        a1[i][j] = __builtin_amdgcn_mfma_f32_16x16x32_bf16(ah, bfr[j], a1[i][j], 0, 0, 0);
        a1[i][j] = __builtin_amdgcn_mfma_f32_16x16x32_bf16(al, bfr[j], a1[i][j], 0, 0, 0);
      }
    }
    // bias + relu -> o1buf (8B packed writes; wave-private region)
    #pragma unroll
    for (int i = 0; i < 4; i++) {
      float bv[4];
      #pragma unroll
      for (int r = 0; r < 4; r++) {
        int out = c * 64 + i * 16 + rq * 4 + r;
        bv[r] = (out < 128) ? b1[n * 128 + out] : b1[2048 + n * 128 + out - 128];
      }
      #pragma unroll
      for (int j = 0; j < 4; j++) {
        ushort4 pk;
        u16* pp = &pk.x;
        #pragma unroll
        for (int r = 0; r < 4; r++)
          pp[r] = f2b(fmaxf(a1[i][j][r] + bv[r], 0.0f));
        *(ushort4*)&o1buf[w][j * 16 + rl][i * 16 + rq * 4] = pk;
      }
    }
    // L2 partial over this chunk's k-range (wave-private LDS reads)
    #pragma unroll
    for (int ks = 0; ks < 2; ks++) {
      int kg = c * 64 + ks * 32 + kq;
      #pragma unroll
      for (int i2 = 0; i2 < 2; i2++) {
        int out2 = i2 * 16 + rl;
        bf16x8 ah = *(const bf16x8*)(W2h + ((size_t)n * 32 + out2) * 256 + kg);
        bf16x8 al = *(const bf16x8*)(W2l + ((size_t)n * 32 + out2) * 256 + kg);
        #pragma unroll
        for (int j = 0; j < 4; j++) {
          bf16x8 bb = *(const bf16x8*)&o1buf[w][j * 16 + rl][ks * 32 + kq];
          acc2[i2][j] = __builtin_amdgcn_mfma_f32_16x16x32_bf16(ah, bb, acc2[i2][j], 0, 0, 0);
          acc2[i2][j] = __builtin_amdgcn_mfma_f32_16x16x32_bf16(al, bb, acc2[i2][j], 0, 0, 0);
        }
      }
    }
  }
  // epilogue: bias2 + softshrink -> Or/Oi
  #pragma unroll
  for (int i2 = 0; i2 < 2; i2++)
    #pragma unroll
    for (int r = 0; r < 4; r++) {
      int out2 = i2 * 16 + rq * 4 + r;
      float bv = (out2 < 16) ? b2[n * 16 + out2] : b2[256 + n * 16 + out2 - 16];
      int ch = (out2 < 16) ? out2 : out2 - 16;
      #pragma unroll
      for (int j = 0; j < 4; j++) {
        float v = acc2[i2][j][r] + bv;
        v = copysignf(fmaxf(fabsf(v) - LAM, 0.0f), v);
        size_t g = (size_t)(p0 + j * 16 + rl) * 256 + n * 16 + ch;
        if (out2 < 16) Or[g] = f2b(v);
        else Oi[g] = f2b(v);
      }
    }
}

// ------- MFMA GEMM: C[m,n] = act(A[m,k]*B[n,k] + bias[n]) (+resid) -----------
template<int ACT, int RT, int OUTF>
__global__ __launch_bounds__(256) void k_mgemm(const u16* __restrict__ Ap,
                                               const u16* __restrict__ Bp,
                                               const float* __restrict__ bias,
                                               const u16* __restrict__ resid,
                                               void* __restrict__ Cp,
                                               int M, int N, int K) {
  __shared__ u16 As[128][40];
  __shared__ u16 Bs[128][40];
  int tid = threadIdx.x;
  int lane = tid & 63, w = tid >> 6;
  int wm = w >> 1, wn = w & 1;
  int m0 = blockIdx.x * 128, n0 = blockIdx.y * 128;
  int srow = tid >> 1, sseg = tid & 1;
  const u16* ag = Ap + (size_t)(m0 + srow) * K + sseg * 16;
  const u16* bg = Bp + (size_t)(n0 + srow) * K + sseg * 16;
  int rl = lane & 15, kq = (lane >> 4) * 8;
  f32x4 acc[4][4] = {};
  for (int k0 = 0; k0 < K; k0 += 32) {
    __syncthreads();
    *(u16x8*)&As[srow][sseg * 16]     = *(const u16x8*)(ag + k0);
    *(u16x8*)&As[srow][sseg * 16 + 8] = *(const u16x8*)(ag + k0 + 8);
    *(u16x8*)&Bs[srow][sseg * 16]     = *(const u16x8*)(bg + k0);
    *(u16x8*)&Bs[srow][sseg * 16 + 8] = *(const u16x8*)(bg + k0 + 8);
    __syncthreads();
    bf16x8 af[4], bf[4];
    #pragma unroll
    for (int i = 0; i < 4; i++) {
      af[i] = *(const bf16x8*)&As[wm * 64 + i * 16 + rl][kq];
      bf[i] = *(const bf16x8*)&Bs[wn * 64 + i * 16 + rl][kq];
    }
    #pragma unroll
    for (int i = 0; i < 4; i++)
      #pragma unroll
      for (int j = 0; j < 4; j++)
        acc[i][j] = __builtin_amdgcn_mfma_f32_16x16x32_bf16(af[i], bf[j], acc[i][j], 0, 0, 0);
  }
  int rq = lane >> 4;
  #pragma unroll
  for (int i = 0; i < 4; i++) {
    #pragma unroll
    for (int j = 0; j < 4; j++) {
      #pragma unroll
      for (int r = 0; r < 4; r++) {
        int m = m0 + wm * 64 + i * 16 + rq * 4 + r;
        int n = n0 + wn * 64 + j * 16 + rl;
        float v = acc[i][j][r] + bias[n];
        if (ACT) v = 0.5f * v * (1.0f + erff(v * 0.70710678118654752f));
        if (RT) v += b2f(resid[(size_t)m * N + n]);
        if (OUTF) ((float*)Cp)[(size_t)m * N + n] = v;
        else ((u16*)Cp)[(size_t)m * N + n] = f2b(v);
      }
    }
  }
}

// ---------------- per-head LN over DH=32, bf16 in-place ----------------------
__global__ __launch_bounds__(256) void k_lnhead(u16* __restrict__ X,
                                                const float* __restrict__ g,
                                                const float* __restrict__ bta) {
  int tid = threadIdx.x, lane = tid & 63;
  size_t token = (size_t)blockIdx.x * 4 + (tid >> 6);
  int c = lane * 4;
  ushort4 u = *(const ushort4*)(X + token * Cch + c);
  float v[4] = {b2f(u.x), b2f(u.y), b2f(u.z), b2f(u.w)};
  float s = v[0] + v[1] + v[2] + v[3];
  s += __shfl_xor(s, 1); s += __shfl_xor(s, 2); s += __shfl_xor(s, 4);
  float mu = s * (1.0f / 32.0f);
  float q = 0.f;
  #pragma unroll
  for (int j = 0; j < 4; j++) { float d = v[j] - mu; q += d * d; }
  q += __shfl_xor(q, 1); q += __shfl_xor(q, 2); q += __shfl_xor(q, 4);
  float rs = rsqrtf(q * (1.0f / 32.0f) + EPSN);
  ushort4 o;
  o.x = f2b((v[0] - mu) * rs * g[c + 0] + bta[c + 0]);
  o.y = f2b((v[1] - mu) * rs * g[c + 1] + bta[c + 1]);
  o.z = f2b((v[2] - mu) * rs * g[c + 2] + bta[c + 2]);
  o.w = f2b((v[3] - mu) * rs * g[c + 3] + bta[c + 3]);
  *(ushort4*)(X + token * Cch + c) = o;
}

// ---------------- kv partial sums over 16 chunks of 1024 tokens --------------
__global__ __launch_bounds__(256) void k_kv_partial(const u16* __restrict__ Kb,
                                                    const u16* __restrict__ Vb,
                                                    float* __restrict__ part) {
  __shared__ float kl[64][33], vl[64][33];
  int tid = threadIdx.x;
  int bh = blockIdx.x;
  int b = bh >> 3, h = bh & 7;
  int n0 = blockIdx.y * 1024;
  int d = tid >> 3, eg = tid & 7;
  float acc[4] = {0.f, 0.f, 0.f, 0.f};
  for (int sub = 0; sub < 16; sub++) {
    __syncthreads();
    for (int idx = tid; idx < 64 * 32; idx += 256) {
      int nn = idx >> 5, c = idx & 31;
      size_t o = ((size_t)(b * 16384 + n0 + sub * 64 + nn)) * Cch + h * 32 + c;
      kl[nn][c] = b2f(Kb[o]); vl[nn][c] = b2f(Vb[o]);
    }
    __syncthreads();
    #pragma unroll 4
    for (int nn = 0; nn < 64; nn++) {
      float kd = kl[nn][d];
      #pragma unroll
      for (int j = 0; j < 4; j++) acc[j] += kd * vl[nn][eg * 4 + j];
    }
  }
  size_t base = ((size_t)bh * 16 + blockIdx.y) * 1024 + d * 32 + eg * 4;
  #pragma unroll
  for (int j = 0; j < 4; j++) part[base + j] = acc[j];
}

// reduce partials -> kvT (transposed [e][d]) hi/lo bf16, fp32-accurate pair
__global__ __launch_bounds__(1024) void k_kv_reduce(const float* __restrict__ part,
                                                    u16* __restrict__ kvTh,
                                                    u16* __restrict__ kvTl) {
  int bh = blockIdx.x, o = threadIdx.x;
  float s = 0.f;
  #pragma unroll
  for (int p = 0; p < 16; p++) s += part[((size_t)bh * 16 + p) * 1024 + o];
  s *= (1.0f / 16384.0f);
  int d = o >> 5, e = o & 31;
  u16 hi = f2b(s);
  kvTh[(size_t)bh * 1024 + e * 32 + d] = hi;
  kvTl[(size_t)bh * 1024 + e * 32 + d] = f2b(s - b2f(hi));
}

// ------- MFMA attn: ATT[t, h*32+e] = sum_d Q[t, h*32+d] * kvT[b,h][e][d] ----
__global__ __launch_bounds__(256) void k_attn_m(const u16* __restrict__ Q,
                                                const u16* __restrict__ kvTh,
                                                const u16* __restrict__ kvTl,
                                                u16* __restrict__ ATT) {
  int tid = threadIdx.x;
  int lane = tid & 63, w = tid >> 6;
  int h = blockIdx.y;
  int t0 = blockIdx.x * 64 + w * 16;
  int b = t0 >> 14;
  int rl = lane & 15, rq = lane >> 4, kq = rq * 8;
  bf16x8 a = *(const bf16x8*)(Q + (size_t)(t0 + rl) * 256 + h * 32 + kq);
  const u16* kh = kvTh + (size_t)(b * 8 + h) * 1024;
  const u16* kl = kvTl + (size_t)(b * 8 + h) * 1024;
  f32x4 acc[2] = {};
  #pragma unroll
  for (int j = 0; j < 2; j++) {
    bf16x8 bh_ = *(const bf16x8*)(kh + (j * 16 + rl) * 32 + kq);
    bf16x8 bl_ = *(const bf16x8*)(kl + (j * 16 + rl) * 32 + kq);
    acc[j] = __builtin_amdgcn_mfma_f32_16x16x32_bf16(a, bh_, acc[j], 0, 0, 0);
    acc[j] = __builtin_amdgcn_mfma_f32_16x16x32_bf16(a, bl_, acc[j], 0, 0, 0);
  }
  #pragma unroll
  for (int j = 0; j < 2; j++)
    #pragma unroll
    for (int r = 0; r < 4; r++)
      ATT[(size_t)(t0 + rq * 4 + r) * 256 + h * 32 + j * 16 + rl] = f2b(acc[j][r]);
}

extern "C" void kernel_launch(void* const* d_in, const int* in_sizes, int n_in,
                              void* d_out, int out_size, void* d_ws, size_t ws_size,
                              hipStream_t stream) {
  (void)in_sizes; (void)n_in; (void)out_size; (void)ws_size;
  const float* x    = (const float*)d_in[0];
  const float* w1   = (const float*)d_in[1];
  const float* b1   = (const float*)d_in[2];
  const float* w2   = (const float*)d_in[3];
  const float* b2   = (const float*)d_in[4];
  const float* wq   = (const float*)d_in[5];
  const float* bq   = (const float*)d_in[6];
  const float* wk   = (const float*)d_in[7];
  const float* bk   = (const float*)d_in[8];
  const float* wv   = (const float*)d_in[9];
  const float* bv   = (const float*)d_in[10];
  const float* lnkg = (const float*)d_in[11];
  const float* lnkb = (const float*)d_in[12];
  const float* lnvg = (const float*)d_in[13];
  const float* lnvb = (const float*)d_in[14];
  const float* wo   = (const float*)d_in[15];
  const float* bo   = (const float*)d_in[16];
  const float* wup  = (const float*)d_in[17];
  const float* bup  = (const float*)d_in[18];
  const float* wdn  = (const float*)d_in[19];
  const float* bdn  = (const float*)d_in[20];
  const float* n1g  = (const float*)d_in[21];
  const float* n1b  = (const float*)d_in[22];
  const float* n2g  = (const float*)d_in[23];
  const float* n2b  = (const float*)d_in[24];
  const float* n3g  = (const float*)d_in[25];
  const float* n3b  = (const float*)d_in[26];

  // ws layout unchanged (max 51,970,048 proven safe).
  char* ws = (char*)d_ws;
  u16* A    = (u16*)(ws + 0);
  u16* S1r  = (u16*)(ws + 16777216);
  u16* S1i  = (u16*)(ws + 25296896);
  u16* S2r  = (u16*)(ws + 33816576);
  u16* S2i  = (u16*)(ws + 42336256);
  u16* X1   = (u16*)(ws + 16777216);
  u16* Vb   = (u16*)(ws + 16777216);
  u16* Qb   = (u16*)(ws + 16777216);
  u16* X2   = (u16*)(ws + 16777216);
  u16* Kb   = (u16*)(ws + 33816576);
  u16* ATT  = (u16*)(ws + 33816576);
  u16* UP   = (u16*)(ws + 33816576);
  u16* wq_b = (u16*)(ws + 33554432);
  u16* wk_b = (u16*)(ws + 33685504);
  u16* wv_b = (u16*)(ws + 50593792);
  u16* wo_b = (u16*)(ws + 50724864);
  u16* wup_b = (u16*)(ws + 16777216);
  u16* wdn_b = (u16*)(ws + 17825792);
  u16* TW   = (u16*)(ws + 50855936);
  float* KVp = (float*)(ws + 50855936);
  u16* kvTh = (u16*)(ws + 51904512);
  u16* kvTl = (u16*)(ws + 51937280);
  float* outp = (float*)d_out;
  u16* W1h = (u16*)d_out;
  u16* W1l = W1h + 131072;
  u16* W2h = W1h + 262144;
  u16* W2l = W1h + 393216;

  u16 *Cf_h = TW + 0 * 16384, *Cf_l = TW + 1 * 16384;
  u16 *Sf_h = TW + 2 * 16384, *Sf_l = TW + 3 * 16384;
  u16 *Snf_h = TW + 4 * 16384, *Snf_l = TW + 5 * 16384;
  u16 *Cu_h = TW + 6 * 16384, *Cu_l = TW + 7 * 16384;
  u16 *Su_h = TW + 8 * 16384, *Su_l = TW + 9 * 16384;
  u16 *Snu_h = TW + 10 * 16384, *Snu_l = TW + 11 * 16384;
  u16 *Wm_h = TW + 196608, *Wm_l = TW + 217088;

  k_twid<<<128, 128, 0, stream>>>(TW);
  k_wpack<<<1024, 256, 0, stream>>>(w1, w2, W1h, W1l, W2h, W2l);

  // ---- AFNO: x1 = x + ln1(x) + irfft2(shrink(mlp(rfft2(ln1(x))))) ----
  k_ln<1><<<8192, 256, 0, stream>>>((const void*)x, n1g, n1b, A);
  k_dftw_m<<<dim3(256, 2), 256, 0, stream>>>(A, Cu_h, Cu_l, Snu_h, Snu_l, S1r, S1i);
  k_dfth_m<<<dim3(130, 4), 256, 0, stream>>>(S1r, S1i, Cf_h, Cf_l, Sf_h, Sf_l, Snf_h, Snf_l, S2r, S2i);
  k_afno_mfma<<<dim3(4, 260), 256, 0, stream>>>(S2r, S2i, W1h, W1l, W2h, W2l, b1, b2, S1r, S1i);
  k_dfth_m<<<dim3(130, 4), 256, 0, stream>>>(S1r, S1i, Cu_h, Cu_l, Snu_h, Snu_l, Su_h, Su_l, S2r, S2i);
  k_irfft_m<<<dim3(256, 2), 256, 0, stream>>>(S2r, S2i, Wm_h, Wm_l, x, A, X1);

  // ---- convert QKV/O weights to bf16 (dead S1i/S2i slack) ----
  k_cvt2<<<256, 256, 0, stream>>>(wq, wk, wq_b, wk_b, 65536);
  k_cvt2<<<256, 256, 0, stream>>>(wv, wo, wv_b, wo_b, 65536);

  // ---- Galerkin: x2 = ln2(x1) + wo(attn) ; residual = LN2 OUTPUT ----
  k_ln<0><<<8192, 256, 0, stream>>>((const void*)X1, n2g, n2b, A);
  k_mgemm<0, 0, 0><<<dim3(256, 2), 256, 0, stream>>>(A, wk_b, bk, nullptr, (void*)Kb, 32768, 256, 256);
  k_mgemm<0, 0, 0><<<dim3(256, 2), 256, 0, stream>>>(A, wv_b, bv, nullptr, (void*)Vb, 32768, 256, 256);
  k_lnhead<<<8192, 256, 0, stream>>>(Kb, lnkg, lnkb);
  k_lnhead<<<8192, 256, 0, stream>>>(Vb, lnvg, lnvb);
  k_kv_partial<<<dim3(16, 16), 256, 0, stream>>>(Kb, Vb, KVp);
  k_kv_reduce<<<16, 1024, 0, stream>>>(KVp, kvTh, kvTl);
  k_mgemm<0, 0, 0><<<dim3(256, 2), 256, 0, stream>>>(A, wq_b, bq, nullptr, (void*)Qb, 32768, 256, 256);
  k_attn_m<<<dim3(512, 8), 256, 0, stream>>>(Qb, kvTh, kvTl, ATT);
  k_mgemm<0, 1, 0><<<dim3(256, 2), 256, 0, stream>>>(ATT, wo_b, bo, A, (void*)X2, 32768, 256, 256);

  // ---- FFN: out = ln3(x2) + down(gelu(up(ln3))) ; residual = LN3 OUTPUT ----
  k_ln<0><<<8192, 256, 0, stream>>>((const void*)X2, n3g, n3b, A);
  k_cvt2<<<2048, 256, 0, stream>>>(wup, wdn, wup_b, wdn_b, 524288);
  for (int c = 0; c < 8; c++) {
    const u16* Ac = A + (size_t)c * 4096 * 256;
    k_mgemm<1, 0, 0><<<dim3(32, 16), 256, 0, stream>>>(Ac, wup_b, bup, nullptr, (void*)UP, 4096, 2048, 256);
    k_mgemm<0, 1, 1><<<dim3(32, 2), 256, 0, stream>>>(UP, wdn_b, bdn, Ac, (void*)(outp + (size_t)c * 4096 * 256), 4096, 256, 2048);
  }
}

// Round 14
// 742.959 us; speedup vs baseline: 4.3022x; 1.2150x over previous
//
#include <hip/hip_runtime.h>

// InvariantBlock: AFNO spectral block + Galerkin linear attention + GELU FFN
// B=2 H=128 W=128 C=256; tokens 32768; KW=65; HEADS=8 DH=32; NB=16 BS=16 HID=128
// d_in / d_out FP32; intermediates bf16 in ws. Accumulation fp32.
// R13->R14: fix QKV-fusion aliasing bug — Q now lives in d_out scratch
// (dead between afno_mfma and the FFN), V keeps the old X1 overlay.

typedef unsigned short u16;
typedef unsigned int u32;
typedef __attribute__((ext_vector_type(8))) short bf16x8;
typedef __attribute__((ext_vector_type(8))) unsigned short u16x8;
typedef __attribute__((ext_vector_type(4))) float f32x4;
#define DEV __device__ __forceinline__

constexpr int Cch = 256;
constexpr float EPSN = 1e-5f, LAM = 0.01f;
constexpr float TWO_PI = 6.283185307179586f;

DEV float b2f(u16 u) { return __uint_as_float(((u32)u) << 16); }
DEV u16 f2b(float f) {
  u32 x = __float_as_uint(f);
  return (u16)((x + 0x7FFFu + ((x >> 16) & 1u)) >> 16);
}

// ---------------- twiddle matrices (hi/lo split bf16) ------------------------
DEV void put2(u16* tw, int m, int idx, float v) {
  u16 hi = f2b(v);
  tw[m * 16384 + idx] = hi;
  tw[(m + 1) * 16384 + idx] = f2b(v - b2f(hi));
}

__global__ __launch_bounds__(128) void k_twid(u16* __restrict__ tw) {
  int p = blockIdx.x, q = threadIdx.x;
  int idx = p * 128 + q;
  float ang = TWO_PI * (float)((p * q) & 127) * (1.0f / 128.0f);
  float c = cosf(ang), s = sinf(ang);
  put2(tw, 0, idx, c * (1.0f / 128.0f));
  put2(tw, 2, idx, s * (1.0f / 128.0f));
  put2(tw, 4, idx, -s * (1.0f / 128.0f));
  put2(tw, 6, idx, c);
  put2(tw, 8, idx, s);
  put2(tw, 10, idx, -s);
  u16* wmh = tw + 196608;
  u16* wml = tw + 217088;
  for (int k = q; k < 160; k += 128) {
    float v = 0.0f;
    if (k < 65) {
      float sc = (k == 0 || k == 64) ? 1.0f : 2.0f;
      v = sc * cosf(TWO_PI * (float)((p * k) & 127) * (1.0f / 128.0f)) * (1.0f / 128.0f);
    } else if (k < 130) {
      int kk = k - 65;
      float sc = (kk == 0 || kk == 64) ? 1.0f : 2.0f;
      v = -sc * sinf(TWO_PI * (float)((p * kk) & 127) * (1.0f / 128.0f)) * (1.0f / 128.0f);
    }
    u16 hi = f2b(v);
    wmh[p * 160 + k] = hi;
    wml[p * 160 + k] = f2b(v - b2f(hi));
  }
}

// ------- pack AFNO MLP weights as hi/lo bf16 GEMM operands -------------------
__global__ __launch_bounds__(256) void k_wpack(const float* __restrict__ w1,
                                               const float* __restrict__ w2,
                                               u16* __restrict__ W1h, u16* __restrict__ W1l,
                                               u16* __restrict__ W2h, u16* __restrict__ W2l) {
  int idx = blockIdx.x * 256 + threadIdx.x;
  if (idx < 131072) {
    int n = idx >> 13, rem = idx & 8191;
    int out = rem >> 5, k = rem & 31;
    float v;
    if (out < 128)
      v = (k < 16) ? w1[((size_t)n * 16 + k) * 128 + out]
                   : -w1[((size_t)(16 + n) * 16 + (k - 16)) * 128 + out];
    else {
      int o = out - 128;
      v = (k < 16) ? w1[((size_t)(16 + n) * 16 + k) * 128 + o]
                   : w1[((size_t)n * 16 + (k - 16)) * 128 + o];
    }
    u16 hi = f2b(v);
    W1h[idx] = hi; W1l[idx] = f2b(v - b2f(hi));
  } else if (idx < 262144) {
    int id2 = idx - 131072;
    int n = id2 >> 13, rem = id2 & 8191;
    int out2 = rem >> 8, k = rem & 255;
    float v;
    if (out2 < 16)
      v = (k < 128) ? w2[((size_t)n * 128 + k) * 16 + out2]
                    : -w2[((size_t)(16 + n) * 128 + (k - 128)) * 16 + out2];
    else {
      int o = out2 - 16;
      v = (k < 128) ? w2[((size_t)(16 + n) * 128 + k) * 16 + o]
                    : w2[((size_t)n * 128 + (k - 128)) * 16 + o];
    }
    u16 hi = f2b(v);
    W2h[id2] = hi; W2l[id2] = f2b(v - b2f(hi));
  }
}

// ---------------- fp32 -> bf16 weight convert (two arrays) -------------------
__global__ __launch_bounds__(256) void k_cvt2(const float* __restrict__ s0,
                                              const float* __restrict__ s1,
                                              u16* __restrict__ d0,
                                              u16* __restrict__ d1, int n) {
  int i = blockIdx.x * 256 + threadIdx.x;
  if (i < n) { d0[i] = f2b(s0[i]); d1[i] = f2b(s1[i]); }
}

// ---------------- LayerNorm over C=256; INF=1 fp32 input, else bf16 ----------
template<int INF>
__global__ __launch_bounds__(256) void k_ln(const void* __restrict__ in,
                                            const float* __restrict__ g,
                                            const float* __restrict__ bta,
                                            u16* __restrict__ out) {
  int tid = threadIdx.x, lane = tid & 63;
  size_t token = (size_t)blockIdx.x * 4 + (tid >> 6);
  int c = lane * 4;
  float v[4];
  if (INF) {
    float4 f = *(const float4*)((const float*)in + token * Cch + c);
    v[0] = f.x; v[1] = f.y; v[2] = f.z; v[3] = f.w;
  } else {
    ushort4 u = *(const ushort4*)((const u16*)in + token * Cch + c);
    v[0] = b2f(u.x); v[1] = b2f(u.y); v[2] = b2f(u.z); v[3] = b2f(u.w);
  }
  float s = v[0] + v[1] + v[2] + v[3];
  #pragma unroll
  for (int m = 1; m < 64; m <<= 1) s += __shfl_xor(s, m);
  float mu = s * (1.0f / 256.0f);
  float q = 0.f;
  #pragma unroll
  for (int j = 0; j < 4; j++) { float d = v[j] - mu; q += d * d; }
  #pragma unroll
  for (int m = 1; m < 64; m <<= 1) q += __shfl_xor(q, m);
  float rs = rsqrtf(q * (1.0f / 256.0f) + EPSN);
  ushort4 o;
  o.x = f2b((v[0] - mu) * rs * g[c + 0] + bta[c + 0]);
  o.y = f2b((v[1] - mu) * rs * g[c + 1] + bta[c + 1]);
  o.z = f2b((v[2] - mu) * rs * g[c + 2] + bta[c + 2]);
  o.w = f2b((v[3] - mu) * rs * g[c + 3] + bta[c + 3]);
  *(ushort4*)(out + token * Cch + c) = o;
}

// ------- MFMA forward rDFT over W (cos+sin from one staged tile) -------------
__global__ __launch_bounds__(256) void k_dftw_m(
    const u16* __restrict__ Yg,
    const u16* __restrict__ Chi_, const u16* __restrict__ Clo_,
    const u16* __restrict__ Shi_, const u16* __restrict__ Slo_,
    u16* __restrict__ Or, u16* __restrict__ Oi) {
  __shared__ u16 Bs[128][40];
  int tid = threadIdx.x;
  int bh = blockIdx.x;
  int c0 = blockIdx.y * 128;
  int lane = tid & 63, w = tid >> 6;
  int wm = w >> 1, wn = w & 1;
  int rl = lane & 15, kq = (lane >> 4) * 8, rq = lane >> 4;
  f32x4 accC[4][4] = {};
  f32x4 accS[4][4] = {};
  for (int k0 = 0; k0 < 128; k0 += 32) {
    __syncthreads();
    for (int idx = tid; idx < 1024; idx += 256) {
      int q = idx >> 5, c4 = (idx & 31) * 4;
      ushort4 v = *(const ushort4*)(Yg + ((size_t)bh * 128 + k0 + q) * 256 + c0 + c4);
      Bs[c4 + 0][q] = v.x; Bs[c4 + 1][q] = v.y;
      Bs[c4 + 2][q] = v.z; Bs[c4 + 3][q] = v.w;
    }
    __syncthreads();
    bf16x8 aCh[4], aCl[4], aSh[4], aSl[4], bf[4];
    #pragma unroll
    for (int i = 0; i < 4; i++) {
      int off = (wm * 64 + i * 16 + rl) * 128 + k0 + kq;
      aCh[i] = *(const bf16x8*)(Chi_ + off);
      aCl[i] = *(const bf16x8*)(Clo_ + off);
      aSh[i] = *(const bf16x8*)(Shi_ + off);
      aSl[i] = *(const bf16x8*)(Slo_ + off);
    }
    #pragma unroll
    for (int j = 0; j < 4; j++)
      bf[j] = *(const bf16x8*)&Bs[wn * 64 + j * 16 + rl][kq];
    #pragma unroll
    for (int i = 0; i < 4; i++)
      #pragma unroll
      for (int j = 0; j < 4; j++) {
        accC[i][j] = __builtin_amdgcn_mfma_f32_16x16x32_bf16(aCh[i], bf[j], accC[i][j], 0, 0, 0);
        accC[i][j] = __builtin_amdgcn_mfma_f32_16x16x32_bf16(aCl[i], bf[j], accC[i][j], 0, 0, 0);
        accS[i][j] = __builtin_amdgcn_mfma_f32_16x16x32_bf16(aSh[i], bf[j], accS[i][j], 0, 0, 0);
        accS[i][j] = __builtin_amdgcn_mfma_f32_16x16x32_bf16(aSl[i], bf[j], accS[i][j], 0, 0, 0);
      }
  }
  #pragma unroll
  for (int i = 0; i < 4; i++)
    #pragma unroll
    for (int j = 0; j < 4; j++)
      #pragma unroll
      for (int r = 0; r < 4; r++) {
        int p = wm * 64 + i * 16 + rq * 4 + r;
        if (p < 65) {
          int c = c0 + wn * 64 + j * 16 + rl;
          size_t g = ((size_t)bh * 65 + p) * 256 + c;
          Or[g] = f2b(accC[i][j][r]);
          Oi[g] = f2b(accS[i][j][r]);
        }
      }
}

// ------- MFMA complex DFT over H for fixed (b,kw): O = C*B1 + Ssel*B2 --------
__global__ __launch_bounds__(256) void k_dfth_m(
    const u16* __restrict__ Br_g, const u16* __restrict__ Bi_g,
    const u16* __restrict__ Chi, const u16* __restrict__ Clo,
    const u16* __restrict__ SRhi, const u16* __restrict__ SRlo,
    const u16* __restrict__ SIhi, const u16* __restrict__ SIlo,
    u16* __restrict__ Or, u16* __restrict__ Oi) {
  __shared__ u16 B1s[128][40], B2s[128][40];
  int tid = threadIdx.x;
  int bk = blockIdx.x;
  int b = bk / 65, kw = bk % 65;
  int c0 = (blockIdx.y & 1) * 128;
  int outI = blockIdx.y >> 1;
  const u16* B1g = outI ? Bi_g : Br_g;
  const u16* B2g = outI ? Br_g : Bi_g;
  const u16* Shi = outI ? SIhi : SRhi;
  const u16* Slo = outI ? SIlo : SRlo;
  u16* outp = outI ? Oi : Or;
  int lane = tid & 63, w = tid >> 6;
  int wm = w >> 1, wn = w & 1;
  int rl = lane & 15, kq = (lane >> 4) * 8, rq = lane >> 4;
  f32x4 acc[4][4] = {};
  for (int k0 = 0; k0 < 128; k0 += 32) {
    __syncthreads();
    for (int idx = tid; idx < 1024; idx += 256) {
      int q = idx >> 5, c4 = (idx & 31) * 4;
      size_t g = (((size_t)b * 128 + k0 + q) * 65 + kw) * 256 + c0 + c4;
      ushort4 v1 = *(const ushort4*)(B1g + g);
      ushort4 v2 = *(const ushort4*)(B2g + g);
      B1s[c4 + 0][q] = v1.x; B1s[c4 + 1][q] = v1.y;
      B1s[c4 + 2][q] = v1.z; B1s[c4 + 3][q] = v1.w;
      B2s[c4 + 0][q] = v2.x; B2s[c4 + 1][q] = v2.y;
      B2s[c4 + 2][q] = v2.z; B2s[c4 + 3][q] = v2.w;
    }
    __syncthreads();
    bf16x8 aCh[4], aCl[4], aSh[4], aSl[4], b1[4], b2[4];
    #pragma unroll
    for (int i = 0; i < 4; i++) {
      int off = (wm * 64 + i * 16 + rl) * 128 + k0 + kq;
      aCh[i] = *(const bf16x8*)(Chi + off);
      aCl[i] = *(const bf16x8*)(Clo + off);
      aSh[i] = *(const bf16x8*)(Shi + off);
      aSl[i] = *(const bf16x8*)(Slo + off);
    }
    #pragma unroll
    for (int j = 0; j < 4; j++) {
      b1[j] = *(const bf16x8*)&B1s[wn * 64 + j * 16 + rl][kq];
      b2[j] = *(const bf16x8*)&B2s[wn * 64 + j * 16 + rl][kq];
    }
    #pragma unroll
    for (int i = 0; i < 4; i++)
      #pragma unroll
      for (int j = 0; j < 4; j++) {
        acc[i][j] = __builtin_amdgcn_mfma_f32_16x16x32_bf16(aCh[i], b1[j], acc[i][j], 0, 0, 0);
        acc[i][j] = __builtin_amdgcn_mfma_f32_16x16x32_bf16(aCl[i], b1[j], acc[i][j], 0, 0, 0);
        acc[i][j] = __builtin_amdgcn_mfma_f32_16x16x32_bf16(aSh[i], b2[j], acc[i][j], 0, 0, 0);
        acc[i][j] = __builtin_amdgcn_mfma_f32_16x16x32_bf16(aSl[i], b2[j], acc[i][j], 0, 0, 0);
      }
  }
  #pragma unroll
  for (int i = 0; i < 4; i++)
    #pragma unroll
    for (int j = 0; j < 4; j++)
      #pragma unroll
      for (int r = 0; r < 4; r++) {
        int p = wm * 64 + i * 16 + rq * 4 + r;
        int c = c0 + wn * 64 + j * 16 + rl;
        outp[(((size_t)b * 128 + p) * 65 + kw) * 256 + c] = f2b(acc[i][j][r]);
      }
}

// ------- MFMA inverse rDFT over W + x + ln1out -> X1. K=160 (65r+65i+pad) ----
__global__ __launch_bounds__(256) void k_irfft_m(
    const u16* __restrict__ Ur, const u16* __restrict__ Ui,
    const u16* __restrict__ Whi, const u16* __restrict__ Wlo,
    const float* __restrict__ x_in, const u16* __restrict__ lnout,
    u16* __restrict__ X1) {
  __shared__ u16 Bs[128][40];
  int tid = threadIdx.x;
  int bh = blockIdx.x;
  int c0 = blockIdx.y * 128;
  int lane = tid & 63, w = tid >> 6;
  int wm = w >> 1, wn = w & 1;
  int rl = lane & 15, kq = (lane >> 4) * 8, rq = lane >> 4;
  f32x4 acc[4][4] = {};
  for (int k0 = 0; k0 < 160; k0 += 32) {
    __syncthreads();
    for (int idx = tid; idx < 1024; idx += 256) {
      int q = idx >> 5, c4 = (idx & 31) * 4;
      int grow = k0 + q;
      ushort4 v;
      if (grow < 65)
        v = *(const ushort4*)(Ur + ((size_t)bh * 65 + grow) * 256 + c0 + c4);
      else if (grow < 130)
        v = *(const ushort4*)(Ui + ((size_t)bh * 65 + grow - 65) * 256 + c0 + c4);
      else
        v = make_ushort4(0, 0, 0, 0);
      Bs[c4 + 0][q] = v.x; Bs[c4 + 1][q] = v.y;
      Bs[c4 + 2][q] = v.z; Bs[c4 + 3][q] = v.w;
    }
    __syncthreads();
    bf16x8 ah[4], al[4], bf[4];
    #pragma unroll
    for (int i = 0; i < 4; i++) {
      int off = (wm * 64 + i * 16 + rl) * 160 + k0 + kq;
      ah[i] = *(const bf16x8*)(Whi + off);
      al[i] = *(const bf16x8*)(Wlo + off);
    }
    #pragma unroll
    for (int j = 0; j < 4; j++)
      bf[j] = *(const bf16x8*)&Bs[wn * 64 + j * 16 + rl][kq];
    #pragma unroll
    for (int i = 0; i < 4; i++)
      #pragma unroll
      for (int j = 0; j < 4; j++) {
        acc[i][j] = __builtin_amdgcn_mfma_f32_16x16x32_bf16(ah[i], bf[j], acc[i][j], 0, 0, 0);
        acc[i][j] = __builtin_amdgcn_mfma_f32_16x16x32_bf16(al[i], bf[j], acc[i][j], 0, 0, 0);
      }
  }
  #pragma unroll
  for (int i = 0; i < 4; i++)
    #pragma unroll
    for (int j = 0; j < 4; j++)
      #pragma unroll
      for (int r = 0; r < 4; r++) {
        int p = wm * 64 + i * 16 + rq * 4 + r;
        int c = c0 + wn * 64 + j * 16 + rl;
        size_t g = ((size_t)bh * 128 + p) * 256 + c;
        X1[g] = f2b(x_in[g] + b2f(lnout[g]) + acc[i][j][r]);
      }
}

// ------- fused AFNO MLP, barrier-free (XOR-swizzled o1buf) -------------------
__global__ __launch_bounds__(256) void k_afno_mfma(
    const u16* __restrict__ Zr, const u16* __restrict__ Zi,
    const u16* __restrict__ W1h, const u16* __restrict__ W1l,
    const u16* __restrict__ W2h, const u16* __restrict__ W2l,
    const float* __restrict__ b1, const float* __restrict__ b2,
    u16* __restrict__ Or, u16* __restrict__ Oi) {
  __shared__ u16 o1buf[4][64][74];
  int tid = threadIdx.x;
  int lane = tid & 63, w = tid >> 6;
  int n = blockIdx.x * 4 + w;
  int p0 = blockIdx.y * 64;
  int rl = lane & 15, rq = lane >> 4, kq = rq * 8;
  bf16x8 bfr[4];
  #pragma unroll
  for (int j = 0; j < 4; j++) {
    int p = p0 + j * 16 + rl;
    const u16* src = (kq < 16) ? (Zr + (size_t)p * 256 + n * 16 + kq)
                               : (Zi + (size_t)p * 256 + n * 16 + kq - 16);
    bfr[j] = *(const bf16x8*)src;
  }
  f32x4 acc2[2][4] = {};
  for (int c = 0; c < 4; c++) {
    f32x4 a1[4][4] = {};
    #pragma unroll
    for (int i = 0; i < 4; i++) {
      int out = c * 64 + i * 16 + rl;
      bf16x8 ah = *(const bf16x8*)(W1h + ((size_t)n * 256 + out) * 32 + kq);
      bf16x8 al = *(const bf16x8*)(W1l + ((size_t)n * 256 + out) * 32 + kq);
      #pragma unroll
      for (int j = 0; j < 4; j++) {
        a1[i][j] = __builtin_amdgcn_mfma_f32_16x16x32_bf16(ah, bfr[j], a1[i][j], 0, 0, 0);
        a1[i][j] = __builtin_amdgcn_mfma_f32_16x16x32_bf16(al, bfr[j], a1[i][j], 0, 0, 0);
      }
    }
    #pragma unroll
    for (int i = 0; i < 4; i++) {
      float bv[4];
      #pragma unroll
      for (int r = 0; r < 4; r++) {
        int out = c * 64 + i * 16 + rq * 4 + r;
        bv[r] = (out < 128) ? b1[n * 128 + out] : b1[2048 + n * 128 + out - 128];
      }
      #pragma unroll
      for (int j = 0; j < 4; j++) {
        int pos = j * 16 + rl;
        ushort4 pk;
        u16* pp = &pk.x;
        #pragma unroll
        for (int r = 0; r < 4; r++)
          pp[r] = f2b(fmaxf(a1[i][j][r] + bv[r], 0.0f));
        *(ushort4*)&o1buf[w][pos][(i * 16 + rq * 4) ^ ((pos & 7) << 3)] = pk;
      }
    }
    #pragma unroll
    for (int ks = 0; ks < 2; ks++) {
      int kg = c * 64 + ks * 32 + kq;
      #pragma unroll
      for (int i2 = 0; i2 < 2; i2++) {
        int out2 = i2 * 16 + rl;
        bf16x8 ah = *(const bf16x8*)(W2h + ((size_t)n * 32 + out2) * 256 + kg);
        bf16x8 al = *(const bf16x8*)(W2l + ((size_t)n * 32 + out2) * 256 + kg);
        #pragma unroll
        for (int j = 0; j < 4; j++) {
          int pos = j * 16 + rl;
          bf16x8 bb = *(const bf16x8*)&o1buf[w][pos][(ks * 32 + kq) ^ ((pos & 7) << 3)];
          acc2[i2][j] = __builtin_amdgcn_mfma_f32_16x16x32_bf16(ah, bb, acc2[i2][j], 0, 0, 0);
          acc2[i2][j] = __builtin_amdgcn_mfma_f32_16x16x32_bf16(al, bb, acc2[i2][j], 0, 0, 0);
        }
      }
    }
  }
  #pragma unroll
  for (int i2 = 0; i2 < 2; i2++)
    #pragma unroll
    for (int r = 0; r < 4; r++) {
      int out2 = i2 * 16 + rq * 4 + r;
      float bv = (out2 < 16) ? b2[n * 16 + out2] : b2[256 + n * 16 + out2 - 16];
      int ch = (out2 < 16) ? out2 : out2 - 16;
      #pragma unroll
      for (int j = 0; j < 4; j++) {
        float v = acc2[i2][j][r] + bv;
        v = copysignf(fmaxf(fabsf(v) - LAM, 0.0f), v);
        size_t g = (size_t)(p0 + j * 16 + rl) * 256 + n * 16 + ch;
        if (out2 < 16) Or[g] = f2b(v);
        else Oi[g] = f2b(v);
      }
    }
}

// ------- MFMA GEMM 128x128: C[m,n] = act(A*B^T + bias) (+resid) --------------
template<int ACT, int RT, int OUTF>
__global__ __launch_bounds__(256) void k_mgemm(const u16* __restrict__ Ap,
                                               const u16* __restrict__ Bp,
                                               const float* __restrict__ bias,
                                               const u16* __restrict__ resid,
                                               void* __restrict__ Cp,
                                               int M, int N, int K) {
  __shared__ u16 As[128][40];
  __shared__ u16 Bs[128][40];
  int tid = threadIdx.x;
  int lane = tid & 63, w = tid >> 6;
  int wm = w >> 1, wn = w & 1;
  int m0 = blockIdx.x * 128, n0 = blockIdx.y * 128;
  int srow = tid >> 1, sseg = tid & 1;
  const u16* ag = Ap + (size_t)(m0 + srow) * K + sseg * 16;
  const u16* bg = Bp + (size_t)(n0 + srow) * K + sseg * 16;
  int rl = lane & 15, kq = (lane >> 4) * 8;
  f32x4 acc[4][4] = {};
  for (int k0 = 0; k0 < K; k0 += 32) {
    __syncthreads();
    *(u16x8*)&As[srow][sseg * 16]     = *(const u16x8*)(ag + k0);
    *(u16x8*)&As[srow][sseg * 16 + 8] = *(const u16x8*)(ag + k0 + 8);
    *(u16x8*)&Bs[srow][sseg * 16]     = *(const u16x8*)(bg + k0);
    *(u16x8*)&Bs[srow][sseg * 16 + 8] = *(const u16x8*)(bg + k0 + 8);
    __syncthreads();
    bf16x8 af[4], bf[4];
    #pragma unroll
    for (int i = 0; i < 4; i++) {
      af[i] = *(const bf16x8*)&As[wm * 64 + i * 16 + rl][kq];
      bf[i] = *(const bf16x8*)&Bs[wn * 64 + i * 16 + rl][kq];
    }
    #pragma unroll
    for (int i = 0; i < 4; i++)
      #pragma unroll
      for (int j = 0; j < 4; j++)
        acc[i][j] = __builtin_amdgcn_mfma_f32_16x16x32_bf16(af[i], bf[j], acc[i][j], 0, 0, 0);
  }
  int rq = lane >> 4;
  #pragma unroll
  for (int i = 0; i < 4; i++) {
    #pragma unroll
    for (int j = 0; j < 4; j++) {
      #pragma unroll
      for (int r = 0; r < 4; r++) {
        int m = m0 + wm * 64 + i * 16 + rq * 4 + r;
        int n = n0 + wn * 64 + j * 16 + rl;
        float v = acc[i][j][r] + bias[n];
        if (ACT) v = 0.5f * v * (1.0f + erff(v * 0.70710678118654752f));
        if (RT) v += b2f(resid[(size_t)m * N + n]);
        if (OUTF) ((float*)Cp)[(size_t)m * N + n] = v;
        else ((u16*)Cp)[(size_t)m * N + n] = f2b(v);
      }
    }
  }
}

// ------- fused QKV GEMM: grid (256, 6); y -> {K,V,Q} x col-half --------------
__global__ __launch_bounds__(256) void k_mgemm_qkv(
    const u16* __restrict__ Ap,
    const u16* __restrict__ Wk, const u16* __restrict__ Wv, const u16* __restrict__ Wq,
    const float* __restrict__ bk, const float* __restrict__ bv, const float* __restrict__ bq,
    u16* __restrict__ Ko, u16* __restrict__ Vo, u16* __restrict__ Qo) {
  __shared__ u16 As[128][40];
  __shared__ u16 Bs[128][40];
  int sel = blockIdx.y >> 1;
  const u16* Bp = (sel == 0) ? Wk : (sel == 1) ? Wv : Wq;
  const float* bias = (sel == 0) ? bk : (sel == 1) ? bv : bq;
  u16* Cp = (sel == 0) ? Ko : (sel == 1) ? Vo : Qo;
  int tid = threadIdx.x;
  int lane = tid & 63, w = tid >> 6;
  int wm = w >> 1, wn = w & 1;
  int m0 = blockIdx.x * 128, n0 = (blockIdx.y & 1) * 128;
  int srow = tid >> 1, sseg = tid & 1;
  const u16* ag = Ap + (size_t)(m0 + srow) * 256 + sseg * 16;
  const u16* bg = Bp + (size_t)(n0 + srow) * 256 + sseg * 16;
  int rl = lane & 15, kq = (lane >> 4) * 8;
  f32x4 acc[4][4] = {};
  for (int k0 = 0; k0 < 256; k0 += 32) {
    __syncthreads();
    *(u16x8*)&As[srow][sseg * 16]     = *(const u16x8*)(ag + k0);
    *(u16x8*)&As[srow][sseg * 16 + 8] = *(const u16x8*)(ag + k0 + 8);
    *(u16x8*)&Bs[srow][sseg * 16]     = *(const u16x8*)(bg + k0);
    *(u16x8*)&Bs[srow][sseg * 16 + 8] = *(const u16x8*)(bg + k0 + 8);
    __syncthreads();
    bf16x8 af[4], bf[4];
    #pragma unroll
    for (int i = 0; i < 4; i++) {
      af[i] = *(const bf16x8*)&As[wm * 64 + i * 16 + rl][kq];
      bf[i] = *(const bf16x8*)&Bs[wn * 64 + i * 16 + rl][kq];
    }
    #pragma unroll
    for (int i = 0; i < 4; i++)
      #pragma unroll
      for (int j = 0; j < 4; j++)
        acc[i][j] = __builtin_amdgcn_mfma_f32_16x16x32_bf16(af[i], bf[j], acc[i][j], 0, 0, 0);
  }
  int rq = lane >> 4;
  #pragma unroll
  for (int i = 0; i < 4; i++)
    #pragma unroll
    for (int j = 0; j < 4; j++)
      #pragma unroll
      for (int r = 0; r < 4; r++) {
        int m = m0 + wm * 64 + i * 16 + rq * 4 + r;
        int n = n0 + wn * 64 + j * 16 + rl;
        Cp[(size_t)m * 256 + n] = f2b(acc[i][j][r] + bias[n]);
      }
}

// ------- MFMA GEMM 64x64 tile (FFN down: K=2048, grid (64,4)) ----------------
__global__ __launch_bounds__(256) void k_mgemm_d(const u16* __restrict__ Ap,
                                                 const u16* __restrict__ Bp,
                                                 const float* __restrict__ bias,
                                                 const u16* __restrict__ resid,
                                                 float* __restrict__ Cp,
                                                 int M, int N, int K) {
  __shared__ u16 As[64][40];
  __shared__ u16 Bs[64][40];
  int tid = threadIdx.x;
  int lane = tid & 63, w = tid >> 6;
  int wm = w >> 1, wn = w & 1;
  int m0 = blockIdx.x * 64, n0 = blockIdx.y * 64;
  int srow = tid >> 2, sseg = tid & 3;
  const u16* ag = Ap + (size_t)(m0 + srow) * K + sseg * 8;
  const u16* bg = Bp + (size_t)(n0 + srow) * K + sseg * 8;
  int rl = lane & 15, kq = (lane >> 4) * 8;
  f32x4 acc[2][2] = {};
  for (int k0 = 0; k0 < K; k0 += 32) {
    __syncthreads();
    *(u16x8*)&As[srow][sseg * 8] = *(const u16x8*)(ag + k0);
    *(u16x8*)&Bs[srow][sseg * 8] = *(const u16x8*)(bg + k0);
    __syncthreads();
    bf16x8 af[2], bf[2];
    #pragma unroll
    for (int i = 0; i < 2; i++) {
      af[i] = *(const bf16x8*)&As[wm * 32 + i * 16 + rl][kq];
      bf[i] = *(const bf16x8*)&Bs[wn * 32 + i * 16 + rl][kq];
    }
    #pragma unroll
    for (int i = 0; i < 2; i++)
      #pragma unroll
      for (int j = 0; j < 2; j++)
        acc[i][j] = __builtin_amdgcn_mfma_f32_16x16x32_bf16(af[i], bf[j], acc[i][j], 0, 0, 0);
  }
  int rq = lane >> 4;
  #pragma unroll
  for (int i = 0; i < 2; i++)
    #pragma unroll
    for (int j = 0; j < 2; j++)
      #pragma unroll
      for (int r = 0; r < 4; r++) {
        int m = m0 + wm * 32 + i * 16 + rq * 4 + r;
        int n = n0 + wn * 32 + j * 16 + rl;
        float v = acc[i][j][r] + bias[n] + b2f(resid[(size_t)m * N + n]);
        Cp[(size_t)m * N + n] = v;
      }
}

// ---------------- per-head LN over DH=32, K and V in one launch --------------
__global__ __launch_bounds__(256) void k_lnhead2(u16* __restrict__ K,
                                                 u16* __restrict__ V,
                                                 const float* __restrict__ kg,
                                                 const float* __restrict__ kb,
                                                 const float* __restrict__ vg,
                                                 const float* __restrict__ vb) {
  int tid = threadIdx.x, lane = tid & 63;
  u16* X = blockIdx.y ? V : K;
  const float* g = blockIdx.y ? vg : kg;
  const float* bta = blockIdx.y ? vb : kb;
  size_t token = (size_t)blockIdx.x * 4 + (tid >> 6);
  int c = lane * 4;
  ushort4 u = *(const ushort4*)(X + token * Cch + c);
  float v[4] = {b2f(u.x), b2f(u.y), b2f(u.z), b2f(u.w)};
  float s = v[0] + v[1] + v[2] + v[3];
  s += __shfl_xor(s, 1); s += __shfl_xor(s, 2); s += __shfl_xor(s, 4);
  float mu = s * (1.0f / 32.0f);
  float q = 0.f;
  #pragma unroll
  for (int j = 0; j < 4; j++) { float d = v[j] - mu; q += d * d; }
  q += __shfl_xor(q, 1); q += __shfl_xor(q, 2); q += __shfl_xor(q, 4);
  float rs = rsqrtf(q * (1.0f / 32.0f) + EPSN);
  ushort4 o;
  o.x = f2b((v[0] - mu) * rs * g[c + 0] + bta[c + 0]);
  o.y = f2b((v[1] - mu) * rs * g[c + 1] + bta[c + 1]);
  o.z = f2b((v[2] - mu) * rs * g[c + 2] + bta[c + 2]);
  o.w = f2b((v[3] - mu) * rs * g[c + 3] + bta[c + 3]);
  *(ushort4*)(X + token * Cch + c) = o;
}

// ---------------- kv partial sums over 16 chunks of 1024 tokens --------------
__global__ __launch_bounds__(256) void k_kv_partial(const u16* __restrict__ Kb,
                                                    const u16* __restrict__ Vb,
                                                    float* __restrict__ part) {
  __shared__ float kl[64][33], vl[64][33];
  int tid = threadIdx.x;
  int bh = blockIdx.x;
  int b = bh >> 3, h = bh & 7;
  int n0 = blockIdx.y * 1024;
  int d = tid >> 3, eg = tid & 7;
  float acc[4] = {0.f, 0.f, 0.f, 0.f};
  for (int sub = 0; sub < 16; sub++) {
    __syncthreads();
    for (int idx = tid; idx < 64 * 32; idx += 256) {
      int nn = idx >> 5, c = idx & 31;
      size_t o = ((size_t)(b * 16384 + n0 + sub * 64 + nn)) * Cch + h * 32 + c;
      kl[nn][c] = b2f(Kb[o]); vl[nn][c] = b2f(Vb[o]);
    }
    __syncthreads();
    #pragma unroll 4
    for (int nn = 0; nn < 64; nn++) {
      float kd = kl[nn][d];
      #pragma unroll
      for (int j = 0; j < 4; j++) acc[j] += kd * vl[nn][eg * 4 + j];
    }
  }
  size_t base = ((size_t)bh * 16 + blockIdx.y) * 1024 + d * 32 + eg * 4;
  #pragma unroll
  for (int j = 0; j < 4; j++) part[base + j] = acc[j];
}

// reduce partials -> kvT (transposed [e][d]) hi/lo bf16, fp32-accurate pair
__global__ __launch_bounds__(1024) void k_kv_reduce(const float* __restrict__ part,
                                                    u16* __restrict__ kvTh,
                                                    u16* __restrict__ kvTl) {
  int bh = blockIdx.x, o = threadIdx.x;
  float s = 0.f;
  #pragma unroll
  for (int p = 0; p < 16; p++) s += part[((size_t)bh * 16 + p) * 1024 + o];
  s *= (1.0f / 16384.0f);
  int d = o >> 5, e = o & 31;
  u16 hi = f2b(s);
  kvTh[(size_t)bh * 1024 + e * 32 + d] = hi;
  kvTl[(size_t)bh * 1024 + e * 32 + d] = f2b(s - b2f(hi));
}

// ------- MFMA attn: ATT[t, h*32+e] = sum_d Q[t, h*32+d] * kvT[b,h][e][d] ----
__global__ __launch_bounds__(256) void k_attn_m(const u16* __restrict__ Q,
                                                const u16* __restrict__ kvTh,
                                                const u16* __restrict__ kvTl,
                                                u16* __restrict__ ATT) {
  int tid = threadIdx.x;
  int lane = tid & 63, w = tid >> 6;
  int h = blockIdx.y;
  int t0 = blockIdx.x * 64 + w * 16;
  int b = t0 >> 14;
  int rl = lane & 15, rq = lane >> 4, kq = rq * 8;
  bf16x8 a = *(const bf16x8*)(Q + (size_t)(t0 + rl) * 256 + h * 32 + kq);
  const u16* kh = kvTh + (size_t)(b * 8 + h) * 1024;
  const u16* kl = kvTl + (size_t)(b * 8 + h) * 1024;
  f32x4 acc[2] = {};
  #pragma unroll
  for (int j = 0; j < 2; j++) {
    bf16x8 bh_ = *(const bf16x8*)(kh + (j * 16 + rl) * 32 + kq);
    bf16x8 bl_ = *(const bf16x8*)(kl + (j * 16 + rl) * 32 + kq);
    acc[j] = __builtin_amdgcn_mfma_f32_16x16x32_bf16(a, bh_, acc[j], 0, 0, 0);
    acc[j] = __builtin_amdgcn_mfma_f32_16x16x32_bf16(a, bl_, acc[j], 0, 0, 0);
  }
  #pragma unroll
  for (int j = 0; j < 2; j++)
    #pragma unroll
    for (int r = 0; r < 4; r++)
      ATT[(size_t)(t0 + rq * 4 + r) * 256 + h * 32 + j * 16 + rl] = f2b(acc[j][r]);
}

extern "C" void kernel_launch(void* const* d_in, const int* in_sizes, int n_in,
                              void* d_out, int out_size, void* d_ws, size_t ws_size,
                              hipStream_t stream) {
  (void)in_sizes; (void)n_in; (void)out_size; (void)ws_size;
  const float* x    = (const float*)d_in[0];
  const float* w1   = (const float*)d_in[1];
  const float* b1   = (const float*)d_in[2];
  const float* w2   = (const float*)d_in[3];
  const float* b2   = (const float*)d_in[4];
  const float* wq   = (const float*)d_in[5];
  const float* bq   = (const float*)d_in[6];
  const float* wk   = (const float*)d_in[7];
  const float* bk   = (const float*)d_in[8];
  const float* wv   = (const float*)d_in[9];
  const float* bv   = (const float*)d_in[10];
  const float* lnkg = (const float*)d_in[11];
  const float* lnkb = (const float*)d_in[12];
  const float* lnvg = (const float*)d_in[13];
  const float* lnvb = (const float*)d_in[14];
  const float* wo   = (const float*)d_in[15];
  const float* bo   = (const float*)d_in[16];
  const float* wup  = (const float*)d_in[17];
  const float* bup  = (const float*)d_in[18];
  const float* wdn  = (const float*)d_in[19];
  const float* bdn  = (const float*)d_in[20];
  const float* n1g  = (const float*)d_in[21];
  const float* n1b  = (const float*)d_in[22];
  const float* n2g  = (const float*)d_in[23];
  const float* n2b  = (const float*)d_in[24];
  const float* n3g  = (const float*)d_in[25];
  const float* n3b  = (const float*)d_in[26];

  // ws layout (max 51,970,048, proven safe). Qb lives in d_out scratch:
  // d_out is dead from after k_afno_mfma (weight packs consumed) until the
  // FFN overwrites all of it; Q is written by QKV and consumed by attn.
  char* ws = (char*)d_ws;
  u16* A    = (u16*)(ws + 0);
  u16* S1r  = (u16*)(ws + 16777216);
  u16* S1i  = (u16*)(ws + 25296896);
  u16* S2r  = (u16*)(ws + 33816576);
  u16* S2i  = (u16*)(ws + 42336256);
  u16* X1   = (u16*)(ws + 16777216);
  u16* Vb   = (u16*)(ws + 16777216);   // over X1 (dead after ln2)
  u16* X2   = (u16*)(ws + 16777216);   // over V (dead after kv_partial)
  u16* Kb   = (u16*)(ws + 33816576);   // over S2 (dead after irfft)
  u16* ATT  = (u16*)(ws + 33816576);   // over K (dead after kv_partial)
  u16* UP   = (u16*)(ws + 33816576);   // over ATT (dead after wo)
  u16* wq_b = (u16*)(ws + 33554432);
  u16* wk_b = (u16*)(ws + 33685504);
  u16* wv_b = (u16*)(ws + 50593792);
  u16* wo_b = (u16*)(ws + 50724864);
  u16* wup_b = (u16*)(ws + 16777216);  // over X2 (dead after ln3)
  u16* wdn_b = (u16*)(ws + 17825792);
  u16* TW   = (u16*)(ws + 50855936);
  float* KVp = (float*)(ws + 50855936);
  u16* kvTh = (u16*)(ws + 51904512);
  u16* kvTl = (u16*)(ws + 51937280);
  float* outp = (float*)d_out;
  u16* Qb  = (u16*)d_out;              // d_out scratch (dead until FFN)
  u16* W1h = (u16*)d_out;
  u16* W1l = W1h + 131072;
  u16* W2h = W1h + 262144;
  u16* W2l = W1h + 393216;

  u16 *Cf_h = TW + 0 * 16384, *Cf_l = TW + 1 * 16384;
  u16 *Sf_h = TW + 2 * 16384, *Sf_l = TW + 3 * 16384;
  u16 *Snf_h = TW + 4 * 16384, *Snf_l = TW + 5 * 16384;
  u16 *Cu_h = TW + 6 * 16384, *Cu_l = TW + 7 * 16384;
  u16 *Su_h = TW + 8 * 16384, *Su_l = TW + 9 * 16384;
  u16 *Snu_h = TW + 10 * 16384, *Snu_l = TW + 11 * 16384;
  u16 *Wm_h = TW + 196608, *Wm_l = TW + 217088;

  k_twid<<<128, 128, 0, stream>>>(TW);
  k_wpack<<<1024, 256, 0, stream>>>(w1, w2, W1h, W1l, W2h, W2l);

  // ---- AFNO: x1 = x + ln1(x) + irfft2(shrink(mlp(rfft2(ln1(x))))) ----
  k_ln<1><<<8192, 256, 0, stream>>>((const void*)x, n1g, n1b, A);
  k_dftw_m<<<dim3(256, 2), 256, 0, stream>>>(A, Cu_h, Cu_l, Snu_h, Snu_l, S1r, S1i);
  k_dfth_m<<<dim3(130, 4), 256, 0, stream>>>(S1r, S1i, Cf_h, Cf_l, Sf_h, Sf_l, Snf_h, Snf_l, S2r, S2i);
  k_afno_mfma<<<dim3(4, 260), 256, 0, stream>>>(S2r, S2i, W1h, W1l, W2h, W2l, b1, b2, S1r, S1i);
  k_dfth_m<<<dim3(130, 4), 256, 0, stream>>>(S1r, S1i, Cu_h, Cu_l, Snu_h, Snu_l, Su_h, Su_l, S2r, S2i);
  k_irfft_m<<<dim3(256, 2), 256, 0, stream>>>(S2r, S2i, Wm_h, Wm_l, x, A, X1);

  // ---- convert QKV/O weights to bf16 (dead S1i/S2i slack) ----
  k_cvt2<<<256, 256, 0, stream>>>(wq, wk, wq_b, wk_b, 65536);
  k_cvt2<<<256, 256, 0, stream>>>(wv, wo, wv_b, wo_b, 65536);

  // ---- Galerkin: x2 = ln2(x1) + wo(attn) ; residual = LN2 OUTPUT ----
  k_ln<0><<<8192, 256, 0, stream>>>((const void*)X1, n2g, n2b, A);
  k_mgemm_qkv<<<dim3(256, 6), 256, 0, stream>>>(A, wk_b, wv_b, wq_b, bk, bv, bq, Kb, Vb, Qb);
  k_lnhead2<<<dim3(8192, 2), 256, 0, stream>>>(Kb, Vb, lnkg, lnkb, lnvg, lnvb);
  k_kv_partial<<<dim3(16, 16), 256, 0, stream>>>(Kb, Vb, KVp);
  k_kv_reduce<<<16, 1024, 0, stream>>>(KVp, kvTh, kvTl);
  k_attn_m<<<dim3(512, 8), 256, 0, stream>>>(Qb, kvTh, kvTl, ATT);
  k_mgemm<0, 1, 0><<<dim3(256, 2), 256, 0, stream>>>(ATT, wo_b, bo, A, (void*)X2, 32768, 256, 256);

  // ---- FFN: out = ln3(x2) + down(gelu(up(ln3))) ; residual = LN3 OUTPUT ----
  k_ln<0><<<8192, 256, 0, stream>>>((const void*)X2, n3g, n3b, A);
  k_cvt2<<<2048, 256, 0, stream>>>(wup, wdn, wup_b, wdn_b, 524288);
  for (int c = 0; c < 8; c++) {
    const u16* Ac = A + (size_t)c * 4096 * 256;
    k_mgemm<1, 0, 0><<<dim3(32, 16), 256, 0, stream>>>(Ac, wup_b, bup, nullptr, (void*)UP, 4096, 2048, 256);
    k_mgemm_d<<<dim3(64, 4), 256, 0, stream>>>(UP, wdn_b, bdn, Ac, outp + (size_t)c * 4096 * 256, 4096, 256, 2048);
  }
}